// Round 12
// baseline (172.904 us; speedup 1.0000x reference)
//
#include <hip/hip_runtime.h>
#include <math.h>

#define NV 6
#define FHH 32
#define FWW 96
#define PIMG (FHH*FWW)   // 3072
#define HH 64
#define WWD 64
#define PBEV (HH*WWD)    // 4096
#define HEADS 4
#define DHD 32
#define KROWS 288
#define BN_S 0.9999950000374996f
#define LN_EPS 1e-5f
#define ATT_SCALE 0.17677669529663687f  // 32^-0.5

typedef __attribute__((ext_vector_type(8))) short short8;
typedef __attribute__((ext_vector_type(4))) float f32x4;
typedef __attribute__((ext_vector_type(8))) unsigned short u16x8;

__device__ __forceinline__ float gelu_f(float x) {
    return 0.5f * x * (1.0f + erff(x * 0.70710678118654752f));
}

__device__ __forceinline__ unsigned short f2bf(float f) {
    union { float f; unsigned int u; } c; c.f = f;
    unsigned int r = (c.u + 0x7fffu + ((c.u >> 16) & 1u)) >> 16;
    return (unsigned short)r;
}

// bf16 weight arena offsets (u16 elements)
#define OFF_FP    0
#define OFF_FL    16384
#define OFF_A1QW  32768
#define OFF_A1KW  49152
#define OFF_A2KW  65536
#define OFF_A1VW  81920
#define OFF_A2VW  98304
#define OFF_A1PW  114688
#define OFF_M1W1  131072
#define OFF_M1W2  163840
#define OFF_A2QW  196608
#define OFF_A2PW  212992
#define OFF_M2W1  229376
#define OFF_M2W2  262144
#define OFF_MBEW  294912
#define OFF_MBPW  360448
#define OFF_PMW1  425984
#define OFF_PMW2  458752
#define OFF_POW   491520
#define WTOTAL    507904

// ---------- prep: weight f32->bf16 arena (blocks 0..247) + x transpose (248..759) ----------
__global__ void k_prep(const float* p0, const float* p1, const float* p2,
                       const float* p3, const float* p4, const float* p5,
                       const float* p6, const float* p7, const float* p8,
                       const float* p9, const float* p10, const float* p11,
                       const float* p12, const float* p13, const float* p14,
                       const float* p15, const float* p16, const float* p17,
                       const float* p18, unsigned short* wb,
                       const float* __restrict__ x, float* __restrict__ x_cl) {
    __shared__ float tile[32][33];
    if (blockIdx.x < 248) {
        int idx = (blockIdx.x * 256 + threadIdx.x) * 8;
        if (idx >= WTOTAL) return;
        const float* s;
        if      (idx < OFF_FL)   s = p0  + idx;
        else if (idx < OFF_A1QW) s = p1  + (idx - OFF_FL);
        else if (idx < OFF_A1KW) s = p2  + (idx - OFF_A1QW);
        else if (idx < OFF_A2KW) s = p3  + (idx - OFF_A1KW);
        else if (idx < OFF_A1VW) s = p4  + (idx - OFF_A2KW);
        else if (idx < OFF_A2VW) s = p5  + (idx - OFF_A1VW);
        else if (idx < OFF_A1PW) s = p6  + (idx - OFF_A2VW);
        else if (idx < OFF_M1W1) s = p7  + (idx - OFF_A1PW);
        else if (idx < OFF_M1W2) s = p8  + (idx - OFF_M1W1);
        else if (idx < OFF_A2QW) s = p9  + (idx - OFF_M1W2);
        else if (idx < OFF_A2PW) s = p10 + (idx - OFF_A2QW);
        else if (idx < OFF_M2W1) s = p11 + (idx - OFF_A2PW);
        else if (idx < OFF_M2W2) s = p12 + (idx - OFF_M2W1);
        else if (idx < OFF_MBEW) s = p13 + (idx - OFF_M2W2);
        else if (idx < OFF_MBPW) s = p14 + (idx - OFF_MBEW);
        else if (idx < OFF_PMW1) s = p15 + (idx - OFF_MBPW);
        else if (idx < OFF_PMW2) s = p16 + (idx - OFF_PMW1);
        else if (idx < OFF_POW)  s = p17 + (idx - OFF_PMW2);
        else                     s = p18 + (idx - OFF_POW);
        float4 v0 = *(const float4*)&s[0];
        float4 v1 = *(const float4*)&s[4];
        u16x8 o = { f2bf(v0.x), f2bf(v0.y), f2bf(v0.z), f2bf(v0.w),
                    f2bf(v1.x), f2bf(v1.y), f2bf(v1.z), f2bf(v1.w) };
        *(u16x8*)&wb[idx] = o;
    } else {
        int bb = blockIdx.x - 248;
        int p0_ = (bb & 127) * 32, c0 = (bb >> 7) * 32;
        int tp = threadIdx.x & 31, tg = threadIdx.x >> 5;
        #pragma unroll
        for (int i = 0; i < 4; ++i)
            tile[tg + 8 * i][tp] = x[(size_t)(c0 + tg + 8 * i) * PBEV + p0_ + tp];
        __syncthreads();
        #pragma unroll
        for (int i = 0; i < 4; ++i)
            x_cl[(size_t)(p0_ + tg + 8 * i) * 128 + c0 + tp] = tile[tp][tg + 8 * i];
    }
}

// ---------- mega key/val: feature GEMM + img-embed + LN + 4 head GEMMs ----------
__global__ __launch_bounds__(256)
void k_keyval(const float* __restrict__ feat, const unsigned short* __restrict__ wb,
              const float* __restrict__ ie_w, const float* __restrict__ ce_w,
              const float* __restrict__ I_inv, const float* __restrict__ E_inv,
              const float* __restrict__ a1_kb, const float* __restrict__ a2_kb,
              const float* __restrict__ a1_vb, const float* __restrict__ a2_vb,
              unsigned short* __restrict__ kh1b, unsigned short* __restrict__ kh2b,
              unsigned short* __restrict__ vh1b, unsigned short* __restrict__ vh2b) {
    __shared__ unsigned short Al[64 * 136];
    __shared__ unsigned short Bl[64 * 136];
    __shared__ unsigned short Wl[128 * 136];
    const int t = threadIdx.x;
    const int rb = blockIdx.x * 64;
    const int n = rb / PIMG;
    const int lane = t & 63, wv = t >> 6;
    const int la = lane & 15, g = lane >> 4;

    // stage feature (transpose + BN + relu) -> Al
    {
        int p0 = rb % PIMG;
        int r = t & 63, kseg = t >> 6;
        #pragma unroll
        for (int j8 = 0; j8 < 4; ++j8) {
            u16x8 o;
            #pragma unroll
            for (int j = 0; j < 8; ++j) {
                int k = kseg * 32 + j8 * 8 + j;
                float v = feat[((size_t)(n * 128 + k)) * PIMG + p0 + r];
                o[j] = f2bf(fmaxf(v * BN_S, 0.0f));
            }
            *(u16x8*)&Al[r * 136 + kseg * 32 + j8 * 8] = o;
        }
    }

    // geometry per-row (for EMB on key set)
    float d0[4], d1[4], d2[4], d3[4];
    {
        const float* Ii = I_inv + n * 9;
        const float* E  = E_inv + n * 16;
        #pragma unroll
        for (int r = 0; r < 4; ++r) {
            int row = rb + wv * 16 + g * 4 + r;
            int p = row % PIMG;
            int hh = p / FWW, wp = p % FWW;
            float gx = (float)wp * (768.0f / 95.0f);
            float gy = (float)hh * (256.0f / 31.0f);
            float c0 = Ii[0]*gx + Ii[1]*gy + Ii[2];
            float c1 = Ii[3]*gx + Ii[4]*gy + Ii[5];
            float c2 = Ii[6]*gx + Ii[7]*gy + Ii[8];
            d0[r] = E[0]*c0  + E[1]*c1  + E[2]*c2  + E[3];
            d1[r] = E[4]*c0  + E[5]*c1  + E[6]*c2  + E[7];
            d2[r] = E[8]*c0  + E[9]*c1  + E[10]*c2 + E[11];
            d3[r] = E[12]*c0 + E[13]*c1 + E[14]*c2 + E[15];
        }
    }

    #pragma unroll 1
    for (int kv = 0; kv < 2; ++kv) {
        __syncthreads();
        // base GEMM: f . (fp|fl)^T
        {
            const unsigned short* Wf = wb + (kv ? OFF_FL : OFF_FP);
            #pragma unroll
            for (int i = 0; i < 8; ++i) {
                int chunk = i * 256 + t;
                int c = chunk >> 4, k8 = chunk & 15;
                *(u16x8*)&Wl[c * 136 + k8 * 8] = *(const u16x8*)&Wf[(size_t)c * 128 + k8 * 8];
            }
        }
        __syncthreads();
        short8 af[4];
        #pragma unroll
        for (int ks = 0; ks < 4; ++ks)
            af[ks] = *(short8*)&Al[(wv * 16 + la) * 136 + ks * 32 + g * 8];
        float vacc[8][4];
        #pragma unroll
        for (int ct = 0; ct < 8; ++ct) {
            f32x4 a = (f32x4){0.f, 0.f, 0.f, 0.f};
            #pragma unroll
            for (int ks = 0; ks < 4; ++ks) {
                short8 bf = *(short8*)&Wl[(ct * 16 + la) * 136 + ks * 32 + g * 8];
                a = __builtin_amdgcn_mfma_f32_16x16x32_bf16(af[ks], bf, a, 0, 0, 0);
            }
            #pragma unroll
            for (int r = 0; r < 4; ++r) vacc[ct][r] = a[r];
        }
        if (kv == 0) {
            // EMB: normalized geometric image embedding
            const float* E = E_inv + n * 16;
            float embv[8][4];
            float ssr[4] = {0.f, 0.f, 0.f, 0.f};
            #pragma unroll
            for (int ct = 0; ct < 8; ++ct) {
                int col = ct * 16 + la;
                const float* iw = ie_w + col * 4;
                const float* cw = ce_w + col * 4;
                float cemb = E[3]*cw[0] + E[7]*cw[1] + E[11]*cw[2] + E[15]*cw[3];
                #pragma unroll
                for (int r = 0; r < 4; ++r) {
                    float e = d0[r]*iw[0] + d1[r]*iw[1] + d2[r]*iw[2] + d3[r]*iw[3] - cemb;
                    embv[ct][r] = e;
                    ssr[r] += e * e;
                }
            }
            #pragma unroll
            for (int r = 0; r < 4; ++r) {
                float s = ssr[r];
                s += __shfl_xor(s, 1); s += __shfl_xor(s, 2);
                s += __shfl_xor(s, 4); s += __shfl_xor(s, 8);
                float inv = 1.0f / (sqrtf(s) + 1e-7f);
                #pragma unroll
                for (int ct = 0; ct < 8; ++ct) vacc[ct][r] += embv[ct][r] * inv;
            }
        }
        // LN per row (in-register)
        #pragma unroll
        for (int r = 0; r < 4; ++r) {
            float s = 0.f;
            #pragma unroll
            for (int ct = 0; ct < 8; ++ct) s += vacc[ct][r];
            s += __shfl_xor(s, 1); s += __shfl_xor(s, 2);
            s += __shfl_xor(s, 4); s += __shfl_xor(s, 8);
            float mu = s * (1.0f / 128.0f);
            float ss = 0.f;
            #pragma unroll
            for (int ct = 0; ct < 8; ++ct) { float d = vacc[ct][r] - mu; ss += d * d; }
            ss += __shfl_xor(ss, 1); ss += __shfl_xor(ss, 2);
            ss += __shfl_xor(ss, 4); ss += __shfl_xor(ss, 8);
            float rs = rsqrtf(ss * (1.0f / 128.0f) + LN_EPS);
            int brow = wv * 16 + g * 4 + r;
            #pragma unroll
            for (int ct = 0; ct < 8; ++ct)
                Bl[brow * 136 + ct * 16 + la] = f2bf((vacc[ct][r] - mu) * rs);
        }

        // two head GEMMs from Bl
        #pragma unroll 1
        for (int hs = 0; hs < 2; ++hs) {
            __syncthreads();
            const unsigned short* Wh = wb + (kv == 0 ? (hs ? OFF_A2KW : OFF_A1KW)
                                                     : (hs ? OFF_A2VW : OFF_A1VW));
            const float* hb = kv == 0 ? (hs ? a2_kb : a1_kb) : (hs ? a2_vb : a1_vb);
            unsigned short* oc = kv == 0 ? (hs ? kh2b : kh1b) : (hs ? vh2b : vh1b);
            #pragma unroll
            for (int i = 0; i < 8; ++i) {
                int chunk = i * 256 + t;
                int c = chunk >> 4, k8 = chunk & 15;
                *(u16x8*)&Wl[c * 136 + k8 * 8] = *(const u16x8*)&Wh[(size_t)c * 128 + k8 * 8];
            }
            __syncthreads();
            short8 af2[4];
            #pragma unroll
            for (int ks = 0; ks < 4; ++ks)
                af2[ks] = *(short8*)&Bl[(wv * 16 + la) * 136 + ks * 32 + g * 8];
            #pragma unroll
            for (int ct = 0; ct < 8; ++ct) {
                f32x4 a = (f32x4){0.f, 0.f, 0.f, 0.f};
                #pragma unroll
                for (int ks = 0; ks < 4; ++ks) {
                    short8 bf = *(short8*)&Wl[(ct * 16 + la) * 136 + ks * 32 + g * 8];
                    a = __builtin_amdgcn_mfma_f32_16x16x32_bf16(af2[ks], bf, a, 0, 0, 0);
                }
                int col = ct * 16 + la;
                float bv = hb[col];
                #pragma unroll
                for (int r = 0; r < 4; ++r)
                    oc[(size_t)(rb + wv * 16 + g * 4 + r) * 128 + col] = f2bf(a[r] + bv);
            }
        }
    }
}

// ---------- reduced MFMA GEMM (AMODE 0 row-major f32 / 3 fused query gen) ----------
template<int BR, int NOT, int AMODE, int LNF, int BIASF, int ACT, int SCL,
         int OUTBF, int QSCL, int WRLN>
__global__ __launch_bounds__(256)
void k_gemm_mfma(const float* __restrict__ A, const unsigned short* __restrict__ Wb,
                 const float* __restrict__ bias, const float* __restrict__ bev,
                 const float* __restrict__ x_cl, const float* __restrict__ be_w,
                 const float* __restrict__ be_b, const float* __restrict__ E_inv,
                 const float* __restrict__ ce_w, float* __restrict__ aux,
                 void* __restrict__ outv) {
    constexpr int RW = BR / 16;
    constexpr int CT = 8 / (4 / RW);
    __shared__ unsigned short Al[BR * 136];
    __shared__ unsigned short Wl[128 * 136];
    const int t = threadIdx.x;
    const int rb = blockIdx.x * BR;
    const int co = blockIdx.y * 128;
    const int lane = t & 63, wv = t >> 6;
    const int la = lane & 15, g = lane >> 4;
    const int roww = wv % RW, colg = wv / RW;

    {
        constexpr int TPR = 256 / BR;
        constexpr int CPT = 128 / TPR;
        int r = t / TPR, seg = t % TPR;
        float v[CPT];
        if constexpr (AMODE == 3) {
            int grow = rb + r;
            int n = grow >> 12, p = grow & 4095;
            const float* E = E_inv + n * 16;
            float bp0 = bev[p], bp1 = bev[PBEV + p];
            float ss = 0.f;
            #pragma unroll
            for (int j = 0; j < CPT; ++j) {
                int c = seg * CPT + j;
                float cemb = E[3]  * ce_w[c*4+0] + E[7]  * ce_w[c*4+1]
                           + E[11] * ce_w[c*4+2] + E[15] * ce_w[c*4+3];
                float emb = bp0 * be_w[c*2] + bp1 * be_w[c*2+1] + be_b[c] - cemb;
                v[j] = emb; ss += emb * emb;
            }
            #pragma unroll
            for (int o = 1; o < TPR; o <<= 1) ss += __shfl_xor(ss, o, 64);
            float invn = 1.0f / (sqrtf(ss) + 1e-7f);
            const float* xr = x_cl + (size_t)p * 128 + seg * CPT;
            #pragma unroll
            for (int j = 0; j < CPT; ++j) v[j] = v[j] * invn + xr[j];
        } else {
            const float* ar = A + (size_t)(rb + r) * 128 + seg * CPT;
            #pragma unroll
            for (int j4 = 0; j4 < CPT / 4; ++j4)
                *(float4*)&v[4 * j4] = *(const float4*)&ar[4 * j4];
        }
        if constexpr (LNF) {
            float s = 0.f;
            #pragma unroll
            for (int j = 0; j < CPT; ++j) s += v[j];
            #pragma unroll
            for (int o = 1; o < TPR; o <<= 1) s += __shfl_xor(s, o, 64);
            float mu = s * (1.0f / 128.0f);
            float ss = 0.f;
            #pragma unroll
            for (int j = 0; j < CPT; ++j) { float d = v[j] - mu; ss += d * d; }
            #pragma unroll
            for (int o = 1; o < TPR; o <<= 1) ss += __shfl_xor(ss, o, 64);
            float rs = rsqrtf(ss * (1.0f / 128.0f) + LN_EPS);
            #pragma unroll
            for (int j = 0; j < CPT; ++j) v[j] = (v[j] - mu) * rs;
            if constexpr (WRLN) {
                if (blockIdx.y == 0) {
                    #pragma unroll
                    for (int j4 = 0; j4 < CPT / 4; ++j4) {
                        float4 o4 = {v[4*j4], v[4*j4+1], v[4*j4+2], v[4*j4+3]};
                        *(float4*)&aux[(size_t)(rb + r) * 128 + seg * CPT + 4 * j4] = o4;
                    }
                }
            }
        }
        #pragma unroll
        for (int j8 = 0; j8 < CPT / 8; ++j8) {
            u16x8 o;
            #pragma unroll
            for (int j = 0; j < 8; ++j) o[j] = f2bf(v[8 * j8 + j]);
            *(u16x8*)&Al[r * 136 + seg * CPT + 8 * j8] = o;
        }
    }

    #pragma unroll
    for (int i = 0; i < 8; ++i) {
        int chunk = i * 256 + t;
        int c = chunk >> 4, k8 = chunk & 15;
        *(u16x8*)&Wl[c * 136 + k8 * 8] = *(const u16x8*)&Wb[(size_t)(co + c) * 128 + k8 * 8];
    }
    __syncthreads();

    short8 af[4];
    #pragma unroll
    for (int ks = 0; ks < 4; ++ks)
        af[ks] = *(short8*)&Al[(roww * 16 + la) * 136 + ks * 32 + g * 8];
    #pragma unroll
    for (int cti = 0; cti < CT; ++cti) {
        int ct = colg * CT + cti;
        f32x4 acc = (f32x4){0.f, 0.f, 0.f, 0.f};
        #pragma unroll
        for (int ks = 0; ks < 4; ++ks) {
            short8 bf = *(short8*)&Wl[(ct * 16 + la) * 136 + ks * 32 + g * 8];
            acc = __builtin_amdgcn_mfma_f32_16x16x32_bf16(af[ks], bf, acc, 0, 0, 0);
        }
        int col = co + ct * 16 + la;
        float bv = 0.f;
        if constexpr (BIASF) bv = bias[col];
        #pragma unroll
        for (int r = 0; r < 4; ++r) {
            int row = rb + roww * 16 + g * 4 + r;
            float v = acc[r] + bv;
            if constexpr (SCL)  v *= BN_S;
            if constexpr (ACT)  v = gelu_f(v);
            if constexpr (QSCL) v *= ATT_SCALE;
            if constexpr (OUTBF) ((unsigned short*)outv)[(size_t)row * NOT + col] = f2bf(v);
            else                 ((float*)outv)[(size_t)row * NOT + col] = v;
        }
    }
}

// ---------- fused attn-out projection (+residual) + LN-MLP ----------
__global__ __launch_bounds__(256)
void k_projmlp(const float* __restrict__ Ain, const unsigned short* __restrict__ pwb,
               const float* __restrict__ pb, const float* __restrict__ resid,
               const unsigned short* __restrict__ w1b, const float* __restrict__ b1,
               const unsigned short* __restrict__ w2b, const float* __restrict__ b2,
               float* __restrict__ out) {
    __shared__ unsigned short Al[16 * 136];
    __shared__ unsigned short Wl[128 * 72];
    __shared__ unsigned short Gl[16 * 264];
    __shared__ float Xf[16 * 132];
    const int t = threadIdx.x;
    const int rb = blockIdx.x * 16;
    const int lane = t & 63, wv = t >> 6;
    const int la = lane & 15, g = lane >> 4;

    {
        int r = t >> 4, seg = t & 15;
        const float* ar = Ain + (size_t)(rb + r) * 128 + seg * 8;
        float v[8];
        *(float4*)&v[0] = *(const float4*)&ar[0];
        *(float4*)&v[4] = *(const float4*)&ar[4];
        u16x8 o;
        #pragma unroll
        for (int jj = 0; jj < 8; ++jj) o[jj] = f2bf(v[jj]);
        *(u16x8*)&Al[r * 136 + seg * 8] = o;
    }
    __syncthreads();

    f32x4 acc2[2];
    acc2[0] = (f32x4){0.f, 0.f, 0.f, 0.f};
    acc2[1] = (f32x4){0.f, 0.f, 0.f, 0.f};
    #pragma unroll 1
    for (int kc = 0; kc < 2; ++kc) {
        if (kc) __syncthreads();
        {
            int c = t >> 1, s2 = t & 1;
            const unsigned short* wr = pwb + (size_t)c * 128 + kc * 64 + s2 * 32;
            #pragma unroll
            for (int j8 = 0; j8 < 4; ++j8)
                *(u16x8*)&Wl[c * 72 + s2 * 32 + 8 * j8] = *(const u16x8*)&wr[8 * j8];
        }
        __syncthreads();
        #pragma unroll
        for (int half = 0; half < 2; ++half) {
            short8 pf = *(short8*)&Al[la * 136 + kc * 64 + half * 32 + g * 8];
            #pragma unroll
            for (int ct = 0; ct < 2; ++ct) {
                short8 bf = *(short8*)&Wl[((wv * 2 + ct) * 16 + la) * 72 + half * 32 + g * 8];
                acc2[ct] = __builtin_amdgcn_mfma_f32_16x16x32_bf16(pf, bf, acc2[ct], 0, 0, 0);
            }
        }
    }
    __syncthreads();
    #pragma unroll
    for (int ct = 0; ct < 2; ++ct) {
        int col = (wv * 2 + ct) * 16 + la;
        float bv = pb[col];
        #pragma unroll
        for (int r = 0; r < 4; ++r) {
            int row = g * 4 + r;
            Xf[row * 132 + col] = acc2[ct][r] + bv
                                + resid[(size_t)(rb + row) * 128 + col];
        }
    }
    __syncthreads();

    {
        int r = t >> 4, seg = t & 15;
        float v[8];
        #pragma unroll
        for (int jj = 0; jj < 8; ++jj) v[jj] = Xf[r * 132 + seg * 8 + jj];
        float s = 0.f;
        #pragma unroll
        for (int jj = 0; jj < 8; ++jj) s += v[jj];
        s += __shfl_xor(s, 1); s += __shfl_xor(s, 2);
        s += __shfl_xor(s, 4); s += __shfl_xor(s, 8);
        float mu = s * (1.0f / 128.0f);
        float ss = 0.f;
        #pragma unroll
        for (int jj = 0; jj < 8; ++jj) { float d = v[jj] - mu; ss += d * d; }
        ss += __shfl_xor(ss, 1); ss += __shfl_xor(ss, 2);
        ss += __shfl_xor(ss, 4); ss += __shfl_xor(ss, 8);
        float rs = rsqrtf(ss * (1.0f / 128.0f) + LN_EPS);
        u16x8 o;
        #pragma unroll
        for (int jj = 0; jj < 8; ++jj) o[jj] = f2bf((v[jj] - mu) * rs);
        *(u16x8*)&Al[r * 136 + seg * 8] = o;
    }
    __syncthreads();

    short8 af[4];
    #pragma unroll
    for (int ks = 0; ks < 4; ++ks)
        af[ks] = *(short8*)&Al[la * 136 + ks * 32 + g * 8];

    #pragma unroll 1
    for (int cc = 0; cc < 4; ++cc) {
        {
            int c = t >> 2, s2 = t & 3;
            const unsigned short* wr = w1b + (size_t)(cc * 64 + c) * 128 + s2 * 32;
            #pragma unroll
            for (int j8 = 0; j8 < 4; ++j8)
                *(u16x8*)&Wl[c * 136 + s2 * 32 + 8 * j8] = *(const u16x8*)&wr[8 * j8];
        }
        __syncthreads();
        f32x4 acc = (f32x4){0.f, 0.f, 0.f, 0.f};
        #pragma unroll
        for (int ks = 0; ks < 4; ++ks) {
            short8 bf = *(short8*)&Wl[(wv * 16 + la) * 136 + ks * 32 + g * 8];
            acc = __builtin_amdgcn_mfma_f32_16x16x32_bf16(af[ks], bf, acc, 0, 0, 0);
        }
        int col = cc * 64 + wv * 16 + la;
        float bv = b1[col];
        #pragma unroll
        for (int r = 0; r < 4; ++r)
            Gl[(g * 4 + r) * 264 + col] = f2bf(gelu_f(acc[r] + bv));
        __syncthreads();
    }

    acc2[0] = (f32x4){0.f, 0.f, 0.f, 0.f};
    acc2[1] = (f32x4){0.f, 0.f, 0.f, 0.f};
    #pragma unroll 1
    for (int kc = 0; kc < 4; ++kc) {
        {
            int c = t >> 1, s2 = t & 1;
            const unsigned short* wr = w2b + (size_t)c * 256 + kc * 64 + s2 * 32;
            #pragma unroll
            for (int j8 = 0; j8 < 4; ++j8)
                *(u16x8*)&Wl[c * 72 + s2 * 32 + 8 * j8] = *(const u16x8*)&wr[8 * j8];
        }
        __syncthreads();
        #pragma unroll
        for (int half = 0; half < 2; ++half) {
            short8 pf = *(short8*)&Gl[la * 264 + kc * 64 + half * 32 + g * 8];
            #pragma unroll
            for (int ct = 0; ct < 2; ++ct) {
                short8 bf = *(short8*)&Wl[((wv * 2 + ct) * 16 + la) * 72 + half * 32 + g * 8];
                acc2[ct] = __builtin_amdgcn_mfma_f32_16x16x32_bf16(pf, bf, acc2[ct], 0, 0, 0);
            }
        }
        __syncthreads();
    }
    #pragma unroll
    for (int ct = 0; ct < 2; ++ct) {
        int col = (wv * 2 + ct) * 16 + la;
        float bv = b2[col];
        #pragma unroll
        for (int r = 0; r < 4; ++r) {
            int row = g * 4 + r;
            out[(size_t)(rb + row) * 128 + col] = acc2[ct][r] + bv + Xf[row * 132 + col];
        }
    }
}

// ---------- fused mbproj(+SE,+zln) -> pm-FFN -> proj_out (gelu, transposed) ----------
__global__ __launch_bounds__(256)
void k_mbprojmlp(const float* __restrict__ dwo, const unsigned short* __restrict__ mbpwb,
                 const float* __restrict__ se, const float* __restrict__ zln,
                 const unsigned short* __restrict__ w1b, const float* __restrict__ b1,
                 const unsigned short* __restrict__ w2b, const float* __restrict__ b2,
                 const unsigned short* __restrict__ pob, const float* __restrict__ pb,
                 float* __restrict__ out) {
    __shared__ unsigned short Al[16 * 136];
    __shared__ unsigned short Wl[128 * 72];
    __shared__ unsigned short Gl[16 * 264];
    __shared__ float Xf[16 * 132];
    const int t = threadIdx.x;
    const int rb = blockIdx.x * 16;
    const int lane = t & 63, wv = t >> 6;
    const int la = lane & 15, g = lane >> 4;

    f32x4 acc2[2];
    acc2[0] = (f32x4){0.f, 0.f, 0.f, 0.f};
    acc2[1] = (f32x4){0.f, 0.f, 0.f, 0.f};
    #pragma unroll 1
    for (int kc = 0; kc < 8; ++kc) {
        if (kc) __syncthreads();
        {
            int r = t >> 4, seg = t & 15;
            const float* ar = dwo + (size_t)(rb + r) * 512 + kc * 64 + seg * 4;
            float4 v = *(const float4*)ar;
            const float* sp = se + kc * 64 + seg * 4;
            v.x *= sp[0]; v.y *= sp[1]; v.z *= sp[2]; v.w *= sp[3];
            unsigned short* dst = &Al[r * 136 + seg * 4];
            dst[0] = f2bf(v.x); dst[1] = f2bf(v.y);
            dst[2] = f2bf(v.z); dst[3] = f2bf(v.w);
        }
        {
            int c = t >> 1, s2 = t & 1;
            const unsigned short* wr = mbpwb + (size_t)c * 512 + kc * 64 + s2 * 32;
            #pragma unroll
            for (int j8 = 0; j8 < 4; ++j8)
                *(u16x8*)&Wl[c * 72 + s2 * 32 + 8 * j8] = *(const u16x8*)&wr[8 * j8];
        }
        __syncthreads();
        #pragma unroll
        for (int half = 0; half < 2; ++half) {
            short8 pf = *(short8*)&Al[la * 136 + half * 32 + g * 8];
            #pragma unroll
            for (int ct = 0; ct < 2; ++ct) {
                short8 bf = *(short8*)&Wl[((wv * 2 + ct) * 16 + la) * 72 + half * 32 + g * 8];
                acc2[ct] = __builtin_amdgcn_mfma_f32_16x16x32_bf16(pf, bf, acc2[ct], 0, 0, 0);
            }
        }
    }
    __syncthreads();
    #pragma unroll
    for (int ct = 0; ct < 2; ++ct) {
        int col = (wv * 2 + ct) * 16 + la;
        #pragma unroll
        for (int r = 0; r < 4; ++r) {
            int row = g * 4 + r;
            Xf[row * 132 + col] = acc2[ct][r] * BN_S
                                + zln[(size_t)(rb + row) * 128 + col];
        }
    }
    __syncthreads();

    {
        int r = t >> 4, seg = t & 15;
        u16x8 o;
        #pragma unroll
        for (int jj = 0; jj < 8; ++jj) o[jj] = f2bf(Xf[r * 132 + seg * 8 + jj]);
        *(u16x8*)&Al[r * 136 + seg * 8] = o;
    }
    __syncthreads();

    short8 af[4];
    #pragma unroll
    for (int ks = 0; ks < 4; ++ks)
        af[ks] = *(short8*)&Al[la * 136 + ks * 32 + g * 8];

    #pragma unroll 1
    for (int cc = 0; cc < 4; ++cc) {
        {
            int c = t >> 2, s2 = t & 3;
            const unsigned short* wr = w1b + (size_t)(cc * 64 + c) * 128 + s2 * 32;
            #pragma unroll
            for (int j8 = 0; j8 < 4; ++j8)
                *(u16x8*)&Wl[c * 136 + s2 * 32 + 8 * j8] = *(const u16x8*)&wr[8 * j8];
        }
        __syncthreads();
        f32x4 acc = (f32x4){0.f, 0.f, 0.f, 0.f};
        #pragma unroll
        for (int ks = 0; ks < 4; ++ks) {
            short8 bf = *(short8*)&Wl[(wv * 16 + la) * 136 + ks * 32 + g * 8];
            acc = __builtin_amdgcn_mfma_f32_16x16x32_bf16(af[ks], bf, acc, 0, 0, 0);
        }
        int col = cc * 64 + wv * 16 + la;
        float bv = b1[col];
        #pragma unroll
        for (int r = 0; r < 4; ++r)
            Gl[(g * 4 + r) * 264 + col] = f2bf(gelu_f(acc[r] + bv));
        __syncthreads();
    }

    acc2[0] = (f32x4){0.f, 0.f, 0.f, 0.f};
    acc2[1] = (f32x4){0.f, 0.f, 0.f, 0.f};
    #pragma unroll 1
    for (int kc = 0; kc < 4; ++kc) {
        {
            int c = t >> 1, s2 = t & 1;
            const unsigned short* wr = w2b + (size_t)c * 256 + kc * 64 + s2 * 32;
            #pragma unroll
            for (int j8 = 0; j8 < 4; ++j8)
                *(u16x8*)&Wl[c * 72 + s2 * 32 + 8 * j8] = *(const u16x8*)&wr[8 * j8];
        }
        __syncthreads();
        #pragma unroll
        for (int half = 0; half < 2; ++half) {
            short8 pf = *(short8*)&Gl[la * 264 + kc * 64 + half * 32 + g * 8];
            #pragma unroll
            for (int ct = 0; ct < 2; ++ct) {
                short8 bf = *(short8*)&Wl[((wv * 2 + ct) * 16 + la) * 72 + half * 32 + g * 8];
                acc2[ct] = __builtin_amdgcn_mfma_f32_16x16x32_bf16(pf, bf, acc2[ct], 0, 0, 0);
            }
        }
        __syncthreads();
    }
    #pragma unroll
    for (int ct = 0; ct < 2; ++ct) {
        int col = (wv * 2 + ct) * 16 + la;
        float bv = b2[col];
        #pragma unroll
        for (int r = 0; r < 4; ++r) {
            int row = g * 4 + r;
            float y = acc2[ct][r] + bv + Xf[row * 132 + col];
            Al[row * 136 + col] = f2bf(y);
        }
    }
    __syncthreads();

    f32x4 acc3[2];
    acc3[0] = (f32x4){0.f, 0.f, 0.f, 0.f};
    acc3[1] = (f32x4){0.f, 0.f, 0.f, 0.f};
    #pragma unroll 1
    for (int kc = 0; kc < 2; ++kc) {
        if (kc) __syncthreads();
        {
            int c = t >> 1, s2 = t & 1;
            const unsigned short* wr = pob + (size_t)c * 128 + kc * 64 + s2 * 32;
            #pragma unroll
            for (int j8 = 0; j8 < 4; ++j8)
                *(u16x8*)&Wl[c * 72 + s2 * 32 + 8 * j8] = *(const u16x8*)&wr[8 * j8];
        }
        __syncthreads();
        #pragma unroll
        for (int half = 0; half < 2; ++half) {
            short8 pf = *(short8*)&Al[la * 136 + kc * 64 + half * 32 + g * 8];
            #pragma unroll
            for (int ct = 0; ct < 2; ++ct) {
                short8 bf = *(short8*)&Wl[((wv * 2 + ct) * 16 + la) * 72 + half * 32 + g * 8];
                acc3[ct] = __builtin_amdgcn_mfma_f32_16x16x32_bf16(pf, bf, acc3[ct], 0, 0, 0);
            }
        }
    }
    #pragma unroll
    for (int ct = 0; ct < 2; ++ct) {
        int col = (wv * 2 + ct) * 16 + la;
        float bv = pb[col];
        float4 o4;
        o4.x = gelu_f(acc3[ct][0] + bv);
        o4.y = gelu_f(acc3[ct][1] + bv);
        o4.z = gelu_f(acc3[ct][2] + bv);
        o4.w = gelu_f(acc3[ct][3] + bv);
        *(float4*)&out[(size_t)col * PBEV + rb + g * 4] = o4;
    }
}

// ---------- MFMA flash attention (S^T trick; MODE1 fuses the 6-view mean) ----------
template<int MODE>
__global__ __launch_bounds__(MODE == 1 ? 512 : 256)
void k_attn_mfma(const unsigned short* __restrict__ qh, const unsigned short* __restrict__ kh,
                 const unsigned short* __restrict__ vh, float* __restrict__ aout) {
    constexpr int WAVES = (MODE == 1) ? 8 : 4;
    constexpr int QTPW  = (MODE == 1) ? 3 : 1;
    constexpr int T = WAVES * 64;
    const int l = blockIdx.x, m = blockIdx.y;
    const int xw = l >> 3, yw = l & 7;
    const int t = threadIdx.x;
    const int lane = t & 63, wv = t >> 6;
    const int la = lane & 15, g = lane >> 4;

    __shared__ unsigned short Kl[KROWS * 40];
    __shared__ unsigned short Vt[32 * 312];
    __shared__ float Ol[64 * 33];   // MODE1 mean accumulator

    if constexpr (MODE == 1) {
        for (int i = t; i < 64 * 33; i += T) Ol[i] = 0.f;
    }

    for (int i = t; i < KROWS * 4; i += T) {
        int row = i >> 2, seg = i & 3;
        int n = row / 48, kk = row % 48;
        int k1 = kk / 12, k2 = kk % 12;
        int h, w;
        if (MODE == 1) { h = xw * 4 + k1;  w = yw * 12 + k2; }
        else           { h = k1 * 8 + xw;  w = k2 * 8 + yw;  }
        size_t src = ((size_t)(n * PIMG + h * FWW + w)) * 128 + m * DHD + seg * 8;
        short8 kv = *(const short8*)&kh[src];
        *(short8*)&Kl[row * 40 + seg * 8] = kv;
        short8 vv = *(const short8*)&vh[src];
        #pragma unroll
        for (int j = 0; j < 8; ++j)
            Vt[(seg * 8 + j) * 312 + row] = (unsigned short)vv[j];
    }

    short8 qf[QTPW];
    #pragma unroll
    for (int qt = 0; qt < QTPW; ++qt) {
        int q = (wv * QTPW + qt) * 16 + la;
        int row;
        if (MODE == 1) {
            int n = q >> 6, ww = q & 63;
            row = n * PBEV + (xw * 8 + (ww >> 3)) * 64 + yw * 8 + (ww & 7);
        } else {
            row = ((q >> 3) * 8 + xw) * 64 + (q & 7) * 8 + yw;
        }
        qf[qt] = *(const short8*)&qh[(size_t)row * 128 + m * DHD + g * 8];
    }
    __syncthreads();

    f32x4 acc[QTPW][2];
    float srow[QTPW];
    #pragma unroll
    for (int qt = 0; qt < QTPW; ++qt) {
        acc[qt][0] = (f32x4){0.f, 0.f, 0.f, 0.f};
        acc[qt][1] = (f32x4){0.f, 0.f, 0.f, 0.f};
        srow[qt] = 0.f;
    }
    const int a0 = la + 32 * (g & 1);
    const int a1 = a0 + 16;
    const bool selA = (g < 2);

    #pragma unroll 1
    for (int c = 0; c < 9; ++c) {
        const int kk0 = c * 32;
        short8 kf0 = *(short8*)&Kl[(kk0 + la) * 40 + g * 8];
        short8 kf1 = *(short8*)&Kl[(kk0 + 16 + la) * 40 + g * 8];
        short8 vf0 = *(short8*)&Vt[la * 312 + kk0 + g * 8];
        short8 vf1 = *(short8*)&Vt[(16 + la) * 312 + kk0 + g * 8];
        #pragma unroll
        for (int qt = 0; qt < QTPW; ++qt) {
            f32x4 sA = __builtin_amdgcn_mfma_f32_16x16x32_bf16(kf0, qf[qt], (f32x4){0.f,0.f,0.f,0.f}, 0, 0, 0);
            f32x4 sB = __builtin_amdgcn_mfma_f32_16x16x32_bf16(kf1, qf[qt], (f32x4){0.f,0.f,0.f,0.f}, 0, 0, 0);
            float pA[4], pB[4];
            #pragma unroll
            for (int r = 0; r < 4; ++r) { pA[r] = __expf(sA[r]); pB[r] = __expf(sB[r]); }
            srow[qt] += ((pA[0] + pA[1]) + (pA[2] + pA[3]))
                      + ((pB[0] + pB[1]) + (pB[2] + pB[3]));
            unsigned int loA = (unsigned int)f2bf(pA[0]) | ((unsigned int)f2bf(pA[1]) << 16);
            unsigned int hiA = (unsigned int)f2bf(pA[2]) | ((unsigned int)f2bf(pA[3]) << 16);
            unsigned int loB = (unsigned int)f2bf(pB[0]) | ((unsigned int)f2bf(pB[1]) << 16);
            unsigned int hiB = (unsigned int)f2bf(pB[2]) | ((unsigned int)f2bf(pB[3]) << 16);
            int w0A = __shfl((int)loA, a0); int w0B = __shfl((int)loB, a0);
            int w1A = __shfl((int)hiA, a0); int w1B = __shfl((int)hiB, a0);
            int w2A = __shfl((int)loA, a1); int w2B = __shfl((int)loB, a1);
            int w3A = __shfl((int)hiA, a1); int w3B = __shfl((int)hiB, a1);
            union { int u[4]; short8 s; } pu;
            pu.u[0] = selA ? w0A : w0B;
            pu.u[1] = selA ? w1A : w1B;
            pu.u[2] = selA ? w2A : w2B;
            pu.u[3] = selA ? w3A : w3B;
            acc[qt][0] = __builtin_amdgcn_mfma_f32_16x16x32_bf16(pu.s, vf0, acc[qt][0], 0, 0, 0);
            acc[qt][1] = __builtin_amdgcn_mfma_f32_16x16x32_bf16(pu.s, vf1, acc[qt][1], 0, 0, 0);
        }
    }

    if constexpr (MODE == 1) {
        #pragma unroll
        for (int qt = 0; qt < QTPW; ++qt) {
            float s = srow[qt];
            s += __shfl_xor(s, 16);
            s += __shfl_xor(s, 32);
            #pragma unroll
            for (int r = 0; r < 4; ++r) {
                float sq = __shfl(s, g * 4 + r);
                float inv = 1.0f / (6.0f * sq);
                int q = (wv * QTPW + qt) * 16 + g * 4 + r;
                int ww = q & 63;
                atomicAdd(&Ol[ww * 33 + la],      acc[qt][0][r] * inv);
                atomicAdd(&Ol[ww * 33 + 16 + la], acc[qt][1][r] * inv);
            }
        }
        __syncthreads();
        for (int i = t; i < 2048; i += T) {
            int ww = i >> 5, col = i & 31;
            int h = xw * 8 + (ww >> 3), w = yw * 8 + (ww & 7);
            aout[(size_t)(h * 64 + w) * 128 + m * 32 + col] = Ol[ww * 33 + col];
        }
    } else {
        #pragma unroll
        for (int qt = 0; qt < QTPW; ++qt) {
            float s = srow[qt];
            s += __shfl_xor(s, 16);
            s += __shfl_xor(s, 32);
            #pragma unroll
            for (int r = 0; r < 4; ++r) {
                float sq = __shfl(s, g * 4 + r);
                float inv = 1.0f / sq;
                int q = (wv * QTPW + qt) * 16 + g * 4 + r;
                size_t orow = (size_t)(((q >> 3) * 8 + xw) * 64 + (q & 7) * 8 + yw);
                float* ap = aout + orow * 128 + m * DHD;
                ap[la]      = acc[qt][0][r] * inv;
                ap[16 + la] = acc[qt][1][r] * inv;
            }
        }
    }
}

// ---------- depthwise 3x3 + gelu + SE partials ----------
__global__ void k_dwconv(const float* __restrict__ ex, const float* __restrict__ dwgt,
                         float* __restrict__ dwout, float* __restrict__ separt) {
    const int TILE = 16;
    int ch = threadIdx.x;
    int hw0 = blockIdx.x * TILE;
    float wreg[9];
    #pragma unroll
    for (int i = 0; i < 9; ++i) wreg[i] = dwgt[ch * 9 + i];
    float sacc = 0.f;
    for (int ti = 0; ti < TILE; ++ti) {
        int hw = hw0 + ti;
        int h = hw >> 6, w = hw & 63;
        float s = 0.f;
        #pragma unroll
        for (int dy = -1; dy <= 1; ++dy) {
            int h2 = h + dy;
            if (h2 < 0 || h2 >= 64) continue;
            #pragma unroll
            for (int dx = -1; dx <= 1; ++dx) {
                int w2 = w + dx;
                if (w2 < 0 || w2 >= 64) continue;
                s += ex[((size_t)(h2 * 64 + w2)) * 512 + ch] * wreg[(dy + 1) * 3 + (dx + 1)];
            }
        }
        float o = gelu_f(s * BN_S);
        dwout[(size_t)hw * 512 + ch] = o;
        sacc += o;
    }
    separt[(size_t)blockIdx.x * 512 + ch] = sacc;
}

// ---------- SE (reduce 256 partials + 2 matvecs) ----------
__global__ void k_se(const float* __restrict__ separt,
                     const float* __restrict__ s1w, const float* __restrict__ s1b,
                     const float* __restrict__ s2w, const float* __restrict__ s2b,
                     float* __restrict__ se) {
    __shared__ float mean[512];
    __shared__ float s1[32];
    int t = threadIdx.x;
    float s = 0.f;
    #pragma unroll 8
    for (int b = 0; b < 256; ++b) s += separt[(size_t)b * 512 + t];
    mean[t] = s * (1.0f / 4096.0f);
    __syncthreads();
    int u = t >> 4, seg = t & 15;
    float acc = 0.f;
    #pragma unroll
    for (int j = 0; j < 32; ++j) {
        int c = seg + 16 * j;
        acc += mean[c] * s1w[u * 512 + c];
    }
    acc += __shfl_xor(acc, 1); acc += __shfl_xor(acc, 2);
    acc += __shfl_xor(acc, 4); acc += __shfl_xor(acc, 8);
    if (seg == 0) s1[u] = gelu_f(acc + s1b[u]);
    __syncthreads();
    float a2 = s2b[t];
    #pragma unroll
    for (int j = 0; j < 32; ++j) a2 += s1[j] * s2w[t * 32 + j];
    se[t] = 1.0f / (1.0f + __expf(-a2));
}

extern "C" void kernel_launch(void* const* d_in, const int* in_sizes, int n_in,
                              void* d_out, int out_size, void* d_ws, size_t ws_size,
                              hipStream_t stream) {
    (void)in_sizes; (void)n_in; (void)out_size; (void)ws_size;
    const float* x      = (const float*)d_in[1];
    const float* feat   = (const float*)d_in[2];
    const float* I_inv  = (const float*)d_in[3];
    const float* E_inv  = (const float*)d_in[4];
    const float* bev    = (const float*)d_in[5];
    const float* fl_w   = (const float*)d_in[6];
    const float* fp_w   = (const float*)d_in[7];
    const float* be_w   = (const float*)d_in[8];
    const float* be_b   = (const float*)d_in[9];
    const float* ie_w   = (const float*)d_in[10];
    const float* ce_w   = (const float*)d_in[11];
    const float* a1_qw  = (const float*)d_in[12];
    const float* a1_qb  = (const float*)d_in[13];
    const float* a1_kw  = (const float*)d_in[14];
    const float* a1_kb  = (const float*)d_in[15];
    const float* a1_vw  = (const float*)d_in[16];
    const float* a1_vb  = (const float*)d_in[17];
    const float* a1_pw  = (const float*)d_in[18];
    const float* a1_pb  = (const float*)d_in[19];
    const float* a2_qw  = (const float*)d_in[20];
    const float* a2_qb  = (const float*)d_in[21];
    const float* a2_kw  = (const float*)d_in[22];
    const float* a2_kb  = (const float*)d_in[23];
    const float* a2_vw  = (const float*)d_in[24];
    const float* a2_vb  = (const float*)d_in[25];
    const float* a2_pw  = (const float*)d_in[26];
    const float* a2_pb  = (const float*)d_in[27];
    const float* m1_w1  = (const float*)d_in[28];
    const float* m1_b1  = (const float*)d_in[29];
    const float* m1_w2  = (const float*)d_in[30];
    const float* m1_b2  = (const float*)d_in[31];
    const float* m2_w1  = (const float*)d_in[32];
    const float* m2_b1  = (const float*)d_in[33];
    const float* m2_w2  = (const float*)d_in[34];
    const float* m2_b2  = (const float*)d_in[35];
    const float* mb_ew  = (const float*)d_in[36];
    const float* mb_dw  = (const float*)d_in[37];
    const float* mb_s1w = (const float*)d_in[38];
    const float* mb_s1b = (const float*)d_in[39];
    const float* mb_s2w = (const float*)d_in[40];
    const float* mb_s2b = (const float*)d_in[41];
    const float* mb_pw  = (const float*)d_in[42];
    const float* pm_w1  = (const float*)d_in[43];
    const float* pm_b1  = (const float*)d_in[44];
    const float* pm_w2  = (const float*)d_in[45];
    const float* pm_b2  = (const float*)d_in[46];
    const float* po_w   = (const float*)d_in[47];
    const float* po_b   = (const float*)d_in[48];

    float* ws = (float*)d_ws;
    float* x_cl = ws + 0;                                      // 524288
    unsigned short* qh1b = (unsigned short*)(ws + 524288);     // 1572864 f
    unsigned short* kh1b = (unsigned short*)(ws + 2097152);    // 1179648 f
    unsigned short* vh1b = (unsigned short*)(ws + 3276800);
    unsigned short* kh2b = (unsigned short*)(ws + 4456448);
    unsigned short* vh2b = (unsigned short*)(ws + 5636096);
    float* amean  = ws + 6815744;    // 524288
    float* qimg   = ws + 7340032;
    float* qimg2  = ws + 7864320;
    float* zln    = ws + 8388608;
    float* abuf2  = ws + 8912896;
    float* expandb = ws + 9437184;   // 2097152
    float* dwout   = ws + 11534336;  // 2097152
    float* separt  = ws + 13631488;  // 131072
    float* sebuf   = ws + 13762560;  // 512
    unsigned short* wb = (unsigned short*)(ws + 13763072);     // 507904 u16
    unsigned short* qh2b = qh1b;

    // prep: weights -> bf16 arena, x transpose
    k_prep<<<760, 256, 0, stream>>>(fp_w, fl_w, a1_qw, a1_kw, a2_kw, a1_vw, a2_vw,
                                    a1_pw, m1_w1, m1_w2, a2_qw, a2_pw, m2_w1, m2_w2,
                                    mb_ew, mb_pw, pm_w1, pm_w2, po_w, wb, x, x_cl);

    // mega key/val: feature GEMM + embed + LN + 4 head GEMMs
    k_keyval<<<288, 256, 0, stream>>>(feat, wb, ie_w, ce_w, I_inv, E_inv,
                                      a1_kb, a2_kb, a1_vb, a2_vb,
                                      kh1b, kh2b, vh1b, vh2b);

    // q head (query gen fused, pre-scaled by ATT_SCALE)
    k_gemm_mfma<64,128,3, 1,1,0,0, 1,1,0><<<384, 256, 0, stream>>>(
        nullptr, wb + OFF_A1QW, a1_qb, bev, x_cl, be_w, be_b, E_inv, ce_w,
        nullptr, qh1b);
    k_attn_mfma<1><<<dim3(64, HEADS), 512, 0, stream>>>(qh1b, kh1b, vh1b, amean);
    k_projmlp<<<256, 256, 0, stream>>>(amean, wb + OFF_A1PW, a1_pb, x_cl,
                                       wb + OFF_M1W1, m1_b1, wb + OFF_M1W2, m1_b2, qimg);

    // stage 2
    k_gemm_mfma<16,128,0, 1,1,0,0, 1,1,0><<<256, 256, 0, stream>>>(
        qimg, wb + OFF_A2QW, a2_qb, nullptr, nullptr, nullptr, nullptr, nullptr,
        nullptr, nullptr, qh2b);
    k_attn_mfma<2><<<dim3(64, HEADS), 256, 0, stream>>>(qh2b, kh2b, vh2b, abuf2);
    k_projmlp<<<256, 256, 0, stream>>>(abuf2, wb + OFF_A2PW, a2_pb, qimg,
                                       wb + OFF_M2W1, m2_b1, wb + OFF_M2W2, m2_b2, qimg2);

    // stage 3
    k_gemm_mfma<16,512,0, 1,0,1,1, 0,0,1><<<dim3(256, 4), 256, 0, stream>>>(
        qimg2, wb + OFF_MBEW, nullptr, nullptr, nullptr, nullptr, nullptr, nullptr,
        nullptr, zln, expandb);
    k_dwconv<<<256, 512, 0, stream>>>(expandb, mb_dw, dwout, separt);
    k_se<<<1, 512, 0, stream>>>(separt, mb_s1w, mb_s1b, mb_s2w, mb_s2b, sebuf);
    k_mbprojmlp<<<256, 256, 0, stream>>>(dwout, wb + OFF_MBPW, sebuf, zln,
                                         wb + OFF_PMW1, pm_b1, wb + OFF_PMW2, pm_b2,
                                         wb + OFF_POW, po_b, (float*)d_out);
}

// Round 13
// 154.705 us; speedup vs baseline: 1.1176x; 1.1176x over previous
//
#include <hip/hip_runtime.h>
#include <math.h>

#define NV 6
#define FHH 32
#define FWW 96
#define PIMG (FHH*FWW)   // 3072
#define HH 64
#define WWD 64
#define PBEV (HH*WWD)    // 4096
#define HEADS 4
#define DHD 32
#define KROWS 288
#define BN_S 0.9999950000374996f
#define LN_EPS 1e-5f
#define ATT_SCALE 0.17677669529663687f  // 32^-0.5

typedef __attribute__((ext_vector_type(8))) short short8;
typedef __attribute__((ext_vector_type(4))) float f32x4;
typedef __attribute__((ext_vector_type(8))) unsigned short u16x8;

__device__ __forceinline__ float gelu_f(float x) {
    return 0.5f * x * (1.0f + erff(x * 0.70710678118654752f));
}

__device__ __forceinline__ unsigned short f2bf(float f) {
    union { float f; unsigned int u; } c; c.f = f;
    unsigned int r = (c.u + 0x7fffu + ((c.u >> 16) & 1u)) >> 16;
    return (unsigned short)r;
}

// bf16 weight arena offsets (u16 elements)
#define OFF_FP    0
#define OFF_FL    16384
#define OFF_A1QW  32768
#define OFF_A1KW  49152
#define OFF_A2KW  65536
#define OFF_A1VW  81920
#define OFF_A2VW  98304
#define OFF_A1PW  114688
#define OFF_M1W1  131072
#define OFF_M1W2  163840
#define OFF_A2QW  196608
#define OFF_A2PW  212992
#define OFF_M2W1  229376
#define OFF_M2W2  262144
#define OFF_MBEW  294912
#define OFF_MBPW  360448
#define OFF_PMW1  425984
#define OFF_PMW2  458752
#define OFF_POW   491520
#define WTOTAL    507904

// ---------- weight f32 -> bf16 arena ----------
__global__ void k_cvtw(const float* p0, const float* p1, const float* p2,
                       const float* p3, const float* p4, const float* p5,
                       const float* p6, const float* p7, const float* p8,
                       const float* p9, const float* p10, const float* p11,
                       const float* p12, const float* p13, const float* p14,
                       const float* p15, const float* p16, const float* p17,
                       const float* p18, unsigned short* wb) {
    int idx = (blockIdx.x * 256 + threadIdx.x) * 8;
    if (idx >= WTOTAL) return;
    const float* s;
    if      (idx < OFF_FL)   s = p0  + idx;
    else if (idx < OFF_A1QW) s = p1  + (idx - OFF_FL);
    else if (idx < OFF_A1KW) s = p2  + (idx - OFF_A1QW);
    else if (idx < OFF_A2KW) s = p3  + (idx - OFF_A1KW);
    else if (idx < OFF_A1VW) s = p4  + (idx - OFF_A2KW);
    else if (idx < OFF_A2VW) s = p5  + (idx - OFF_A1VW);
    else if (idx < OFF_A1PW) s = p6  + (idx - OFF_A2VW);
    else if (idx < OFF_M1W1) s = p7  + (idx - OFF_A1PW);
    else if (idx < OFF_M1W2) s = p8  + (idx - OFF_M1W1);
    else if (idx < OFF_A2QW) s = p9  + (idx - OFF_M1W2);
    else if (idx < OFF_A2PW) s = p10 + (idx - OFF_A2QW);
    else if (idx < OFF_M2W1) s = p11 + (idx - OFF_A2PW);
    else if (idx < OFF_M2W2) s = p12 + (idx - OFF_M2W1);
    else if (idx < OFF_MBEW) s = p13 + (idx - OFF_M2W2);
    else if (idx < OFF_MBPW) s = p14 + (idx - OFF_MBEW);
    else if (idx < OFF_PMW1) s = p15 + (idx - OFF_MBPW);
    else if (idx < OFF_PMW2) s = p16 + (idx - OFF_PMW1);
    else if (idx < OFF_POW)  s = p17 + (idx - OFF_PMW2);
    else                     s = p18 + (idx - OFF_POW);
    float4 v0 = *(const float4*)&s[0];
    float4 v1 = *(const float4*)&s[4];
    u16x8 o = { f2bf(v0.x), f2bf(v0.y), f2bf(v0.z), f2bf(v0.w),
                f2bf(v1.x), f2bf(v1.y), f2bf(v1.z), f2bf(v1.w) };
    *(u16x8*)&wb[idx] = o;
}

// ---------- x transpose: [128][4096] -> [4096][128] ----------
__global__ void k_transx(const float* __restrict__ x, float* __restrict__ x_cl) {
    __shared__ float tile[32][33];
    int c0 = blockIdx.y * 32, p0 = blockIdx.x * 32;
    int tp = threadIdx.x & 31, tg = threadIdx.x >> 5;
    #pragma unroll
    for (int i = 0; i < 4; ++i)
        tile[tg + 8 * i][tp] = x[(size_t)(c0 + tg + 8 * i) * PBEV + p0 + tp];
    __syncthreads();
    #pragma unroll
    for (int i = 0; i < 4; ++i)
        x_cl[(size_t)(p0 + tg + 8 * i) * 128 + c0 + tp] = tile[tp][tg + 8 * i];
}

// ---------- universal MFMA GEMM ----------
template<int BR, int KCH, int NOT, int AMODE, int LNF, int BIASF, int ACT, int SCL,
         int ADDM, int STM, int ASCL, int DUAL, int OUTBF, int QSCL, int WRLN,
         int EMB, int WBF>
__global__ __launch_bounds__(256)
void k_gemm_mfma(const float* __restrict__ A, const float* __restrict__ W,
                 const float* __restrict__ bias, const float* __restrict__ addb,
                 const float* __restrict__ ascale, const float* __restrict__ W2,
                 const float* __restrict__ bias2, void* __restrict__ out2v,
                 float* __restrict__ aux, void* __restrict__ outv) {
    constexpr int NI = KCH * 128;
    constexpr int RW = BR / 16;
    constexpr int CT = 8 / (4 / RW);
    __shared__ unsigned short Al[BR * 136];
    __shared__ unsigned short Wl[128 * 136];
    const int t = threadIdx.x;
    const int rb = blockIdx.x * BR;
    const int co = blockIdx.y * 128;
    const int lane = t & 63, wv = t >> 6;
    const int la = lane & 15, g = lane >> 4;
    const int roww = wv % RW, colg = wv / RW;

    if constexpr (KCH == 1) {
        if constexpr (AMODE == 1) {
            int n = rb / PIMG, p0 = rb % PIMG;
            int r = t & 63, kseg = t >> 6;
            #pragma unroll
            for (int j8 = 0; j8 < 4; ++j8) {
                u16x8 o;
                #pragma unroll
                for (int j = 0; j < 8; ++j) {
                    int k = kseg * 32 + j8 * 8 + j;
                    float v = A[((size_t)(n * 128 + k)) * PIMG + p0 + r];
                    o[j] = f2bf(fmaxf(v * BN_S, 0.0f));
                }
                *(u16x8*)&Al[r * 136 + kseg * 32 + j8 * 8] = o;
            }
        } else {
            constexpr int TPR = 256 / BR;
            constexpr int CPT = 128 / TPR;
            int r = t / TPR, seg = t % TPR;
            float v[CPT];
            if constexpr (AMODE == 3) {
                int grow = rb + r;
                int n = grow >> 12, p = grow & 4095;
                const float* E = ((const float*)out2v) + n * 16;
                const float* cew = (const float*)aux;
                float bp0 = addb[p], bp1 = addb[PBEV + p];
                float ss = 0.f;
                #pragma unroll
                for (int j = 0; j < CPT; ++j) {
                    int c = seg * CPT + j;
                    float cemb = E[3]  * cew[c*4+0] + E[7]  * cew[c*4+1]
                               + E[11] * cew[c*4+2] + E[15] * cew[c*4+3];
                    float emb = bp0 * W2[c*2] + bp1 * W2[c*2+1] + bias2[c] - cemb;
                    v[j] = emb; ss += emb * emb;
                }
                #pragma unroll
                for (int o = 1; o < TPR; o <<= 1) ss += __shfl_xor(ss, o, 64);
                float invn = 1.0f / (sqrtf(ss) + 1e-7f);
                const float* xr = ascale + (size_t)p * 128 + seg * CPT;
                #pragma unroll
                for (int j = 0; j < CPT; ++j) v[j] = v[j] * invn + xr[j];
            } else {
                const float* ar = A + (size_t)(rb + r) * 128 + seg * CPT;
                #pragma unroll
                for (int j4 = 0; j4 < CPT / 4; ++j4)
                    *(float4*)&v[4 * j4] = *(const float4*)&ar[4 * j4];
            }
            if constexpr (LNF) {
                float s = 0.f;
                #pragma unroll
                for (int j = 0; j < CPT; ++j) s += v[j];
                #pragma unroll
                for (int o = 1; o < TPR; o <<= 1) s += __shfl_xor(s, o, 64);
                float mu = s * (1.0f / 128.0f);
                float ss = 0.f;
                #pragma unroll
                for (int j = 0; j < CPT; ++j) { float d = v[j] - mu; ss += d * d; }
                #pragma unroll
                for (int o = 1; o < TPR; o <<= 1) ss += __shfl_xor(ss, o, 64);
                float rs = rsqrtf(ss * (1.0f / 128.0f) + LN_EPS);
                #pragma unroll
                for (int j = 0; j < CPT; ++j) v[j] = (v[j] - mu) * rs;
                if constexpr (WRLN) {
                    if (blockIdx.y == 0) {
                        #pragma unroll
                        for (int j4 = 0; j4 < CPT / 4; ++j4) {
                            float4 o4 = {v[4*j4], v[4*j4+1], v[4*j4+2], v[4*j4+3]};
                            *(float4*)&aux[(size_t)(rb + r) * 128 + seg * CPT + 4 * j4] = o4;
                        }
                    }
                }
            }
            #pragma unroll
            for (int j8 = 0; j8 < CPT / 8; ++j8) {
                u16x8 o;
                #pragma unroll
                for (int j = 0; j < 8; ++j) o[j] = f2bf(v[8 * j8 + j]);
                *(u16x8*)&Al[r * 136 + seg * CPT + 8 * j8] = o;
            }
        }
    }

    #pragma unroll 1
    for (int set = 0; set <= DUAL; ++set) {
        const float* Wc = set ? W2 : W;
        const float* bc = set ? bias2 : bias;
        void* ocv = set ? out2v : outv;
        f32x4 acc[CT];
        #pragma unroll
        for (int i = 0; i < CT; ++i) acc[i] = (f32x4){0.f, 0.f, 0.f, 0.f};

        #pragma unroll 1
        for (int kc = 0; kc < KCH; ++kc) {
            if (set || kc) __syncthreads();
            #pragma unroll
            for (int i = 0; i < 8; ++i) {
                int chunk = i * 256 + t;
                int c = chunk >> 4, k8 = chunk & 15;
                if constexpr (WBF) {
                    const unsigned short* wr = ((const unsigned short*)Wc)
                        + (size_t)(co + c) * NI + kc * 128 + k8 * 8;
                    *(u16x8*)&Wl[c * 136 + k8 * 8] = *(const u16x8*)wr;
                } else {
                    const float* wr = &Wc[(size_t)(co + c) * NI + kc * 128 + k8 * 8];
                    float4 v0 = *(const float4*)&wr[0];
                    float4 v1 = *(const float4*)&wr[4];
                    u16x8 o = { f2bf(v0.x), f2bf(v0.y), f2bf(v0.z), f2bf(v0.w),
                                f2bf(v1.x), f2bf(v1.y), f2bf(v1.z), f2bf(v1.w) };
                    *(u16x8*)&Wl[c * 136 + k8 * 8] = o;
                }
            }
            __syncthreads();
            short8 af[4];
            #pragma unroll
            for (int ks = 0; ks < 4; ++ks)
                af[ks] = *(short8*)&Al[(roww * 16 + la) * 136 + ks * 32 + g * 8];
            #pragma unroll
            for (int cti = 0; cti < CT; ++cti) {
                int ct = colg * CT + cti;
                #pragma unroll
                for (int ks = 0; ks < 4; ++ks) {
                    short8 bf = *(short8*)&Wl[(ct * 16 + la) * 136 + ks * 32 + g * 8];
                    acc[cti] = __builtin_amdgcn_mfma_f32_16x16x32_bf16(af[ks], bf, acc[cti], 0, 0, 0);
                }
            }
        }

        float embv[CT][4];
        float invr[4];
        if constexpr (EMB) {
            if (set == 0) {
                int n = rb / PIMG;
                const float* Ii = ascale + n * 9;
                const float* E  = addb + n * 16;
                float d0[4], d1[4], d2[4], d3[4];
                #pragma unroll
                for (int r = 0; r < 4; ++r) {
                    int row = rb + roww * 16 + g * 4 + r;
                    int p = row % PIMG;
                    int hh = p / FWW, wp = p % FWW;
                    float gx = (float)wp * (768.0f / 95.0f);
                    float gy = (float)hh * (256.0f / 31.0f);
                    float c0 = Ii[0]*gx + Ii[1]*gy + Ii[2];
                    float c1 = Ii[3]*gx + Ii[4]*gy + Ii[5];
                    float c2 = Ii[6]*gx + Ii[7]*gy + Ii[8];
                    d0[r] = E[0]*c0  + E[1]*c1  + E[2]*c2  + E[3];
                    d1[r] = E[4]*c0  + E[5]*c1  + E[6]*c2  + E[7];
                    d2[r] = E[8]*c0  + E[9]*c1  + E[10]*c2 + E[11];
                    d3[r] = E[12]*c0 + E[13]*c1 + E[14]*c2 + E[15];
                }
                float ssr[4] = {0.f, 0.f, 0.f, 0.f};
                #pragma unroll
                for (int cti = 0; cti < CT; ++cti) {
                    int col = co + (colg * CT + cti) * 16 + la;
                    const float* iw = bias + col * 4;
                    const float* cw = bias2 + col * 4;
                    float cemb = E[3]*cw[0] + E[7]*cw[1] + E[11]*cw[2] + E[15]*cw[3];
                    #pragma unroll
                    for (int r = 0; r < 4; ++r) {
                        float e = d0[r]*iw[0] + d1[r]*iw[1] + d2[r]*iw[2] + d3[r]*iw[3] - cemb;
                        embv[cti][r] = e;
                        ssr[r] += e * e;
                    }
                }
                #pragma unroll
                for (int r = 0; r < 4; ++r) {
                    float s = ssr[r];
                    s += __shfl_xor(s, 1); s += __shfl_xor(s, 2);
                    s += __shfl_xor(s, 4); s += __shfl_xor(s, 8);
                    invr[r] = 1.0f / (sqrtf(s) + 1e-7f);
                }
            }
        }

        #pragma unroll
        for (int cti = 0; cti < CT; ++cti) {
            int ct = colg * CT + cti;
            int col = co + ct * 16 + la;
            float bv = 0.f;
            if constexpr (BIASF) bv = bc[col];
            if constexpr (STM == 1) {
                int row0 = rb + roww * 16 + g * 4;
                float vv[4];
                #pragma unroll
                for (int r = 0; r < 4; ++r) {
                    float v = acc[cti][r] + bv;
                    if constexpr (SCL)  v *= BN_S;
                    if constexpr (ACT)  v = gelu_f(v);
                    if constexpr (QSCL) v *= ATT_SCALE;
                    vv[r] = v;
                }
                float4 o4 = {vv[0], vv[1], vv[2], vv[3]};
                *(float4*)&((float*)ocv)[(size_t)col * PBEV + row0] = o4;
            } else {
                #pragma unroll
                for (int r = 0; r < 4; ++r) {
                    int row = rb + roww * 16 + g * 4 + r;
                    float v = acc[cti][r] + bv;
                    if constexpr (SCL)  v *= BN_S;
                    if constexpr (ACT)  v = gelu_f(v);
                    if constexpr (QSCL) v *= ATT_SCALE;
                    if constexpr (EMB) { if (set == 0) v += embv[cti][r] * invr[r]; }
                    if constexpr (ADDM == 1) { if (set == 0) v += addb[(size_t)row * 128 + col]; }
                    if constexpr (ADDM == 2) { if (set == 0) v += addb[(size_t)col * PBEV + row]; }
                    if constexpr (OUTBF) ((unsigned short*)ocv)[(size_t)row * NOT + col] = f2bf(v);
                    else                 ((float*)ocv)[(size_t)row * NOT + col] = v;
                }
            }
        }
    }
}

// ---------- merged k/v head GEMM (bf16 A, LN, dual weights, bf16 out) ----------
struct KVJob {
    const unsigned short* A;
    const unsigned short* W1;
    const float* b1;
    const unsigned short* W2;
    const float* b2;
    unsigned short* o1;
    unsigned short* o2;
};

__device__ __forceinline__ float bf2f(unsigned short u) {
    union { unsigned int u; float f; } c; c.u = ((unsigned int)u) << 16;
    return c.f;
}

__global__ __launch_bounds__(256)
void k_kvheads(KVJob jk, KVJob jv) {
    const KVJob j = (blockIdx.x < 288) ? jk : jv;
    const int rb = (blockIdx.x % 288) * 64;
    __shared__ unsigned short Al[64 * 136];
    __shared__ unsigned short Wl[128 * 136];
    const int t = threadIdx.x;
    const int lane = t & 63, wv = t >> 6;
    const int la = lane & 15, g = lane >> 4;

    {   // stage A rows (bf16 in) + LN
        int r = t >> 2, seg = t & 3;
        const unsigned short* ab = j.A + (size_t)(rb + r) * 128 + seg * 32;
        float v[32];
        #pragma unroll
        for (int j8 = 0; j8 < 4; ++j8) {
            u16x8 raw = *(const u16x8*)&ab[8 * j8];
            #pragma unroll
            for (int jj = 0; jj < 8; ++jj) v[8 * j8 + jj] = bf2f(raw[jj]);
        }
        float s = 0.f;
        #pragma unroll
        for (int jj = 0; jj < 32; ++jj) s += v[jj];
        s += __shfl_xor(s, 1); s += __shfl_xor(s, 2);
        float mu = s * (1.0f / 128.0f);
        float ss = 0.f;
        #pragma unroll
        for (int jj = 0; jj < 32; ++jj) { float d = v[jj] - mu; ss += d * d; }
        ss += __shfl_xor(ss, 1); ss += __shfl_xor(ss, 2);
        float rs = rsqrtf(ss * (1.0f / 128.0f) + LN_EPS);
        #pragma unroll
        for (int j8 = 0; j8 < 4; ++j8) {
            u16x8 o;
            #pragma unroll
            for (int jj = 0; jj < 8; ++jj) o[jj] = f2bf((v[8 * j8 + jj] - mu) * rs);
            *(u16x8*)&Al[r * 136 + seg * 32 + 8 * j8] = o;
        }
    }

    #pragma unroll 1
    for (int set = 0; set < 2; ++set) {
        const unsigned short* Wc = set ? j.W2 : j.W1;
        const float* bc = set ? j.b2 : j.b1;
        unsigned short* oc = set ? j.o2 : j.o1;
        if (set) __syncthreads();
        #pragma unroll
        for (int i = 0; i < 8; ++i) {
            int chunk = i * 256 + t;
            int c = chunk >> 4, k8 = chunk & 15;
            *(u16x8*)&Wl[c * 136 + k8 * 8] =
                *(const u16x8*)&Wc[(size_t)c * 128 + k8 * 8];
        }
        __syncthreads();
        short8 af[4];
        #pragma unroll
        for (int ks = 0; ks < 4; ++ks)
            af[ks] = *(short8*)&Al[(wv * 16 + la) * 136 + ks * 32 + g * 8];
        #pragma unroll
        for (int ct = 0; ct < 8; ++ct) {
            f32x4 acc = (f32x4){0.f, 0.f, 0.f, 0.f};
            #pragma unroll
            for (int ks = 0; ks < 4; ++ks) {
                short8 bf = *(short8*)&Wl[(ct * 16 + la) * 136 + ks * 32 + g * 8];
                acc = __builtin_amdgcn_mfma_f32_16x16x32_bf16(af[ks], bf, acc, 0, 0, 0);
            }
            int col = ct * 16 + la;
            float bv = bc[col];
            #pragma unroll
            for (int r = 0; r < 4; ++r) {
                int row = rb + wv * 16 + g * 4 + r;
                oc[(size_t)row * 128 + col] = f2bf(acc[r] + bv);
            }
        }
    }
}

// ---------- fused attn-out projection (+mean/+residual) + LN-MLP ----------
template<int AM>
__global__ __launch_bounds__(256)
void k_projmlp(const float* __restrict__ Ain, const unsigned short* __restrict__ pwb,
               const float* __restrict__ pb, const float* __restrict__ resid,
               const unsigned short* __restrict__ w1b, const float* __restrict__ b1,
               const unsigned short* __restrict__ w2b, const float* __restrict__ b2,
               float* __restrict__ out) {
    __shared__ unsigned short Al[16 * 136];
    __shared__ unsigned short Wl[128 * 72];
    __shared__ unsigned short Gl[16 * 264];
    __shared__ float Xf[16 * 132];
    const int t = threadIdx.x;
    const int rb = blockIdx.x * 16;
    const int lane = t & 63, wv = t >> 6;
    const int la = lane & 15, g = lane >> 4;

    {   // stage A_in -> Al bf16
        int r = t >> 4, seg = t & 15;
        float v[8];
        if constexpr (AM == 2) {
            int hw = rb + r;
            int h = hw >> 6, w = hw & 63;
            int l = (h >> 3) * 8 + (w >> 3), ww = (h & 7) * 8 + (w & 7);
            const float* src = Ain + ((size_t)(l * 64 + ww)) * 6 * 128 + seg * 8;
            #pragma unroll
            for (int jj = 0; jj < 8; ++jj) v[jj] = 0.f;
            #pragma unroll
            for (int n = 0; n < 6; ++n) {
                float4 x0 = *(const float4*)&src[n * 128];
                float4 x1 = *(const float4*)&src[n * 128 + 4];
                v[0] += x0.x; v[1] += x0.y; v[2] += x0.z; v[3] += x0.w;
                v[4] += x1.x; v[5] += x1.y; v[6] += x1.z; v[7] += x1.w;
            }
            #pragma unroll
            for (int jj = 0; jj < 8; ++jj) v[jj] *= (1.0f / 6.0f);
        } else {
            const float* ar = Ain + (size_t)(rb + r) * 128 + seg * 8;
            *(float4*)&v[0] = *(const float4*)&ar[0];
            *(float4*)&v[4] = *(const float4*)&ar[4];
        }
        u16x8 o;
        #pragma unroll
        for (int jj = 0; jj < 8; ++jj) o[jj] = f2bf(v[jj]);
        *(u16x8*)&Al[r * 136 + seg * 8] = o;
    }
    __syncthreads();

    // proj: X = A . pw^T + pb + resid
    f32x4 acc2[2];
    acc2[0] = (f32x4){0.f, 0.f, 0.f, 0.f};
    acc2[1] = (f32x4){0.f, 0.f, 0.f, 0.f};
    #pragma unroll 1
    for (int kc = 0; kc < 2; ++kc) {
        if (kc) __syncthreads();
        {
            int c = t >> 1, s2 = t & 1;
            const unsigned short* wr = pwb + (size_t)c * 128 + kc * 64 + s2 * 32;
            #pragma unroll
            for (int j8 = 0; j8 < 4; ++j8)
                *(u16x8*)&Wl[c * 72 + s2 * 32 + 8 * j8] = *(const u16x8*)&wr[8 * j8];
        }
        __syncthreads();
        #pragma unroll
        for (int half = 0; half < 2; ++half) {
            short8 pf = *(short8*)&Al[la * 136 + kc * 64 + half * 32 + g * 8];
            #pragma unroll
            for (int ct = 0; ct < 2; ++ct) {
                short8 bf = *(short8*)&Wl[((wv * 2 + ct) * 16 + la) * 72 + half * 32 + g * 8];
                acc2[ct] = __builtin_amdgcn_mfma_f32_16x16x32_bf16(pf, bf, acc2[ct], 0, 0, 0);
            }
        }
    }
    __syncthreads();
    #pragma unroll
    for (int ct = 0; ct < 2; ++ct) {
        int col = (wv * 2 + ct) * 16 + la;
        float bv = pb[col];
        #pragma unroll
        for (int r = 0; r < 4; ++r) {
            int row = g * 4 + r;
            Xf[row * 132 + col] = acc2[ct][r] + bv
                                + resid[(size_t)(rb + row) * 128 + col];
        }
    }
    __syncthreads();

    {   // LN(X) -> Al
        int r = t >> 4, seg = t & 15;
        float v[8];
        #pragma unroll
        for (int jj = 0; jj < 8; ++jj) v[jj] = Xf[r * 132 + seg * 8 + jj];
        float s = 0.f;
        #pragma unroll
        for (int jj = 0; jj < 8; ++jj) s += v[jj];
        s += __shfl_xor(s, 1); s += __shfl_xor(s, 2);
        s += __shfl_xor(s, 4); s += __shfl_xor(s, 8);
        float mu = s * (1.0f / 128.0f);
        float ss = 0.f;
        #pragma unroll
        for (int jj = 0; jj < 8; ++jj) { float d = v[jj] - mu; ss += d * d; }
        ss += __shfl_xor(ss, 1); ss += __shfl_xor(ss, 2);
        ss += __shfl_xor(ss, 4); ss += __shfl_xor(ss, 8);
        float rs = rsqrtf(ss * (1.0f / 128.0f) + LN_EPS);
        u16x8 o;
        #pragma unroll
        for (int jj = 0; jj < 8; ++jj) o[jj] = f2bf((v[jj] - mu) * rs);
        *(u16x8*)&Al[r * 136 + seg * 8] = o;
    }
    __syncthreads();

    short8 af[4];
    #pragma unroll
    for (int ks = 0; ks < 4; ++ks)
        af[ks] = *(short8*)&Al[la * 136 + ks * 32 + g * 8];

    // MLP GEMM1 -> Gl
    #pragma unroll 1
    for (int cc = 0; cc < 4; ++cc) {
        {
            int c = t >> 2, s2 = t & 3;
            const unsigned short* wr = w1b + (size_t)(cc * 64 + c) * 128 + s2 * 32;
            #pragma unroll
            for (int j8 = 0; j8 < 4; ++j8)
                *(u16x8*)&Wl[c * 136 + s2 * 32 + 8 * j8] = *(const u16x8*)&wr[8 * j8];
        }
        __syncthreads();
        f32x4 acc = (f32x4){0.f, 0.f, 0.f, 0.f};
        #pragma unroll
        for (int ks = 0; ks < 4; ++ks) {
            short8 bf = *(short8*)&Wl[(wv * 16 + la) * 136 + ks * 32 + g * 8];
            acc = __builtin_amdgcn_mfma_f32_16x16x32_bf16(af[ks], bf, acc, 0, 0, 0);
        }
        int col = cc * 64 + wv * 16 + la;
        float bv = b1[col];
        #pragma unroll
        for (int r = 0; r < 4; ++r)
            Gl[(g * 4 + r) * 264 + col] = f2bf(gelu_f(acc[r] + bv));
        __syncthreads();
    }

    // MLP GEMM2
    acc2[0] = (f32x4){0.f, 0.f, 0.f, 0.f};
    acc2[1] = (f32x4){0.f, 0.f, 0.f, 0.f};
    #pragma unroll 1
    for (int kc = 0; kc < 4; ++kc) {
        {
            int c = t >> 1, s2 = t & 1;
            const unsigned short* wr = w2b + (size_t)c * 256 + kc * 64 + s2 * 32;
            #pragma unroll
            for (int j8 = 0; j8 < 4; ++j8)
                *(u16x8*)&Wl[c * 72 + s2 * 32 + 8 * j8] = *(const u16x8*)&wr[8 * j8];
        }
        __syncthreads();
        #pragma unroll
        for (int half = 0; half < 2; ++half) {
            short8 pf = *(short8*)&Gl[la * 264 + kc * 64 + half * 32 + g * 8];
            #pragma unroll
            for (int ct = 0; ct < 2; ++ct) {
                short8 bf = *(short8*)&Wl[((wv * 2 + ct) * 16 + la) * 72 + half * 32 + g * 8];
                acc2[ct] = __builtin_amdgcn_mfma_f32_16x16x32_bf16(pf, bf, acc2[ct], 0, 0, 0);
            }
        }
        __syncthreads();
    }
    #pragma unroll
    for (int ct = 0; ct < 2; ++ct) {
        int col = (wv * 2 + ct) * 16 + la;
        float bv = b2[col];
        #pragma unroll
        for (int r = 0; r < 4; ++r) {
            int row = g * 4 + r;
            out[(size_t)(rb + row) * 128 + col] = acc2[ct][r] + bv + Xf[row * 132 + col];
        }
    }
}

// ---------- fused mbproj(+SE,+zln) -> pm-FFN -> proj_out (gelu, transposed) ----------
__global__ __launch_bounds__(256)
void k_mbprojmlp(const float* __restrict__ dwo, const unsigned short* __restrict__ mbpwb,
                 const float* __restrict__ se, const float* __restrict__ zln,
                 const unsigned short* __restrict__ w1b, const float* __restrict__ b1,
                 const unsigned short* __restrict__ w2b, const float* __restrict__ b2,
                 const unsigned short* __restrict__ pob, const float* __restrict__ pb,
                 float* __restrict__ out) {
    __shared__ unsigned short Al[16 * 136];
    __shared__ unsigned short Wl[128 * 72];
    __shared__ unsigned short Gl[16 * 264];
    __shared__ float Xf[16 * 132];
    const int t = threadIdx.x;
    const int rb = blockIdx.x * 16;
    const int lane = t & 63, wv = t >> 6;
    const int la = lane & 15, g = lane >> 4;

    f32x4 acc2[2];
    acc2[0] = (f32x4){0.f, 0.f, 0.f, 0.f};
    acc2[1] = (f32x4){0.f, 0.f, 0.f, 0.f};
    #pragma unroll 1
    for (int kc = 0; kc < 8; ++kc) {
        if (kc) __syncthreads();
        {
            int r = t >> 4, seg = t & 15;
            const float* ar = dwo + (size_t)(rb + r) * 512 + kc * 64 + seg * 4;
            float4 v = *(const float4*)ar;
            const float* sp = se + kc * 64 + seg * 4;
            v.x *= sp[0]; v.y *= sp[1]; v.z *= sp[2]; v.w *= sp[3];
            unsigned short* dst = &Al[r * 136 + seg * 4];
            dst[0] = f2bf(v.x); dst[1] = f2bf(v.y);
            dst[2] = f2bf(v.z); dst[3] = f2bf(v.w);
        }
        {
            int c = t >> 1, s2 = t & 1;
            const unsigned short* wr = mbpwb + (size_t)c * 512 + kc * 64 + s2 * 32;
            #pragma unroll
            for (int j8 = 0; j8 < 4; ++j8)
                *(u16x8*)&Wl[c * 72 + s2 * 32 + 8 * j8] = *(const u16x8*)&wr[8 * j8];
        }
        __syncthreads();
        #pragma unroll
        for (int half = 0; half < 2; ++half) {
            short8 pf = *(short8*)&Al[la * 136 + half * 32 + g * 8];
            #pragma unroll
            for (int ct = 0; ct < 2; ++ct) {
                short8 bf = *(short8*)&Wl[((wv * 2 + ct) * 16 + la) * 72 + half * 32 + g * 8];
                acc2[ct] = __builtin_amdgcn_mfma_f32_16x16x32_bf16(pf, bf, acc2[ct], 0, 0, 0);
            }
        }
    }
    __syncthreads();
    #pragma unroll
    for (int ct = 0; ct < 2; ++ct) {
        int col = (wv * 2 + ct) * 16 + la;
        #pragma unroll
        for (int r = 0; r < 4; ++r) {
            int row = g * 4 + r;
            Xf[row * 132 + col] = acc2[ct][r] * BN_S
                                + zln[(size_t)(rb + row) * 128 + col];
        }
    }
    __syncthreads();

    {
        int r = t >> 4, seg = t & 15;
        u16x8 o;
        #pragma unroll
        for (int jj = 0; jj < 8; ++jj) o[jj] = f2bf(Xf[r * 132 + seg * 8 + jj]);
        *(u16x8*)&Al[r * 136 + seg * 8] = o;
    }
    __syncthreads();

    short8 af[4];
    #pragma unroll
    for (int ks = 0; ks < 4; ++ks)
        af[ks] = *(short8*)&Al[la * 136 + ks * 32 + g * 8];

    #pragma unroll 1
    for (int cc = 0; cc < 4; ++cc) {
        {
            int c = t >> 2, s2 = t & 3;
            const unsigned short* wr = w1b + (size_t)(cc * 64 + c) * 128 + s2 * 32;
            #pragma unroll
            for (int j8 = 0; j8 < 4; ++j8)
                *(u16x8*)&Wl[c * 136 + s2 * 32 + 8 * j8] = *(const u16x8*)&wr[8 * j8];
        }
        __syncthreads();
        f32x4 acc = (f32x4){0.f, 0.f, 0.f, 0.f};
        #pragma unroll
        for (int ks = 0; ks < 4; ++ks) {
            short8 bf = *(short8*)&Wl[(wv * 16 + la) * 136 + ks * 32 + g * 8];
            acc = __builtin_amdgcn_mfma_f32_16x16x32_bf16(af[ks], bf, acc, 0, 0, 0);
        }
        int col = cc * 64 + wv * 16 + la;
        float bv = b1[col];
        #pragma unroll
        for (int r = 0; r < 4; ++r)
            Gl[(g * 4 + r) * 264 + col] = f2bf(gelu_f(acc[r] + bv));
        __syncthreads();
    }

    acc2[0] = (f32x4){0.f, 0.f, 0.f, 0.f};
    acc2[1] = (f32x4){0.f, 0.f, 0.f, 0.f};
    #pragma unroll 1
    for (int kc = 0; kc < 4; ++kc) {
        {
            int c = t >> 1, s2 = t & 1;
            const unsigned short* wr = w2b + (size_t)c * 256 + kc * 64 + s2 * 32;
            #pragma unroll
            for (int j8 = 0; j8 < 4; ++j8)
                *(u16x8*)&Wl[c * 72 + s2 * 32 + 8 * j8] = *(const u16x8*)&wr[8 * j8];
        }
        __syncthreads();
        #pragma unroll
        for (int half = 0; half < 2; ++half) {
            short8 pf = *(short8*)&Gl[la * 264 + kc * 64 + half * 32 + g * 8];
            #pragma unroll
            for (int ct = 0; ct < 2; ++ct) {
                short8 bf = *(short8*)&Wl[((wv * 2 + ct) * 16 + la) * 72 + half * 32 + g * 8];
                acc2[ct] = __builtin_amdgcn_mfma_f32_16x16x32_bf16(pf, bf, acc2[ct], 0, 0, 0);
            }
        }
        __syncthreads();
    }
    #pragma unroll
    for (int ct = 0; ct < 2; ++ct) {
        int col = (wv * 2 + ct) * 16 + la;
        float bv = b2[col];
        #pragma unroll
        for (int r = 0; r < 4; ++r) {
            int row = g * 4 + r;
            float y = acc2[ct][r] + bv + Xf[row * 132 + col];
            Al[row * 136 + col] = f2bf(y);
        }
    }
    __syncthreads();

    f32x4 acc3[2];
    acc3[0] = (f32x4){0.f, 0.f, 0.f, 0.f};
    acc3[1] = (f32x4){0.f, 0.f, 0.f, 0.f};
    #pragma unroll 1
    for (int kc = 0; kc < 2; ++kc) {
        if (kc) __syncthreads();
        {
            int c = t >> 1, s2 = t & 1;
            const unsigned short* wr = pob + (size_t)c * 128 + kc * 64 + s2 * 32;
            #pragma unroll
            for (int j8 = 0; j8 < 4; ++j8)
                *(u16x8*)&Wl[c * 72 + s2 * 32 + 8 * j8] = *(const u16x8*)&wr[8 * j8];
        }
        __syncthreads();
        #pragma unroll
        for (int half = 0; half < 2; ++half) {
            short8 pf = *(short8*)&Al[la * 136 + kc * 64 + half * 32 + g * 8];
            #pragma unroll
            for (int ct = 0; ct < 2; ++ct) {
                short8 bf = *(short8*)&Wl[((wv * 2 + ct) * 16 + la) * 72 + half * 32 + g * 8];
                acc3[ct] = __builtin_amdgcn_mfma_f32_16x16x32_bf16(pf, bf, acc3[ct], 0, 0, 0);
            }
        }
    }
    #pragma unroll
    for (int ct = 0; ct < 2; ++ct) {
        int col = (wv * 2 + ct) * 16 + la;
        float bv = pb[col];
        float4 o4;
        o4.x = gelu_f(acc3[ct][0] + bv);
        o4.y = gelu_f(acc3[ct][1] + bv);
        o4.z = gelu_f(acc3[ct][2] + bv);
        o4.w = gelu_f(acc3[ct][3] + bv);
        *(float4*)&out[(size_t)col * PBEV + rb + g * 4] = o4;
    }
}

// ---------- MFMA flash attention (S^T trick, shfl P re-layout) ----------
template<int MODE>
__global__ __launch_bounds__(MODE == 1 ? 512 : 256)
void k_attn_mfma(const unsigned short* __restrict__ qh, const unsigned short* __restrict__ kh,
                 const unsigned short* __restrict__ vh, float* __restrict__ aout) {
    constexpr int WAVES = (MODE == 1) ? 8 : 4;
    constexpr int QTPW  = (MODE == 1) ? 3 : 1;
    constexpr int T = WAVES * 64;
    const int l = blockIdx.x, m = blockIdx.y;
    const int xw = l >> 3, yw = l & 7;
    const int t = threadIdx.x;
    const int lane = t & 63, wv = t >> 6;
    const int la = lane & 15, g = lane >> 4;

    __shared__ unsigned short Kl[KROWS * 40];
    __shared__ unsigned short Vt[32 * 312];

    for (int i = t; i < KROWS * 4; i += T) {
        int row = i >> 2, seg = i & 3;
        int n = row / 48, kk = row % 48;
        int k1 = kk / 12, k2 = kk % 12;
        int h, w;
        if (MODE == 1) { h = xw * 4 + k1;  w = yw * 12 + k2; }
        else           { h = k1 * 8 + xw;  w = k2 * 8 + yw;  }
        size_t src = ((size_t)(n * PIMG + h * FWW + w)) * 128 + m * DHD + seg * 8;
        short8 kv = *(const short8*)&kh[src];
        *(short8*)&Kl[row * 40 + seg * 8] = kv;
        short8 vv = *(const short8*)&vh[src];
        #pragma unroll
        for (int j = 0; j < 8; ++j)
            Vt[(seg * 8 + j) * 312 + row] = (unsigned short)vv[j];
    }

    short8 qf[QTPW];
    #pragma unroll
    for (int qt = 0; qt < QTPW; ++qt) {
        int q = (wv * QTPW + qt) * 16 + la;
        int row;
        if (MODE == 1) {
            int n = q >> 6, ww = q & 63;
            row = n * PBEV + (xw * 8 + (ww >> 3)) * 64 + yw * 8 + (ww & 7);
        } else {
            row = ((q >> 3) * 8 + xw) * 64 + (q & 7) * 8 + yw;
        }
        qf[qt] = *(const short8*)&qh[(size_t)row * 128 + m * DHD + g * 8];
    }
    __syncthreads();

    f32x4 acc[QTPW][2];
    float srow[QTPW];
    #pragma unroll
    for (int qt = 0; qt < QTPW; ++qt) {
        acc[qt][0] = (f32x4){0.f, 0.f, 0.f, 0.f};
        acc[qt][1] = (f32x4){0.f, 0.f, 0.f, 0.f};
        srow[qt] = 0.f;
    }
    const int a0 = la + 32 * (g & 1);
    const int a1 = a0 + 16;
    const bool selA = (g < 2);

    #pragma unroll 1
    for (int c = 0; c < 9; ++c) {
        const int kk0 = c * 32;
        short8 kf0 = *(short8*)&Kl[(kk0 + la) * 40 + g * 8];
        short8 kf1 = *(short8*)&Kl[(kk0 + 16 + la) * 40 + g * 8];
        short8 vf0 = *(short8*)&Vt[la * 312 + kk0 + g * 8];
        short8 vf1 = *(short8*)&Vt[(16 + la) * 312 + kk0 + g * 8];
        #pragma unroll
        for (int qt = 0; qt < QTPW; ++qt) {
            f32x4 sA = __builtin_amdgcn_mfma_f32_16x16x32_bf16(kf0, qf[qt], (f32x4){0.f,0.f,0.f,0.f}, 0, 0, 0);
            f32x4 sB = __builtin_amdgcn_mfma_f32_16x16x32_bf16(kf1, qf[qt], (f32x4){0.f,0.f,0.f,0.f}, 0, 0, 0);
            float pA[4], pB[4];
            #pragma unroll
            for (int r = 0; r < 4; ++r) { pA[r] = __expf(sA[r]); pB[r] = __expf(sB[r]); }
            srow[qt] += ((pA[0] + pA[1]) + (pA[2] + pA[3]))
                      + ((pB[0] + pB[1]) + (pB[2] + pB[3]));
            unsigned int loA = (unsigned int)f2bf(pA[0]) | ((unsigned int)f2bf(pA[1]) << 16);
            unsigned int hiA = (unsigned int)f2bf(pA[2]) | ((unsigned int)f2bf(pA[3]) << 16);
            unsigned int loB = (unsigned int)f2bf(pB[0]) | ((unsigned int)f2bf(pB[1]) << 16);
            unsigned int hiB = (unsigned int)f2bf(pB[2]) | ((unsigned int)f2bf(pB[3]) << 16);
            int w0A = __shfl((int)loA, a0); int w0B = __shfl((int)loB, a0);
            int w1A = __shfl((int)hiA, a0); int w1B = __shfl((int)hiB, a0);
            int w2A = __shfl((int)loA, a1); int w2B = __shfl((int)loB, a1);
            int w3A = __shfl((int)hiA, a1); int w3B = __shfl((int)hiB, a1);
            union { int u[4]; short8 s; } pu;
            pu.u[0] = selA ? w0A : w0B;
            pu.u[1] = selA ? w1A : w1B;
            pu.u[2] = selA ? w2A : w2B;
            pu.u[3] = selA ? w3A : w3B;
            acc[qt][0] = __builtin_amdgcn_mfma_f32_16x16x32_bf16(pu.s, vf0, acc[qt][0], 0, 0, 0);
            acc[qt][1] = __builtin_amdgcn_mfma_f32_16x16x32_bf16(pu.s, vf1, acc[qt][1], 0, 0, 0);
        }
    }

    #pragma unroll
    for (int qt = 0; qt < QTPW; ++qt) {
        float s = srow[qt];
        s += __shfl_xor(s, 16);
        s += __shfl_xor(s, 32);
        #pragma unroll
        for (int r = 0; r < 4; ++r) {
            float sq = __shfl(s, g * 4 + r);
            float inv = 1.0f / sq;
            int q = (wv * QTPW + qt) * 16 + g * 4 + r;
            size_t orow;
            if (MODE == 1) {
                int n = q >> 6, ww = q & 63;
                orow = (size_t)(l * 64 + ww) * 6 + n;
            } else {
                orow = (size_t)(((q >> 3) * 8 + xw) * 64 + (q & 7) * 8 + yw);
            }
            float* ap = aout + orow * 128 + m * DHD;
            ap[la]      = acc[qt][0][r] * inv;
            ap[16 + la] = acc[qt][1][r] * inv;
        }
    }
}

// ---------- depthwise 3x3 + gelu + SE partials ----------
__global__ void k_dwconv(const float* __restrict__ ex, const float* __restrict__ dwgt,
                         float* __restrict__ dwout, float* __restrict__ separt) {
    const int TILE = 16;
    int ch = threadIdx.x;
    int hw0 = blockIdx.x * TILE;
    float wreg[9];
    #pragma unroll
    for (int i = 0; i < 9; ++i) wreg[i] = dwgt[ch * 9 + i];
    float sacc = 0.f;
    for (int ti = 0; ti < TILE; ++ti) {
        int hw = hw0 + ti;
        int h = hw >> 6, w = hw & 63;
        float s = 0.f;
        #pragma unroll
        for (int dy = -1; dy <= 1; ++dy) {
            int h2 = h + dy;
            if (h2 < 0 || h2 >= 64) continue;
            #pragma unroll
            for (int dx = -1; dx <= 1; ++dx) {
                int w2 = w + dx;
                if (w2 < 0 || w2 >= 64) continue;
                s += ex[((size_t)(h2 * 64 + w2)) * 512 + ch] * wreg[(dy + 1) * 3 + (dx + 1)];
            }
        }
        float o = gelu_f(s * BN_S);
        dwout[(size_t)hw * 512 + ch] = o;
        sacc += o;
    }
    separt[(size_t)blockIdx.x * 512 + ch] = sacc;
}

// ---------- SE reduce stage 1 ----------
__global__ void k_sered(const float* __restrict__ separt, float* __restrict__ separt2) {
    int t = threadIdx.x, bb = blockIdx.x;
    float s = 0.f;
    #pragma unroll
    for (int i = 0; i < 16; ++i)
        s += separt[(size_t)(bb * 16 + i) * 512 + t];
    separt2[(size_t)bb * 512 + t] = s;
}

// ---------- SE final ----------
__global__ void k_se(const float* __restrict__ separt2,
                     const float* __restrict__ s1w, const float* __restrict__ s1b,
                     const float* __restrict__ s2w, const float* __restrict__ s2b,
                     float* __restrict__ se) {
    __shared__ float mean[512];
    __shared__ float s1[32];
    int t = threadIdx.x;
    float s = 0.f;
    #pragma unroll
    for (int b = 0; b < 16; ++b) s += separt2[b * 512 + t];
    mean[t] = s * (1.0f / 4096.0f);
    __syncthreads();
    int u = t >> 4, seg = t & 15;
    float acc = 0.f;
    #pragma unroll
    for (int j = 0; j < 32; ++j) {
        int c = seg + 16 * j;
        acc += mean[c] * s1w[u * 512 + c];
    }
    acc += __shfl_xor(acc, 1); acc += __shfl_xor(acc, 2);
    acc += __shfl_xor(acc, 4); acc += __shfl_xor(acc, 8);
    if (seg == 0) s1[u] = gelu_f(acc + s1b[u]);
    __syncthreads();
    float a2 = s2b[t];
    #pragma unroll
    for (int j = 0; j < 32; ++j) a2 += s1[j] * s2w[t * 32 + j];
    se[t] = 1.0f / (1.0f + __expf(-a2));
}

extern "C" void kernel_launch(void* const* d_in, const int* in_sizes, int n_in,
                              void* d_out, int out_size, void* d_ws, size_t ws_size,
                              hipStream_t stream) {
    (void)in_sizes; (void)n_in; (void)out_size; (void)ws_size;
    const float* x      = (const float*)d_in[1];
    const float* feat   = (const float*)d_in[2];
    const float* I_inv  = (const float*)d_in[3];
    const float* E_inv  = (const float*)d_in[4];
    const float* bev    = (const float*)d_in[5];
    const float* fl_w   = (const float*)d_in[6];
    const float* fp_w   = (const float*)d_in[7];
    const float* be_w   = (const float*)d_in[8];
    const float* be_b   = (const float*)d_in[9];
    const float* ie_w   = (const float*)d_in[10];
    const float* ce_w   = (const float*)d_in[11];
    const float* a1_qw  = (const float*)d_in[12];
    const float* a1_qb  = (const float*)d_in[13];
    const float* a1_kw  = (const float*)d_in[14];
    const float* a1_kb  = (const float*)d_in[15];
    const float* a1_vw  = (const float*)d_in[16];
    const float* a1_vb  = (const float*)d_in[17];
    const float* a1_pw  = (const float*)d_in[18];
    const float* a1_pb  = (const float*)d_in[19];
    const float* a2_qw  = (const float*)d_in[20];
    const float* a2_qb  = (const float*)d_in[21];
    const float* a2_kw  = (const float*)d_in[22];
    const float* a2_kb  = (const float*)d_in[23];
    const float* a2_vw  = (const float*)d_in[24];
    const float* a2_vb  = (const float*)d_in[25];
    const float* a2_pw  = (const float*)d_in[26];
    const float* a2_pb  = (const float*)d_in[27];
    const float* m1_w1  = (const float*)d_in[28];
    const float* m1_b1  = (const float*)d_in[29];
    const float* m1_w2  = (const float*)d_in[30];
    const float* m1_b2  = (const float*)d_in[31];
    const float* m2_w1  = (const float*)d_in[32];
    const float* m2_b1  = (const float*)d_in[33];
    const float* m2_w2  = (const float*)d_in[34];
    const float* m2_b2  = (const float*)d_in[35];
    const float* mb_ew  = (const float*)d_in[36];
    const float* mb_dw  = (const float*)d_in[37];
    const float* mb_s1w = (const float*)d_in[38];
    const float* mb_s1b = (const float*)d_in[39];
    const float* mb_s2w = (const float*)d_in[40];
    const float* mb_s2b = (const float*)d_in[41];
    const float* mb_pw  = (const float*)d_in[42];
    const float* pm_w1  = (const float*)d_in[43];
    const float* pm_b1  = (const float*)d_in[44];
    const float* pm_w2  = (const float*)d_in[45];
    const float* pm_b2  = (const float*)d_in[46];
    const float* po_w   = (const float*)d_in[47];
    const float* po_b   = (const float*)d_in[48];

    float* ws = (float*)d_ws;
    float* x_cl   = ws + 0;          // 524288
    unsigned short* key_b = (unsigned short*)(ws + 524288);
    unsigned short* val_b = (unsigned short*)(ws + 1703936);
    unsigned short* qh1b  = (unsigned short*)(ws + 2883584);
    unsigned short* kh1b  = (unsigned short*)(ws + 4456448);
    unsigned short* vh1b  = (unsigned short*)(ws + 5636096);
    unsigned short* kh2b  = (unsigned short*)(ws + 6815744);
    unsigned short* vh2b  = (unsigned short*)(ws + 7995392);
    float* abuf   = ws + 9175040;    // 3145728
    float* qimg   = ws + 12320768;
    float* qimg2  = ws + 12845056;
    float* zln    = ws + 13369344;
    float* abuf2  = ws + 13893632;
    float* expandb = ws + 14942208;  // 2097152
    float* dwout   = ws + 17039360;  // 2097152
    float* separt  = ws + 19136512;  // 131072
    float* separt2 = ws + 19267584;  // 8192
    float* sebuf   = ws + 19275776;  // 512
    unsigned short* wb = (unsigned short*)(ws + 19276288);  // 507904 u16
    unsigned short* qh2b = qh1b;

    // weight conversion + x transpose
    k_cvtw<<<248, 256, 0, stream>>>(fp_w, fl_w, a1_qw, a1_kw, a2_kw, a1_vw, a2_vw,
                                    a1_pw, m1_w1, m1_w2, a2_qw, a2_pw, m2_w1, m2_w2,
                                    mb_ew, mb_pw, pm_w1, pm_w2, po_w, wb);
    k_transx<<<dim3(128, 4), 256, 0, stream>>>(x, x_cl);

    // key/val (feature transpose + img-embed fused), bf16 out
    k_gemm_mfma<64,1,128, 1,0,0,0,0, 0,0,0,1, 1,0,0,1,1><<<288, 256, 0, stream>>>(
        feat, (const float*)(wb + OFF_FP), ie_w, E_inv, I_inv,
        (const float*)(wb + OFF_FL), ce_w, val_b, nullptr, key_b);

    // q head (query gen fused, pre-scaled); k/v heads merged dual
    k_gemm_mfma<64,1,128, 3,1,1,0,0, 0,0,0,0, 1,1,0,0,1><<<384, 256, 0, stream>>>(
        nullptr, (const float*)(wb + OFF_A1QW), a1_qb, bev, x_cl, be_w, be_b,
        (void*)E_inv, (float*)ce_w, qh1b);
    {
        KVJob jk = { key_b, wb + OFF_A1KW, a1_kb, wb + OFF_A2KW, a2_kb, kh1b, kh2b };
        KVJob jv = { val_b, wb + OFF_A1VW, a1_vb, wb + OFF_A2VW, a2_vb, vh1b, vh2b };
        k_kvheads<<<576, 256, 0, stream>>>(jk, jv);
    }
    k_attn_mfma<1><<<dim3(64, HEADS), 512, 0, stream>>>(qh1b, kh1b, vh1b, abuf);
    k_projmlp<2><<<256, 256, 0, stream>>>(abuf, wb + OFF_A1PW, a1_pb, x_cl,
                                          wb + OFF_M1W1, m1_b1, wb + OFF_M1W2, m1_b2, qimg);

    // stage 2
    k_gemm_mfma<16,1,128, 0,1,1,0,0, 0,0,0,0, 1,1,0,0,1><<<256, 256, 0, stream>>>(
        qimg, (const float*)(wb + OFF_A2QW), a2_qb, nullptr, nullptr, nullptr,
        nullptr, nullptr, nullptr, qh2b);
    k_attn_mfma<2><<<dim3(64, HEADS), 256, 0, stream>>>(qh2b, kh2b, vh2b, abuf2);
    k_projmlp<0><<<256, 256, 0, stream>>>(abuf2, wb + OFF_A2PW, a2_pb, qimg,
                                          wb + OFF_M2W1, m2_b1, wb + OFF_M2W2, m2_b2, qimg2);

    // stage 3
    k_gemm_mfma<16,1,512, 0,1,0,1,1, 0,0,0,0, 0,0,1,0,1><<<dim3(256, 4), 256, 0, stream>>>(
        qimg2, (const float*)(wb + OFF_MBEW), nullptr, nullptr, nullptr, nullptr,
        nullptr, nullptr, zln, expandb);
    k_dwconv<<<256, 512, 0, stream>>>(expandb, mb_dw, dwout, separt);
    k_sered<<<16, 512, 0, stream>>>(separt, separt2);
    k_se<<<1, 512, 0, stream>>>(separt2, mb_s1w, mb_s1b, mb_s2w, mb_s2b, sebuf);
    k_mbprojmlp<<<256, 256, 0, stream>>>(dwout, wb + OFF_MBPW, sebuf, zln,
                                         wb + OFF_PMW1, pm_b1, wb + OFF_PMW2, pm_b2,
                                         wb + OFF_POW, po_b, (float*)d_out);
}

// Round 14
// 151.681 us; speedup vs baseline: 1.1399x; 1.0199x over previous
//
#include <hip/hip_runtime.h>
#include <math.h>

#define NV 6
#define FHH 32
#define FWW 96
#define PIMG (FHH*FWW)   // 3072
#define HH 64
#define WWD 64
#define PBEV (HH*WWD)    // 4096
#define HEADS 4
#define DHD 32
#define KROWS 288
#define BN_S 0.9999950000374996f
#define LN_EPS 1e-5f
#define ATT_SCALE 0.17677669529663687f  // 32^-0.5

typedef __attribute__((ext_vector_type(8))) short short8;
typedef __attribute__((ext_vector_type(4))) float f32x4;
typedef __attribute__((ext_vector_type(8))) unsigned short u16x8;

__device__ __forceinline__ float gelu_f(float x) {
    return 0.5f * x * (1.0f + erff(x * 0.70710678118654752f));
}

__device__ __forceinline__ unsigned short f2bf(float f) {
    union { float f; unsigned int u; } c; c.f = f;
    unsigned int r = (c.u + 0x7fffu + ((c.u >> 16) & 1u)) >> 16;
    return (unsigned short)r;
}

__device__ __forceinline__ float bf2f(unsigned short u) {
    union { unsigned int u; float f; } c; c.u = ((unsigned int)u) << 16;
    return c.f;
}

// bf16 weight arena offsets (u16 elements)
#define OFF_FP    0
#define OFF_FL    16384
#define OFF_A1QW  32768
#define OFF_A1KW  49152
#define OFF_A2KW  65536
#define OFF_A1VW  81920
#define OFF_A2VW  98304
#define OFF_A1PW  114688
#define OFF_M1W1  131072
#define OFF_M1W2  163840
#define OFF_A2QW  196608
#define OFF_A2PW  212992
#define OFF_M2W1  229376
#define OFF_M2W2  262144
#define OFF_MBEW  294912
#define OFF_MBPW  360448
#define OFF_PMW1  425984
#define OFF_PMW2  458752
#define OFF_POW   491520
#define WTOTAL    507904

// ---------- prep: weight f32->bf16 arena (blocks 0..247) + x transpose (248..759) ----------
__global__ void k_prep(const float* p0, const float* p1, const float* p2,
                       const float* p3, const float* p4, const float* p5,
                       const float* p6, const float* p7, const float* p8,
                       const float* p9, const float* p10, const float* p11,
                       const float* p12, const float* p13, const float* p14,
                       const float* p15, const float* p16, const float* p17,
                       const float* p18, unsigned short* wb,
                       const float* __restrict__ x, float* __restrict__ x_cl) {
    __shared__ float tile[32][33];
    if (blockIdx.x < 248) {
        int idx = (blockIdx.x * 256 + threadIdx.x) * 8;
        if (idx >= WTOTAL) return;
        const float* s;
        if      (idx < OFF_FL)   s = p0  + idx;
        else if (idx < OFF_A1QW) s = p1  + (idx - OFF_FL);
        else if (idx < OFF_A1KW) s = p2  + (idx - OFF_A1QW);
        else if (idx < OFF_A2KW) s = p3  + (idx - OFF_A1KW);
        else if (idx < OFF_A1VW) s = p4  + (idx - OFF_A2KW);
        else if (idx < OFF_A2VW) s = p5  + (idx - OFF_A1VW);
        else if (idx < OFF_A1PW) s = p6  + (idx - OFF_A2VW);
        else if (idx < OFF_M1W1) s = p7  + (idx - OFF_A1PW);
        else if (idx < OFF_M1W2) s = p8  + (idx - OFF_M1W1);
        else if (idx < OFF_A2QW) s = p9  + (idx - OFF_M1W2);
        else if (idx < OFF_A2PW) s = p10 + (idx - OFF_A2QW);
        else if (idx < OFF_M2W1) s = p11 + (idx - OFF_A2PW);
        else if (idx < OFF_M2W2) s = p12 + (idx - OFF_M2W1);
        else if (idx < OFF_MBEW) s = p13 + (idx - OFF_M2W2);
        else if (idx < OFF_MBPW) s = p14 + (idx - OFF_MBEW);
        else if (idx < OFF_PMW1) s = p15 + (idx - OFF_MBPW);
        else if (idx < OFF_PMW2) s = p16 + (idx - OFF_PMW1);
        else if (idx < OFF_POW)  s = p17 + (idx - OFF_PMW2);
        else                     s = p18 + (idx - OFF_POW);
        float4 v0 = *(const float4*)&s[0];
        float4 v1 = *(const float4*)&s[4];
        u16x8 o = { f2bf(v0.x), f2bf(v0.y), f2bf(v0.z), f2bf(v0.w),
                    f2bf(v1.x), f2bf(v1.y), f2bf(v1.z), f2bf(v1.w) };
        *(u16x8*)&wb[idx] = o;
    } else {
        int bb = blockIdx.x - 248;
        int p0_ = (bb & 127) * 32, c0 = (bb >> 7) * 32;
        int tp = threadIdx.x & 31, tg = threadIdx.x >> 5;
        #pragma unroll
        for (int i = 0; i < 4; ++i)
            tile[tg + 8 * i][tp] = x[(size_t)(c0 + tg + 8 * i) * PBEV + p0_ + tp];
        __syncthreads();
        #pragma unroll
        for (int i = 0; i < 4; ++i)
            x_cl[(size_t)(p0_ + tg + 8 * i) * 128 + c0 + tp] = tile[tp][tg + 8 * i];
    }
}

// ---------- universal MFMA GEMM ----------
template<int BR, int KCH, int NOT, int AMODE, int LNF, int BIASF, int ACT, int SCL,
         int ADDM, int STM, int ASCL, int DUAL, int OUTBF, int QSCL, int WRLN,
         int EMB, int WBF>
__global__ __launch_bounds__(256)
void k_gemm_mfma(const float* __restrict__ A, const float* __restrict__ W,
                 const float* __restrict__ bias, const float* __restrict__ addb,
                 const float* __restrict__ ascale, const float* __restrict__ W2,
                 const float* __restrict__ bias2, void* __restrict__ out2v,
                 float* __restrict__ aux, void* __restrict__ outv) {
    constexpr int NI = KCH * 128;
    constexpr int RW = BR / 16;
    constexpr int CT = 8 / (4 / RW);
    __shared__ unsigned short Al[BR * 136];
    __shared__ unsigned short Wl[128 * 136];
    const int t = threadIdx.x;
    const int rb = blockIdx.x * BR;
    const int co = blockIdx.y * 128;
    const int lane = t & 63, wv = t >> 6;
    const int la = lane & 15, g = lane >> 4;
    const int roww = wv % RW, colg = wv / RW;

    if constexpr (KCH == 1) {
        if constexpr (AMODE == 1) {
            int n = rb / PIMG, p0 = rb % PIMG;
            int r = t & 63, kseg = t >> 6;
            #pragma unroll
            for (int j8 = 0; j8 < 4; ++j8) {
                u16x8 o;
                #pragma unroll
                for (int j = 0; j < 8; ++j) {
                    int k = kseg * 32 + j8 * 8 + j;
                    float v = A[((size_t)(n * 128 + k)) * PIMG + p0 + r];
                    o[j] = f2bf(fmaxf(v * BN_S, 0.0f));
                }
                *(u16x8*)&Al[r * 136 + kseg * 32 + j8 * 8] = o;
            }
        } else {
            constexpr int TPR = 256 / BR;
            constexpr int CPT = 128 / TPR;
            int r = t / TPR, seg = t % TPR;
            float v[CPT];
            if constexpr (AMODE == 3) {
                int grow = rb + r;
                int n = grow >> 12, p = grow & 4095;
                const float* E = ((const float*)out2v) + n * 16;
                const float* cew = (const float*)aux;
                float bp0 = addb[p], bp1 = addb[PBEV + p];
                float ss = 0.f;
                #pragma unroll
                for (int j = 0; j < CPT; ++j) {
                    int c = seg * CPT + j;
                    float cemb = E[3]  * cew[c*4+0] + E[7]  * cew[c*4+1]
                               + E[11] * cew[c*4+2] + E[15] * cew[c*4+3];
                    float emb = bp0 * W2[c*2] + bp1 * W2[c*2+1] + bias2[c] - cemb;
                    v[j] = emb; ss += emb * emb;
                }
                #pragma unroll
                for (int o = 1; o < TPR; o <<= 1) ss += __shfl_xor(ss, o, 64);
                float invn = 1.0f / (sqrtf(ss) + 1e-7f);
                const float* xr = ascale + (size_t)p * 128 + seg * CPT;
                #pragma unroll
                for (int j = 0; j < CPT; ++j) v[j] = v[j] * invn + xr[j];
            } else {
                const float* ar = A + (size_t)(rb + r) * 128 + seg * CPT;
                #pragma unroll
                for (int j4 = 0; j4 < CPT / 4; ++j4)
                    *(float4*)&v[4 * j4] = *(const float4*)&ar[4 * j4];
            }
            if constexpr (LNF) {
                float s = 0.f;
                #pragma unroll
                for (int j = 0; j < CPT; ++j) s += v[j];
                #pragma unroll
                for (int o = 1; o < TPR; o <<= 1) s += __shfl_xor(s, o, 64);
                float mu = s * (1.0f / 128.0f);
                float ss = 0.f;
                #pragma unroll
                for (int j = 0; j < CPT; ++j) { float d = v[j] - mu; ss += d * d; }
                #pragma unroll
                for (int o = 1; o < TPR; o <<= 1) ss += __shfl_xor(ss, o, 64);
                float rs = rsqrtf(ss * (1.0f / 128.0f) + LN_EPS);
                #pragma unroll
                for (int j = 0; j < CPT; ++j) v[j] = (v[j] - mu) * rs;
                if constexpr (WRLN) {
                    if (blockIdx.y == 0) {
                        #pragma unroll
                        for (int j4 = 0; j4 < CPT / 4; ++j4) {
                            float4 o4 = {v[4*j4], v[4*j4+1], v[4*j4+2], v[4*j4+3]};
                            *(float4*)&aux[(size_t)(rb + r) * 128 + seg * CPT + 4 * j4] = o4;
                        }
                    }
                }
            }
            #pragma unroll
            for (int j8 = 0; j8 < CPT / 8; ++j8) {
                u16x8 o;
                #pragma unroll
                for (int j = 0; j < 8; ++j) o[j] = f2bf(v[8 * j8 + j]);
                *(u16x8*)&Al[r * 136 + seg * CPT + 8 * j8] = o;
            }
        }
    }

    #pragma unroll 1
    for (int set = 0; set <= DUAL; ++set) {
        const float* Wc = set ? W2 : W;
        const float* bc = set ? bias2 : bias;
        void* ocv = set ? out2v : outv;
        f32x4 acc[CT];
        #pragma unroll
        for (int i = 0; i < CT; ++i) acc[i] = (f32x4){0.f, 0.f, 0.f, 0.f};

        #pragma unroll 1
        for (int kc = 0; kc < KCH; ++kc) {
            if (set || kc) __syncthreads();
            #pragma unroll
            for (int i = 0; i < 8; ++i) {
                int chunk = i * 256 + t;
                int c = chunk >> 4, k8 = chunk & 15;
                if constexpr (WBF) {
                    const unsigned short* wr = ((const unsigned short*)Wc)
                        + (size_t)(co + c) * NI + kc * 128 + k8 * 8;
                    *(u16x8*)&Wl[c * 136 + k8 * 8] = *(const u16x8*)wr;
                } else {
                    const float* wr = &Wc[(size_t)(co + c) * NI + kc * 128 + k8 * 8];
                    float4 v0 = *(const float4*)&wr[0];
                    float4 v1 = *(const float4*)&wr[4];
                    u16x8 o = { f2bf(v0.x), f2bf(v0.y), f2bf(v0.z), f2bf(v0.w),
                                f2bf(v1.x), f2bf(v1.y), f2bf(v1.z), f2bf(v1.w) };
                    *(u16x8*)&Wl[c * 136 + k8 * 8] = o;
                }
            }
            __syncthreads();
            short8 af[4];
            #pragma unroll
            for (int ks = 0; ks < 4; ++ks)
                af[ks] = *(short8*)&Al[(roww * 16 + la) * 136 + ks * 32 + g * 8];
            #pragma unroll
            for (int cti = 0; cti < CT; ++cti) {
                int ct = colg * CT + cti;
                #pragma unroll
                for (int ks = 0; ks < 4; ++ks) {
                    short8 bf = *(short8*)&Wl[(ct * 16 + la) * 136 + ks * 32 + g * 8];
                    acc[cti] = __builtin_amdgcn_mfma_f32_16x16x32_bf16(af[ks], bf, acc[cti], 0, 0, 0);
                }
            }
        }

        float embv[CT][4];
        float invr[4];
        if constexpr (EMB) {
            if (set == 0) {
                int n = rb / PIMG;
                const float* Ii = ascale + n * 9;
                const float* E  = addb + n * 16;
                float d0[4], d1[4], d2[4], d3[4];
                #pragma unroll
                for (int r = 0; r < 4; ++r) {
                    int row = rb + roww * 16 + g * 4 + r;
                    int p = row % PIMG;
                    int hh = p / FWW, wp = p % FWW;
                    float gx = (float)wp * (768.0f / 95.0f);
                    float gy = (float)hh * (256.0f / 31.0f);
                    float c0 = Ii[0]*gx + Ii[1]*gy + Ii[2];
                    float c1 = Ii[3]*gx + Ii[4]*gy + Ii[5];
                    float c2 = Ii[6]*gx + Ii[7]*gy + Ii[8];
                    d0[r] = E[0]*c0  + E[1]*c1  + E[2]*c2  + E[3];
                    d1[r] = E[4]*c0  + E[5]*c1  + E[6]*c2  + E[7];
                    d2[r] = E[8]*c0  + E[9]*c1  + E[10]*c2 + E[11];
                    d3[r] = E[12]*c0 + E[13]*c1 + E[14]*c2 + E[15];
                }
                float ssr[4] = {0.f, 0.f, 0.f, 0.f};
                #pragma unroll
                for (int cti = 0; cti < CT; ++cti) {
                    int col = co + (colg * CT + cti) * 16 + la;
                    const float* iw = bias + col * 4;
                    const float* cw = bias2 + col * 4;
                    float cemb = E[3]*cw[0] + E[7]*cw[1] + E[11]*cw[2] + E[15]*cw[3];
                    #pragma unroll
                    for (int r = 0; r < 4; ++r) {
                        float e = d0[r]*iw[0] + d1[r]*iw[1] + d2[r]*iw[2] + d3[r]*iw[3] - cemb;
                        embv[cti][r] = e;
                        ssr[r] += e * e;
                    }
                }
                #pragma unroll
                for (int r = 0; r < 4; ++r) {
                    float s = ssr[r];
                    s += __shfl_xor(s, 1); s += __shfl_xor(s, 2);
                    s += __shfl_xor(s, 4); s += __shfl_xor(s, 8);
                    invr[r] = 1.0f / (sqrtf(s) + 1e-7f);
                }
            }
        }

        #pragma unroll
        for (int cti = 0; cti < CT; ++cti) {
            int ct = colg * CT + cti;
            int col = co + ct * 16 + la;
            float bv = 0.f;
            if constexpr (BIASF) bv = bc[col];
            if constexpr (STM == 1) {
                int row0 = rb + roww * 16 + g * 4;
                float vv[4];
                #pragma unroll
                for (int r = 0; r < 4; ++r) {
                    float v = acc[cti][r] + bv;
                    if constexpr (SCL)  v *= BN_S;
                    if constexpr (ACT)  v = gelu_f(v);
                    if constexpr (QSCL) v *= ATT_SCALE;
                    vv[r] = v;
                }
                float4 o4 = {vv[0], vv[1], vv[2], vv[3]};
                *(float4*)&((float*)ocv)[(size_t)col * PBEV + row0] = o4;
            } else {
                #pragma unroll
                for (int r = 0; r < 4; ++r) {
                    int row = rb + roww * 16 + g * 4 + r;
                    float v = acc[cti][r] + bv;
                    if constexpr (SCL)  v *= BN_S;
                    if constexpr (ACT)  v = gelu_f(v);
                    if constexpr (QSCL) v *= ATT_SCALE;
                    if constexpr (EMB) { if (set == 0) v += embv[cti][r] * invr[r]; }
                    if constexpr (ADDM == 1) { if (set == 0) v += addb[(size_t)row * 128 + col]; }
                    if constexpr (ADDM == 2) { if (set == 0) v += addb[(size_t)col * PBEV + row]; }
                    if constexpr (OUTBF) ((unsigned short*)ocv)[(size_t)row * NOT + col] = f2bf(v);
                    else                 ((float*)ocv)[(size_t)row * NOT + col] = v;
                }
            }
        }
    }
}

// ---------- merged k/v head GEMM (bf16 A, LN, dual weights, bf16 out) ----------
struct KVJob {
    const unsigned short* A;
    const unsigned short* W1;
    const float* b1;
    const unsigned short* W2;
    const float* b2;
    unsigned short* o1;
    unsigned short* o2;
};

__global__ __launch_bounds__(256)
void k_kvheads(KVJob jk, KVJob jv) {
    const KVJob j = (blockIdx.x < 288) ? jk : jv;
    const int rb = (blockIdx.x % 288) * 64;
    __shared__ unsigned short Al[64 * 136];
    __shared__ unsigned short Wl[128 * 136];
    const int t = threadIdx.x;
    const int lane = t & 63, wv = t >> 6;
    const int la = lane & 15, g = lane >> 4;

    {   // stage A rows (bf16 in) + LN
        int r = t >> 2, seg = t & 3;
        const unsigned short* ab = j.A + (size_t)(rb + r) * 128 + seg * 32;
        float v[32];
        #pragma unroll
        for (int j8 = 0; j8 < 4; ++j8) {
            u16x8 raw = *(const u16x8*)&ab[8 * j8];
            #pragma unroll
            for (int jj = 0; jj < 8; ++jj) v[8 * j8 + jj] = bf2f(raw[jj]);
        }
        float s = 0.f;
        #pragma unroll
        for (int jj = 0; jj < 32; ++jj) s += v[jj];
        s += __shfl_xor(s, 1); s += __shfl_xor(s, 2);
        float mu = s * (1.0f / 128.0f);
        float ss = 0.f;
        #pragma unroll
        for (int jj = 0; jj < 32; ++jj) { float d = v[jj] - mu; ss += d * d; }
        ss += __shfl_xor(ss, 1); ss += __shfl_xor(ss, 2);
        float rs = rsqrtf(ss * (1.0f / 128.0f) + LN_EPS);
        #pragma unroll
        for (int j8 = 0; j8 < 4; ++j8) {
            u16x8 o;
            #pragma unroll
            for (int jj = 0; jj < 8; ++jj) o[jj] = f2bf((v[8 * j8 + jj] - mu) * rs);
            *(u16x8*)&Al[r * 136 + seg * 32 + 8 * j8] = o;
        }
    }

    #pragma unroll 1
    for (int set = 0; set < 2; ++set) {
        const unsigned short* Wc = set ? j.W2 : j.W1;
        const float* bc = set ? j.b2 : j.b1;
        unsigned short* oc = set ? j.o2 : j.o1;
        if (set) __syncthreads();
        #pragma unroll
        for (int i = 0; i < 8; ++i) {
            int chunk = i * 256 + t;
            int c = chunk >> 4, k8 = chunk & 15;
            *(u16x8*)&Wl[c * 136 + k8 * 8] =
                *(const u16x8*)&Wc[(size_t)c * 128 + k8 * 8];
        }
        __syncthreads();
        short8 af[4];
        #pragma unroll
        for (int ks = 0; ks < 4; ++ks)
            af[ks] = *(short8*)&Al[(wv * 16 + la) * 136 + ks * 32 + g * 8];
        #pragma unroll
        for (int ct = 0; ct < 8; ++ct) {
            f32x4 acc = (f32x4){0.f, 0.f, 0.f, 0.f};
            #pragma unroll
            for (int ks = 0; ks < 4; ++ks) {
                short8 bf = *(short8*)&Wl[(ct * 16 + la) * 136 + ks * 32 + g * 8];
                acc = __builtin_amdgcn_mfma_f32_16x16x32_bf16(af[ks], bf, acc, 0, 0, 0);
            }
            int col = ct * 16 + la;
            float bv = bc[col];
            #pragma unroll
            for (int r = 0; r < 4; ++r) {
                int row = rb + wv * 16 + g * 4 + r;
                oc[(size_t)row * 128 + col] = f2bf(acc[r] + bv);
            }
        }
    }
}

// ---------- fused attn-out projection (+mean/+residual) + LN-MLP (+opt a2q head) ----------
template<int AM, int QOUT>
__global__ __launch_bounds__(256)
void k_projmlp(const float* __restrict__ Ain, const unsigned short* __restrict__ pwb,
               const float* __restrict__ pb, const float* __restrict__ resid,
               const unsigned short* __restrict__ w1b, const float* __restrict__ b1,
               const unsigned short* __restrict__ w2b, const float* __restrict__ b2,
               float* __restrict__ out, const unsigned short* __restrict__ qwb,
               const float* __restrict__ qb, unsigned short* __restrict__ qout) {
    __shared__ unsigned short Al[16 * 136];
    __shared__ unsigned short Wl[128 * 72];
    __shared__ unsigned short Gl[16 * 264];
    __shared__ float Xf[16 * 132];
    const int t = threadIdx.x;
    const int rb = blockIdx.x * 16;
    const int lane = t & 63, wv = t >> 6;
    const int la = lane & 15, g = lane >> 4;

    {   // stage A_in -> Al bf16
        int r = t >> 4, seg = t & 15;
        float v[8];
        if constexpr (AM == 2) {
            int hw = rb + r;
            int h = hw >> 6, w = hw & 63;
            int l = (h >> 3) * 8 + (w >> 3), ww = (h & 7) * 8 + (w & 7);
            const float* src = Ain + ((size_t)(l * 64 + ww)) * 6 * 128 + seg * 8;
            #pragma unroll
            for (int jj = 0; jj < 8; ++jj) v[jj] = 0.f;
            #pragma unroll
            for (int n = 0; n < 6; ++n) {
                float4 x0 = *(const float4*)&src[n * 128];
                float4 x1 = *(const float4*)&src[n * 128 + 4];
                v[0] += x0.x; v[1] += x0.y; v[2] += x0.z; v[3] += x0.w;
                v[4] += x1.x; v[5] += x1.y; v[6] += x1.z; v[7] += x1.w;
            }
            #pragma unroll
            for (int jj = 0; jj < 8; ++jj) v[jj] *= (1.0f / 6.0f);
        } else {
            const float* ar = Ain + (size_t)(rb + r) * 128 + seg * 8;
            *(float4*)&v[0] = *(const float4*)&ar[0];
            *(float4*)&v[4] = *(const float4*)&ar[4];
        }
        u16x8 o;
        #pragma unroll
        for (int jj = 0; jj < 8; ++jj) o[jj] = f2bf(v[jj]);
        *(u16x8*)&Al[r * 136 + seg * 8] = o;
    }
    __syncthreads();

    // proj: X = A . pw^T + pb + resid
    f32x4 acc2[2];
    acc2[0] = (f32x4){0.f, 0.f, 0.f, 0.f};
    acc2[1] = (f32x4){0.f, 0.f, 0.f, 0.f};
    #pragma unroll 1
    for (int kc = 0; kc < 2; ++kc) {
        if (kc) __syncthreads();
        {
            int c = t >> 1, s2 = t & 1;
            const unsigned short* wr = pwb + (size_t)c * 128 + kc * 64 + s2 * 32;
            #pragma unroll
            for (int j8 = 0; j8 < 4; ++j8)
                *(u16x8*)&Wl[c * 72 + s2 * 32 + 8 * j8] = *(const u16x8*)&wr[8 * j8];
        }
        __syncthreads();
        #pragma unroll
        for (int half = 0; half < 2; ++half) {
            short8 pf = *(short8*)&Al[la * 136 + kc * 64 + half * 32 + g * 8];
            #pragma unroll
            for (int ct = 0; ct < 2; ++ct) {
                short8 bf = *(short8*)&Wl[((wv * 2 + ct) * 16 + la) * 72 + half * 32 + g * 8];
                acc2[ct] = __builtin_amdgcn_mfma_f32_16x16x32_bf16(pf, bf, acc2[ct], 0, 0, 0);
            }
        }
    }
    __syncthreads();
    #pragma unroll
    for (int ct = 0; ct < 2; ++ct) {
        int col = (wv * 2 + ct) * 16 + la;
        float bv = pb[col];
        #pragma unroll
        for (int r = 0; r < 4; ++r) {
            int row = g * 4 + r;
            Xf[row * 132 + col] = acc2[ct][r] + bv
                                + resid[(size_t)(rb + row) * 128 + col];
        }
    }
    __syncthreads();

    {   // LN(X) -> Al
        int r = t >> 4, seg = t & 15;
        float v[8];
        #pragma unroll
        for (int jj = 0; jj < 8; ++jj) v[jj] = Xf[r * 132 + seg * 8 + jj];
        float s = 0.f;
        #pragma unroll
        for (int jj = 0; jj < 8; ++jj) s += v[jj];
        s += __shfl_xor(s, 1); s += __shfl_xor(s, 2);
        s += __shfl_xor(s, 4); s += __shfl_xor(s, 8);
        float mu = s * (1.0f / 128.0f);
        float ss = 0.f;
        #pragma unroll
        for (int jj = 0; jj < 8; ++jj) { float d = v[jj] - mu; ss += d * d; }
        ss += __shfl_xor(ss, 1); ss += __shfl_xor(ss, 2);
        ss += __shfl_xor(ss, 4); ss += __shfl_xor(ss, 8);
        float rs = rsqrtf(ss * (1.0f / 128.0f) + LN_EPS);
        u16x8 o;
        #pragma unroll
        for (int jj = 0; jj < 8; ++jj) o[jj] = f2bf((v[jj] - mu) * rs);
        *(u16x8*)&Al[r * 136 + seg * 8] = o;
    }
    __syncthreads();

    short8 af[4];
    #pragma unroll
    for (int ks = 0; ks < 4; ++ks)
        af[ks] = *(short8*)&Al[la * 136 + ks * 32 + g * 8];

    // MLP GEMM1 -> Gl
    #pragma unroll 1
    for (int cc = 0; cc < 4; ++cc) {
        {
            int c = t >> 2, s2 = t & 3;
            const unsigned short* wr = w1b + (size_t)(cc * 64 + c) * 128 + s2 * 32;
            #pragma unroll
            for (int j8 = 0; j8 < 4; ++j8)
                *(u16x8*)&Wl[c * 136 + s2 * 32 + 8 * j8] = *(const u16x8*)&wr[8 * j8];
        }
        __syncthreads();
        f32x4 acc = (f32x4){0.f, 0.f, 0.f, 0.f};
        #pragma unroll
        for (int ks = 0; ks < 4; ++ks) {
            short8 bf = *(short8*)&Wl[(wv * 16 + la) * 136 + ks * 32 + g * 8];
            acc = __builtin_amdgcn_mfma_f32_16x16x32_bf16(af[ks], bf, acc, 0, 0, 0);
        }
        int col = cc * 64 + wv * 16 + la;
        float bv = b1[col];
        #pragma unroll
        for (int r = 0; r < 4; ++r)
            Gl[(g * 4 + r) * 264 + col] = f2bf(gelu_f(acc[r] + bv));
        __syncthreads();
    }

    // MLP GEMM2
    acc2[0] = (f32x4){0.f, 0.f, 0.f, 0.f};
    acc2[1] = (f32x4){0.f, 0.f, 0.f, 0.f};
    #pragma unroll 1
    for (int kc = 0; kc < 4; ++kc) {
        {
            int c = t >> 1, s2 = t & 1;
            const unsigned short* wr = w2b + (size_t)c * 256 + kc * 64 + s2 * 32;
            #pragma unroll
            for (int j8 = 0; j8 < 4; ++j8)
                *(u16x8*)&Wl[c * 72 + s2 * 32 + 8 * j8] = *(const u16x8*)&wr[8 * j8];
        }
        __syncthreads();
        #pragma unroll
        for (int half = 0; half < 2; ++half) {
            short8 pf = *(short8*)&Gl[la * 264 + kc * 64 + half * 32 + g * 8];
            #pragma unroll
            for (int ct = 0; ct < 2; ++ct) {
                short8 bf = *(short8*)&Wl[((wv * 2 + ct) * 16 + la) * 72 + half * 32 + g * 8];
                acc2[ct] = __builtin_amdgcn_mfma_f32_16x16x32_bf16(pf, bf, acc2[ct], 0, 0, 0);
            }
        }
        __syncthreads();
    }
    #pragma unroll
    for (int ct = 0; ct < 2; ++ct) {
        int col = (wv * 2 + ct) * 16 + la;
        float bv = b2[col];
        #pragma unroll
        for (int r = 0; r < 4; ++r) {
            int row = g * 4 + r;
            float y = acc2[ct][r] + bv + Xf[row * 132 + col];
            out[(size_t)(rb + row) * 128 + col] = y;
            if constexpr (QOUT) Xf[row * 132 + col] = y;
        }
    }

    if constexpr (QOUT) {
        __syncthreads();
        {   // LN(Y) -> Al
            int r = t >> 4, seg = t & 15;
            float v[8];
            #pragma unroll
            for (int jj = 0; jj < 8; ++jj) v[jj] = Xf[r * 132 + seg * 8 + jj];
            float s = 0.f;
            #pragma unroll
            for (int jj = 0; jj < 8; ++jj) s += v[jj];
            s += __shfl_xor(s, 1); s += __shfl_xor(s, 2);
            s += __shfl_xor(s, 4); s += __shfl_xor(s, 8);
            float mu = s * (1.0f / 128.0f);
            float ss = 0.f;
            #pragma unroll
            for (int jj = 0; jj < 8; ++jj) { float d = v[jj] - mu; ss += d * d; }
            ss += __shfl_xor(ss, 1); ss += __shfl_xor(ss, 2);
            ss += __shfl_xor(ss, 4); ss += __shfl_xor(ss, 8);
            float rs = rsqrtf(ss * (1.0f / 128.0f) + LN_EPS);
            u16x8 o;
            #pragma unroll
            for (int jj = 0; jj < 8; ++jj) o[jj] = f2bf((v[jj] - mu) * rs);
            *(u16x8*)&Al[r * 136 + seg * 8] = o;
        }
        __syncthreads();
        // a2 q-head GEMM: qout = (LN(Y) . qw^T + qb) * ATT_SCALE  (bf16)
        f32x4 acc3[2];
        acc3[0] = (f32x4){0.f, 0.f, 0.f, 0.f};
        acc3[1] = (f32x4){0.f, 0.f, 0.f, 0.f};
        #pragma unroll 1
        for (int kc = 0; kc < 2; ++kc) {
            if (kc) __syncthreads();
            {
                int c = t >> 1, s2 = t & 1;
                const unsigned short* wr = qwb + (size_t)c * 128 + kc * 64 + s2 * 32;
                #pragma unroll
                for (int j8 = 0; j8 < 4; ++j8)
                    *(u16x8*)&Wl[c * 72 + s2 * 32 + 8 * j8] = *(const u16x8*)&wr[8 * j8];
            }
            __syncthreads();
            #pragma unroll
            for (int half = 0; half < 2; ++half) {
                short8 pf = *(short8*)&Al[la * 136 + kc * 64 + half * 32 + g * 8];
                #pragma unroll
                for (int ct = 0; ct < 2; ++ct) {
                    short8 bf = *(short8*)&Wl[((wv * 2 + ct) * 16 + la) * 72 + half * 32 + g * 8];
                    acc3[ct] = __builtin_amdgcn_mfma_f32_16x16x32_bf16(pf, bf, acc3[ct], 0, 0, 0);
                }
            }
        }
        #pragma unroll
        for (int ct = 0; ct < 2; ++ct) {
            int col = (wv * 2 + ct) * 16 + la;
            float bv = qb[col];
            #pragma unroll
            for (int r = 0; r < 4; ++r) {
                int row = g * 4 + r;
                qout[(size_t)(rb + row) * 128 + col] = f2bf((acc3[ct][r] + bv) * ATT_SCALE);
            }
        }
    }
}

// ---------- fused mbproj(+SE,+zln) -> pm-FFN -> proj_out (gelu, transposed) ----------
__global__ __launch_bounds__(256)
void k_mbprojmlp(const float* __restrict__ dwo, const unsigned short* __restrict__ mbpwb,
                 const float* __restrict__ se, const float* __restrict__ zln,
                 const unsigned short* __restrict__ w1b, const float* __restrict__ b1,
                 const unsigned short* __restrict__ w2b, const float* __restrict__ b2,
                 const unsigned short* __restrict__ pob, const float* __restrict__ pb,
                 float* __restrict__ out) {
    __shared__ unsigned short Al[16 * 136];
    __shared__ unsigned short Wl[128 * 72];
    __shared__ unsigned short Gl[16 * 264];
    __shared__ float Xf[16 * 132];
    const int t = threadIdx.x;
    const int rb = blockIdx.x * 16;
    const int lane = t & 63, wv = t >> 6;
    const int la = lane & 15, g = lane >> 4;

    f32x4 acc2[2];
    acc2[0] = (f32x4){0.f, 0.f, 0.f, 0.f};
    acc2[1] = (f32x4){0.f, 0.f, 0.f, 0.f};
    #pragma unroll 1
    for (int kc = 0; kc < 8; ++kc) {
        if (kc) __syncthreads();
        {
            int r = t >> 4, seg = t & 15;
            const float* ar = dwo + (size_t)(rb + r) * 512 + kc * 64 + seg * 4;
            float4 v = *(const float4*)ar;
            const float* sp = se + kc * 64 + seg * 4;
            v.x *= sp[0]; v.y *= sp[1]; v.z *= sp[2]; v.w *= sp[3];
            unsigned short* dst = &Al[r * 136 + seg * 4];
            dst[0] = f2bf(v.x); dst[1] = f2bf(v.y);
            dst[2] = f2bf(v.z); dst[3] = f2bf(v.w);
        }
        {
            int c = t >> 1, s2 = t & 1;
            const unsigned short* wr = mbpwb + (size_t)c * 512 + kc * 64 + s2 * 32;
            #pragma unroll
            for (int j8 = 0; j8 < 4; ++j8)
                *(u16x8*)&Wl[c * 72 + s2 * 32 + 8 * j8] = *(const u16x8*)&wr[8 * j8];
        }
        __syncthreads();
        #pragma unroll
        for (int half = 0; half < 2; ++half) {
            short8 pf = *(short8*)&Al[la * 136 + half * 32 + g * 8];
            #pragma unroll
            for (int ct = 0; ct < 2; ++ct) {
                short8 bf = *(short8*)&Wl[((wv * 2 + ct) * 16 + la) * 72 + half * 32 + g * 8];
                acc2[ct] = __builtin_amdgcn_mfma_f32_16x16x32_bf16(pf, bf, acc2[ct], 0, 0, 0);
            }
        }
    }
    __syncthreads();
    #pragma unroll
    for (int ct = 0; ct < 2; ++ct) {
        int col = (wv * 2 + ct) * 16 + la;
        #pragma unroll
        for (int r = 0; r < 4; ++r) {
            int row = g * 4 + r;
            Xf[row * 132 + col] = acc2[ct][r] * BN_S
                                + zln[(size_t)(rb + row) * 128 + col];
        }
    }
    __syncthreads();

    {
        int r = t >> 4, seg = t & 15;
        u16x8 o;
        #pragma unroll
        for (int jj = 0; jj < 8; ++jj) o[jj] = f2bf(Xf[r * 132 + seg * 8 + jj]);
        *(u16x8*)&Al[r * 136 + seg * 8] = o;
    }
    __syncthreads();

    short8 af[4];
    #pragma unroll
    for (int ks = 0; ks < 4; ++ks)
        af[ks] = *(short8*)&Al[la * 136 + ks * 32 + g * 8];

    #pragma unroll 1
    for (int cc = 0; cc < 4; ++cc) {
        {
            int c = t >> 2, s2 = t & 3;
            const unsigned short* wr = w1b + (size_t)(cc * 64 + c) * 128 + s2 * 32;
            #pragma unroll
            for (int j8 = 0; j8 < 4; ++j8)
                *(u16x8*)&Wl[c * 136 + s2 * 32 + 8 * j8] = *(const u16x8*)&wr[8 * j8];
        }
        __syncthreads();
        f32x4 acc = (f32x4){0.f, 0.f, 0.f, 0.f};
        #pragma unroll
        for (int ks = 0; ks < 4; ++ks) {
            short8 bf = *(short8*)&Wl[(wv * 16 + la) * 136 + ks * 32 + g * 8];
            acc = __builtin_amdgcn_mfma_f32_16x16x32_bf16(af[ks], bf, acc, 0, 0, 0);
        }
        int col = cc * 64 + wv * 16 + la;
        float bv = b1[col];
        #pragma unroll
        for (int r = 0; r < 4; ++r)
            Gl[(g * 4 + r) * 264 + col] = f2bf(gelu_f(acc[r] + bv));
        __syncthreads();
    }

    acc2[0] = (f32x4){0.f, 0.f, 0.f, 0.f};
    acc2[1] = (f32x4){0.f, 0.f, 0.f, 0.f};
    #pragma unroll 1
    for (int kc = 0; kc < 4; ++kc) {
        {
            int c = t >> 1, s2 = t & 1;
            const unsigned short* wr = w2b + (size_t)c * 256 + kc * 64 + s2 * 32;
            #pragma unroll
            for (int j8 = 0; j8 < 4; ++j8)
                *(u16x8*)&Wl[c * 72 + s2 * 32 + 8 * j8] = *(const u16x8*)&wr[8 * j8];
        }
        __syncthreads();
        #pragma unroll
        for (int half = 0; half < 2; ++half) {
            short8 pf = *(short8*)&Gl[la * 264 + kc * 64 + half * 32 + g * 8];
            #pragma unroll
            for (int ct = 0; ct < 2; ++ct) {
                short8 bf = *(short8*)&Wl[((wv * 2 + ct) * 16 + la) * 72 + half * 32 + g * 8];
                acc2[ct] = __builtin_amdgcn_mfma_f32_16x16x32_bf16(pf, bf, acc2[ct], 0, 0, 0);
            }
        }
        __syncthreads();
    }
    #pragma unroll
    for (int ct = 0; ct < 2; ++ct) {
        int col = (wv * 2 + ct) * 16 + la;
        float bv = b2[col];
        #pragma unroll
        for (int r = 0; r < 4; ++r) {
            int row = g * 4 + r;
            float y = acc2[ct][r] + bv + Xf[row * 132 + col];
            Al[row * 136 + col] = f2bf(y);
        }
    }
    __syncthreads();

    f32x4 acc3[2];
    acc3[0] = (f32x4){0.f, 0.f, 0.f, 0.f};
    acc3[1] = (f32x4){0.f, 0.f, 0.f, 0.f};
    #pragma unroll 1
    for (int kc = 0; kc < 2; ++kc) {
        if (kc) __syncthreads();
        {
            int c = t >> 1, s2 = t & 1;
            const unsigned short* wr = pob + (size_t)c * 128 + kc * 64 + s2 * 32;
            #pragma unroll
            for (int j8 = 0; j8 < 4; ++j8)
                *(u16x8*)&Wl[c * 72 + s2 * 32 + 8 * j8] = *(const u16x8*)&wr[8 * j8];
        }
        __syncthreads();
        #pragma unroll
        for (int half = 0; half < 2; ++half) {
            short8 pf = *(short8*)&Al[la * 136 + kc * 64 + half * 32 + g * 8];
            #pragma unroll
            for (int ct = 0; ct < 2; ++ct) {
                short8 bf = *(short8*)&Wl[((wv * 2 + ct) * 16 + la) * 72 + half * 32 + g * 8];
                acc3[ct] = __builtin_amdgcn_mfma_f32_16x16x32_bf16(pf, bf, acc3[ct], 0, 0, 0);
            }
        }
    }
    #pragma unroll
    for (int ct = 0; ct < 2; ++ct) {
        int col = (wv * 2 + ct) * 16 + la;
        float bv = pb[col];
        float4 o4;
        o4.x = gelu_f(acc3[ct][0] + bv);
        o4.y = gelu_f(acc3[ct][1] + bv);
        o4.z = gelu_f(acc3[ct][2] + bv);
        o4.w = gelu_f(acc3[ct][3] + bv);
        *(float4*)&out[(size_t)col * PBEV + rb + g * 4] = o4;
    }
}

// ---------- MFMA flash attention (S^T trick, shfl P re-layout) ----------
template<int MODE>
__global__ __launch_bounds__(MODE == 1 ? 512 : 256)
void k_attn_mfma(const unsigned short* __restrict__ qh, const unsigned short* __restrict__ kh,
                 const unsigned short* __restrict__ vh, float* __restrict__ aout) {
    constexpr int WAVES = (MODE == 1) ? 8 : 4;
    constexpr int QTPW  = (MODE == 1) ? 3 : 1;
    constexpr int T = WAVES * 64;
    const int l = blockIdx.x, m = blockIdx.y;
    const int xw = l >> 3, yw = l & 7;
    const int t = threadIdx.x;
    const int lane = t & 63, wv = t >> 6;
    const int la = lane & 15, g = lane >> 4;

    __shared__ unsigned short Kl[KROWS * 40];
    __shared__ unsigned short Vt[32 * 312];

    for (int i = t; i < KROWS * 4; i += T) {
        int row = i >> 2, seg = i & 3;
        int n = row / 48, kk = row % 48;
        int k1 = kk / 12, k2 = kk % 12;
        int h, w;
        if (MODE == 1) { h = xw * 4 + k1;  w = yw * 12 + k2; }
        else           { h = k1 * 8 + xw;  w = k2 * 8 + yw;  }
        size_t src = ((size_t)(n * PIMG + h * FWW + w)) * 128 + m * DHD + seg * 8;
        short8 kv = *(const short8*)&kh[src];
        *(short8*)&Kl[row * 40 + seg * 8] = kv;
        short8 vv = *(const short8*)&vh[src];
        #pragma unroll
        for (int j = 0; j < 8; ++j)
            Vt[(seg * 8 + j) * 312 + row] = (unsigned short)vv[j];
    }

    short8 qf[QTPW];
    #pragma unroll
    for (int qt = 0; qt < QTPW; ++qt) {
        int q = (wv * QTPW + qt) * 16 + la;
        int row;
        if (MODE == 1) {
            int n = q >> 6, ww = q & 63;
            row = n * PBEV + (xw * 8 + (ww >> 3)) * 64 + yw * 8 + (ww & 7);
        } else {
            row = ((q >> 3) * 8 + xw) * 64 + (q & 7) * 8 + yw;
        }
        qf[qt] = *(const short8*)&qh[(size_t)row * 128 + m * DHD + g * 8];
    }
    __syncthreads();

    f32x4 acc[QTPW][2];
    float srow[QTPW];
    #pragma unroll
    for (int qt = 0; qt < QTPW; ++qt) {
        acc[qt][0] = (f32x4){0.f, 0.f, 0.f, 0.f};
        acc[qt][1] = (f32x4){0.f, 0.f, 0.f, 0.f};
        srow[qt] = 0.f;
    }
    const int a0 = la + 32 * (g & 1);
    const int a1 = a0 + 16;
    const bool selA = (g < 2);

    #pragma unroll 1
    for (int c = 0; c < 9; ++c) {
        const int kk0 = c * 32;
        short8 kf0 = *(short8*)&Kl[(kk0 + la) * 40 + g * 8];
        short8 kf1 = *(short8*)&Kl[(kk0 + 16 + la) * 40 + g * 8];
        short8 vf0 = *(short8*)&Vt[la * 312 + kk0 + g * 8];
        short8 vf1 = *(short8*)&Vt[(16 + la) * 312 + kk0 + g * 8];
        #pragma unroll
        for (int qt = 0; qt < QTPW; ++qt) {
            f32x4 sA = __builtin_amdgcn_mfma_f32_16x16x32_bf16(kf0, qf[qt], (f32x4){0.f,0.f,0.f,0.f}, 0, 0, 0);
            f32x4 sB = __builtin_amdgcn_mfma_f32_16x16x32_bf16(kf1, qf[qt], (f32x4){0.f,0.f,0.f,0.f}, 0, 0, 0);
            float pA[4], pB[4];
            #pragma unroll
            for (int r = 0; r < 4; ++r) { pA[r] = __expf(sA[r]); pB[r] = __expf(sB[r]); }
            srow[qt] += ((pA[0] + pA[1]) + (pA[2] + pA[3]))
                      + ((pB[0] + pB[1]) + (pB[2] + pB[3]));
            unsigned int loA = (unsigned int)f2bf(pA[0]) | ((unsigned int)f2bf(pA[1]) << 16);
            unsigned int hiA = (unsigned int)f2bf(pA[2]) | ((unsigned int)f2bf(pA[3]) << 16);
            unsigned int loB = (unsigned int)f2bf(pB[0]) | ((unsigned int)f2bf(pB[1]) << 16);
            unsigned int hiB = (unsigned int)f2bf(pB[2]) | ((unsigned int)f2bf(pB[3]) << 16);
            int w0A = __shfl((int)loA, a0); int w0B = __shfl((int)loB, a0);
            int w1A = __shfl((int)hiA, a0); int w1B = __shfl((int)hiB, a0);
            int w2A = __shfl((int)loA, a1); int w2B = __shfl((int)loB, a1);
            int w3A = __shfl((int)hiA, a1); int w3B = __shfl((int)hiB, a1);
            union { int u[4]; short8 s; } pu;
            pu.u[0] = selA ? w0A : w0B;
            pu.u[1] = selA ? w1A : w1B;
            pu.u[2] = selA ? w2A : w2B;
            pu.u[3] = selA ? w3A : w3B;
            acc[qt][0] = __builtin_amdgcn_mfma_f32_16x16x32_bf16(pu.s, vf0, acc[qt][0], 0, 0, 0);
            acc[qt][1] = __builtin_amdgcn_mfma_f32_16x16x32_bf16(pu.s, vf1, acc[qt][1], 0, 0, 0);
        }
    }

    #pragma unroll
    for (int qt = 0; qt < QTPW; ++qt) {
        float s = srow[qt];
        s += __shfl_xor(s, 16);
        s += __shfl_xor(s, 32);
        #pragma unroll
        for (int r = 0; r < 4; ++r) {
            float sq = __shfl(s, g * 4 + r);
            float inv = 1.0f / sq;
            int q = (wv * QTPW + qt) * 16 + g * 4 + r;
            size_t orow;
            if (MODE == 1) {
                int n = q >> 6, ww = q & 63;
                orow = (size_t)(l * 64 + ww) * 6 + n;
            } else {
                orow = (size_t)(((q >> 3) * 8 + xw) * 64 + (q & 7) * 8 + yw);
            }
            float* ap = aout + orow * 128 + m * DHD;
            ap[la]      = acc[qt][0][r] * inv;
            ap[16 + la] = acc[qt][1][r] * inv;
        }
    }
}

// ---------- depthwise 3x3 + gelu + SE partials ----------
__global__ void k_dwconv(const float* __restrict__ ex, const float* __restrict__ dwgt,
                         float* __restrict__ dwout, float* __restrict__ separt) {
    const int TILE = 16;
    int ch = threadIdx.x;
    int hw0 = blockIdx.x * TILE;
    float wreg[9];
    #pragma unroll
    for (int i = 0; i < 9; ++i) wreg[i] = dwgt[ch * 9 + i];
    float sacc = 0.f;
    for (int ti = 0; ti < TILE; ++ti) {
        int hw = hw0 + ti;
        int h = hw >> 6, w = hw & 63;
        float s = 0.f;
        #pragma unroll
        for (int dy = -1; dy <= 1; ++dy) {
            int h2 = h + dy;
            if (h2 < 0 || h2 >= 64) continue;
            #pragma unroll
            for (int dx = -1; dx <= 1; ++dx) {
                int w2 = w + dx;
                if (w2 < 0 || w2 >= 64) continue;
                s += ex[((size_t)(h2 * 64 + w2)) * 512 + ch] * wreg[(dy + 1) * 3 + (dx + 1)];
            }
        }
        float o = gelu_f(s * BN_S);
        dwout[(size_t)hw * 512 + ch] = o;
        sacc += o;
    }
    separt[(size_t)blockIdx.x * 512 + ch] = sacc;
}

// ---------- SE reduce stage 1 ----------
__global__ void k_sered(const float* __restrict__ separt, float* __restrict__ separt2) {
    int t = threadIdx.x, bb = blockIdx.x;
    float s = 0.f;
    #pragma unroll
    for (int i = 0; i < 16; ++i)
        s += separt[(size_t)(bb * 16 + i) * 512 + t];
    separt2[(size_t)bb * 512 + t] = s;
}

// ---------- SE final ----------
__global__ void k_se(const float* __restrict__ separt2,
                     const float* __restrict__ s1w, const float* __restrict__ s1b,
                     const float* __restrict__ s2w, const float* __restrict__ s2b,
                     float* __restrict__ se) {
    __shared__ float mean[512];
    __shared__ float s1[32];
    int t = threadIdx.x;
    float s = 0.f;
    #pragma unroll
    for (int b = 0; b < 16; ++b) s += separt2[b * 512 + t];
    mean[t] = s * (1.0f / 4096.0f);
    __syncthreads();
    int u = t >> 4, seg = t & 15;
    float acc = 0.f;
    #pragma unroll
    for (int j = 0; j < 32; ++j) {
        int c = seg + 16 * j;
        acc += mean[c] * s1w[u * 512 + c];
    }
    acc += __shfl_xor(acc, 1); acc += __shfl_xor(acc, 2);
    acc += __shfl_xor(acc, 4); acc += __shfl_xor(acc, 8);
    if (seg == 0) s1[u] = gelu_f(acc + s1b[u]);
    __syncthreads();
    float a2 = s2b[t];
    #pragma unroll
    for (int j = 0; j < 32; ++j) a2 += s1[j] * s2w[t * 32 + j];
    se[t] = 1.0f / (1.0f + __expf(-a2));
}

extern "C" void kernel_launch(void* const* d_in, const int* in_sizes, int n_in,
                              void* d_out, int out_size, void* d_ws, size_t ws_size,
                              hipStream_t stream) {
    (void)in_sizes; (void)n_in; (void)out_size; (void)ws_size;
    const float* x      = (const float*)d_in[1];
    const float* feat   = (const float*)d_in[2];
    const float* I_inv  = (const float*)d_in[3];
    const float* E_inv  = (const float*)d_in[4];
    const float* bev    = (const float*)d_in[5];
    const float* fl_w   = (const float*)d_in[6];
    const float* fp_w   = (const float*)d_in[7];
    const float* be_w   = (const float*)d_in[8];
    const float* be_b   = (const float*)d_in[9];
    const float* ie_w   = (const float*)d_in[10];
    const float* ce_w   = (const float*)d_in[11];
    const float* a1_qw  = (const float*)d_in[12];
    const float* a1_qb  = (const float*)d_in[13];
    const float* a1_kw  = (const float*)d_in[14];
    const float* a1_kb  = (const float*)d_in[15];
    const float* a1_vw  = (const float*)d_in[16];
    const float* a1_vb  = (const float*)d_in[17];
    const float* a1_pw  = (const float*)d_in[18];
    const float* a1_pb  = (const float*)d_in[19];
    const float* a2_qw  = (const float*)d_in[20];
    const float* a2_qb  = (const float*)d_in[21];
    const float* a2_kw  = (const float*)d_in[22];
    const float* a2_kb  = (const float*)d_in[23];
    const float* a2_vw  = (const float*)d_in[24];
    const float* a2_vb  = (const float*)d_in[25];
    const float* a2_pw  = (const float*)d_in[26];
    const float* a2_pb  = (const float*)d_in[27];
    const float* m1_w1  = (const float*)d_in[28];
    const float* m1_b1  = (const float*)d_in[29];
    const float* m1_w2  = (const float*)d_in[30];
    const float* m1_b2  = (const float*)d_in[31];
    const float* m2_w1  = (const float*)d_in[32];
    const float* m2_b1  = (const float*)d_in[33];
    const float* m2_w2  = (const float*)d_in[34];
    const float* m2_b2  = (const float*)d_in[35];
    const float* mb_ew  = (const float*)d_in[36];
    const float* mb_dw  = (const float*)d_in[37];
    const float* mb_s1w = (const float*)d_in[38];
    const float* mb_s1b = (const float*)d_in[39];
    const float* mb_s2w = (const float*)d_in[40];
    const float* mb_s2b = (const float*)d_in[41];
    const float* mb_pw  = (const float*)d_in[42];
    const float* pm_w1  = (const float*)d_in[43];
    const float* pm_b1  = (const float*)d_in[44];
    const float* pm_w2  = (const float*)d_in[45];
    const float* pm_b2  = (const float*)d_in[46];
    const float* po_w   = (const float*)d_in[47];
    const float* po_b   = (const float*)d_in[48];

    float* ws = (float*)d_ws;
    float* x_cl   = ws + 0;          // 524288
    unsigned short* key_b = (unsigned short*)(ws + 524288);
    unsigned short* val_b = (unsigned short*)(ws + 1703936);
    unsigned short* qh1b  = (unsigned short*)(ws + 2883584);
    unsigned short* kh1b  = (unsigned short*)(ws + 4456448);
    unsigned short* vh1b  = (unsigned short*)(ws + 5636096);
    unsigned short* kh2b  = (unsigned short*)(ws + 6815744);
    unsigned short* vh2b  = (unsigned short*)(ws + 7995392);
    float* abuf   = ws + 9175040;    // 3145728
    float* qimg   = ws + 12320768;
    float* qimg2  = ws + 12845056;
    float* zln    = ws + 13369344;
    float* abuf2  = ws + 13893632;
    float* expandb = ws + 14942208;  // 2097152
    float* dwout   = ws + 17039360;  // 2097152
    float* separt  = ws + 19136512;  // 131072
    float* separt2 = ws + 19267584;  // 8192
    float* sebuf   = ws + 19275776;  // 512
    unsigned short* wb = (unsigned short*)(ws + 19276288);  // 507904 u16
    unsigned short* qh2b = qh1b;

    // prep: weights -> bf16 arena + x transpose (one launch)
    k_prep<<<760, 256, 0, stream>>>(fp_w, fl_w, a1_qw, a1_kw, a2_kw, a1_vw, a2_vw,
                                    a1_pw, m1_w1, m1_w2, a2_qw, a2_pw, m2_w1, m2_w2,
                                    mb_ew, mb_pw, pm_w1, pm_w2, po_w, wb, x, x_cl);

    // key/val (feature transpose + img-embed fused), bf16 out
    k_gemm_mfma<64,1,128, 1,0,0,0,0, 0,0,0,1, 1,0,0,1,1><<<288, 256, 0, stream>>>(
        feat, (const float*)(wb + OFF_FP), ie_w, E_inv, I_inv,
        (const float*)(wb + OFF_FL), ce_w, val_b, nullptr, key_b);

    // q head (query gen fused, pre-scaled); k/v heads merged dual
    k_gemm_mfma<64,1,128, 3,1,1,0,0, 0,0,0,0, 1,1,0,0,1><<<384, 256, 0, stream>>>(
        nullptr, (const float*)(wb + OFF_A1QW), a1_qb, bev, x_cl, be_w, be_b,
        (void*)E_inv, (float*)ce_w, qh1b);
    {
        KVJob jk = { key_b, wb + OFF_A1KW, a1_kb, wb + OFF_A2KW, a2_kb, kh1b, kh2b };
        KVJob jv = { val_b, wb + OFF_A1VW, a1_vb, wb + OFF_A2VW, a2_vb, vh1b, vh2b };
        k_kvheads<<<576, 256, 0, stream>>>(jk, jv);
    }
    k_attn_mfma<1><<<dim3(64, HEADS), 512, 0, stream>>>(qh1b, kh1b, vh1b, abuf);
    // stage-1 projmlp also emits qh2b (a2 q-head fused, pre-scaled)
    k_projmlp<2,1><<<256, 256, 0, stream>>>(abuf, wb + OFF_A1PW, a1_pb, x_cl,
                                            wb + OFF_M1W1, m1_b1, wb + OFF_M1W2, m1_b2,
                                            qimg, wb + OFF_A2QW, a2_qb, qh2b);

    // stage 2
    k_attn_mfma<2><<<dim3(64, HEADS), 256, 0, stream>>>(qh2b, kh2b, vh2b, abuf2);
    k_projmlp<0,0><<<256, 256, 0, stream>>>(abuf2, wb + OFF_A2PW, a2_pb, qimg,
                                            wb + OFF_M2W1, m2_b1, wb + OFF_M2W2, m2_b2,
                                            qimg2, nullptr, nullptr, nullptr);

    // stage 3
    k_gemm_mfma<16,1,512, 0,1,0,1,1, 0,0,0,0, 0,0,1,0,1><<<dim3(256, 4), 256, 0, stream>>>(
        qimg2, (const float*)(wb + OFF_MBEW), nullptr, nullptr, nullptr, nullptr,
        nullptr, nullptr, zln, expandb);
    k_dwconv<<<256, 512, 0, stream>>>(expandb, mb_dw, dwout, separt);
    k_sered<<<16, 512, 0, stream>>>(separt, separt2);
    k_se<<<1, 512, 0, stream>>>(separt2, mb_s1w, mb_s1b, mb_s2w, mb_s2b, sebuf);
    k_mbprojmlp<<<256, 256, 0, stream>>>(dwout, wb + OFF_MBPW, sebuf, zln,
                                         wb + OFF_PMW1, pm_b1, wb + OFF_PMW2, pm_b2,
                                         wb + OFF_POW, po_b, (float*)d_out);
}

// Round 15
// 150.127 us; speedup vs baseline: 1.1517x; 1.0103x over previous
//
#include <hip/hip_runtime.h>
#include <math.h>

#define NV 6
#define FHH 32
#define FWW 96
#define PIMG (FHH*FWW)   // 3072
#define HH 64
#define WWD 64
#define PBEV (HH*WWD)    // 4096
#define HEADS 4
#define DHD 32
#define KROWS 288
#define BN_S 0.9999950000374996f
#define LN_EPS 1e-5f
#define ATT_SCALE 0.17677669529663687f  // 32^-0.5

typedef __attribute__((ext_vector_type(8))) short short8;
typedef __attribute__((ext_vector_type(4))) float f32x4;
typedef __attribute__((ext_vector_type(8))) unsigned short u16x8;

__device__ __forceinline__ float gelu_f(float x) {
    return 0.5f * x * (1.0f + erff(x * 0.70710678118654752f));
}

__device__ __forceinline__ unsigned short f2bf(float f) {
    union { float f; unsigned int u; } c; c.f = f;
    unsigned int r = (c.u + 0x7fffu + ((c.u >> 16) & 1u)) >> 16;
    return (unsigned short)r;
}

__device__ __forceinline__ float bf2f(unsigned short u) {
    union { unsigned int u; float f; } c; c.u = ((unsigned int)u) << 16;
    return c.f;
}

// bf16 weight arena offsets (u16 elements)
#define OFF_FP    0
#define OFF_FL    16384
#define OFF_A1QW  32768
#define OFF_A1KW  49152
#define OFF_A2KW  65536
#define OFF_A1VW  81920
#define OFF_A2VW  98304
#define OFF_A1PW  114688
#define OFF_M1W1  131072
#define OFF_M1W2  163840
#define OFF_A2QW  196608
#define OFF_A2PW  212992
#define OFF_M2W1  229376
#define OFF_M2W2  262144
#define OFF_MBEW  294912
#define OFF_MBPW  360448
#define OFF_PMW1  425984
#define OFF_PMW2  458752
#define OFF_POW   491520
#define WTOTAL    507904

// ---------- prep: weight f32->bf16 arena (blocks 0..247) + x transpose (248..759) ----------
__global__ void k_prep(const float* p0, const float* p1, const float* p2,
                       const float* p3, const float* p4, const float* p5,
                       const float* p6, const float* p7, const float* p8,
                       const float* p9, const float* p10, const float* p11,
                       const float* p12, const float* p13, const float* p14,
                       const float* p15, const float* p16, const float* p17,
                       const float* p18, unsigned short* wb,
                       const float* __restrict__ x, float* __restrict__ x_cl) {
    __shared__ float tile[32][33];
    if (blockIdx.x < 248) {
        int idx = (blockIdx.x * 256 + threadIdx.x) * 8;
        if (idx >= WTOTAL) return;
        const float* s;
        if      (idx < OFF_FL)   s = p0  + idx;
        else if (idx < OFF_A1QW) s = p1  + (idx - OFF_FL);
        else if (idx < OFF_A1KW) s = p2  + (idx - OFF_A1QW);
        else if (idx < OFF_A2KW) s = p3  + (idx - OFF_A1KW);
        else if (idx < OFF_A1VW) s = p4  + (idx - OFF_A2KW);
        else if (idx < OFF_A2VW) s = p5  + (idx - OFF_A1VW);
        else if (idx < OFF_A1PW) s = p6  + (idx - OFF_A2VW);
        else if (idx < OFF_M1W1) s = p7  + (idx - OFF_A1PW);
        else if (idx < OFF_M1W2) s = p8  + (idx - OFF_M1W1);
        else if (idx < OFF_A2QW) s = p9  + (idx - OFF_M1W2);
        else if (idx < OFF_A2PW) s = p10 + (idx - OFF_A2QW);
        else if (idx < OFF_M2W1) s = p11 + (idx - OFF_A2PW);
        else if (idx < OFF_M2W2) s = p12 + (idx - OFF_M2W1);
        else if (idx < OFF_MBEW) s = p13 + (idx - OFF_M2W2);
        else if (idx < OFF_MBPW) s = p14 + (idx - OFF_MBEW);
        else if (idx < OFF_PMW1) s = p15 + (idx - OFF_MBPW);
        else if (idx < OFF_PMW2) s = p16 + (idx - OFF_PMW1);
        else if (idx < OFF_POW)  s = p17 + (idx - OFF_PMW2);
        else                     s = p18 + (idx - OFF_POW);
        float4 v0 = *(const float4*)&s[0];
        float4 v1 = *(const float4*)&s[4];
        u16x8 o = { f2bf(v0.x), f2bf(v0.y), f2bf(v0.z), f2bf(v0.w),
                    f2bf(v1.x), f2bf(v1.y), f2bf(v1.z), f2bf(v1.w) };
        *(u16x8*)&wb[idx] = o;
    } else {
        int bb = blockIdx.x - 248;
        int p0_ = (bb & 127) * 32, c0 = (bb >> 7) * 32;
        int tp = threadIdx.x & 31, tg = threadIdx.x >> 5;
        #pragma unroll
        for (int i = 0; i < 4; ++i)
            tile[tg + 8 * i][tp] = x[(size_t)(c0 + tg + 8 * i) * PBEV + p0_ + tp];
        __syncthreads();
        #pragma unroll
        for (int i = 0; i < 4; ++i)
            x_cl[(size_t)(p0_ + tg + 8 * i) * 128 + c0 + tp] = tile[tp][tg + 8 * i];
    }
}

// ---------- universal MFMA GEMM device body ----------
template<int BR, int KCH, int NOT, int AMODE, int LNF, int BIASF, int ACT, int SCL,
         int ADDM, int STM, int ASCL, int DUAL, int OUTBF, int QSCL, int WRLN,
         int EMB, int WBF>
__device__ __forceinline__
void gemm_body(unsigned short* __restrict__ Al, unsigned short* __restrict__ Wl,
               const float* __restrict__ A, const float* __restrict__ W,
               const float* __restrict__ bias, const float* __restrict__ addb,
               const float* __restrict__ ascale, const float* __restrict__ W2,
               const float* __restrict__ bias2, void* __restrict__ out2v,
               float* __restrict__ aux, void* __restrict__ outv,
               int rb, int co, int wrln_on) {
    constexpr int NI = KCH * 128;
    constexpr int RW = BR / 16;
    constexpr int CT = 8 / (4 / RW);
    const int t = threadIdx.x;
    const int lane = t & 63, wv = t >> 6;
    const int la = lane & 15, g = lane >> 4;
    const int roww = wv % RW, colg = wv / RW;

    if constexpr (KCH == 1) {
        if constexpr (AMODE == 1) {
            int n = rb / PIMG, p0 = rb % PIMG;
            int r = t & 63, kseg = t >> 6;
            #pragma unroll
            for (int j8 = 0; j8 < 4; ++j8) {
                u16x8 o;
                #pragma unroll
                for (int j = 0; j < 8; ++j) {
                    int k = kseg * 32 + j8 * 8 + j;
                    float v = A[((size_t)(n * 128 + k)) * PIMG + p0 + r];
                    o[j] = f2bf(fmaxf(v * BN_S, 0.0f));
                }
                *(u16x8*)&Al[r * 136 + kseg * 32 + j8 * 8] = o;
            }
        } else {
            constexpr int TPR = 256 / BR;
            constexpr int CPT = 128 / TPR;
            int r = t / TPR, seg = t % TPR;
            float v[CPT];
            if constexpr (AMODE == 3) {
                int grow = rb + r;
                int n = grow >> 12, p = grow & 4095;
                const float* E = ((const float*)out2v) + n * 16;
                const float* cew = (const float*)aux;
                float bp0 = addb[p], bp1 = addb[PBEV + p];
                float ss = 0.f;
                #pragma unroll
                for (int j = 0; j < CPT; ++j) {
                    int c = seg * CPT + j;
                    float cemb = E[3]  * cew[c*4+0] + E[7]  * cew[c*4+1]
                               + E[11] * cew[c*4+2] + E[15] * cew[c*4+3];
                    float emb = bp0 * W2[c*2] + bp1 * W2[c*2+1] + bias2[c] - cemb;
                    v[j] = emb; ss += emb * emb;
                }
                #pragma unroll
                for (int o = 1; o < TPR; o <<= 1) ss += __shfl_xor(ss, o, 64);
                float invn = 1.0f / (sqrtf(ss) + 1e-7f);
                const float* xr = ascale + (size_t)p * 128 + seg * CPT;
                #pragma unroll
                for (int j = 0; j < CPT; ++j) v[j] = v[j] * invn + xr[j];
            } else {
                const float* ar = A + (size_t)(rb + r) * 128 + seg * CPT;
                #pragma unroll
                for (int j4 = 0; j4 < CPT / 4; ++j4)
                    *(float4*)&v[4 * j4] = *(const float4*)&ar[4 * j4];
            }
            if constexpr (LNF) {
                float s = 0.f;
                #pragma unroll
                for (int j = 0; j < CPT; ++j) s += v[j];
                #pragma unroll
                for (int o = 1; o < TPR; o <<= 1) s += __shfl_xor(s, o, 64);
                float mu = s * (1.0f / 128.0f);
                float ss = 0.f;
                #pragma unroll
                for (int j = 0; j < CPT; ++j) { float d = v[j] - mu; ss += d * d; }
                #pragma unroll
                for (int o = 1; o < TPR; o <<= 1) ss += __shfl_xor(ss, o, 64);
                float rs = rsqrtf(ss * (1.0f / 128.0f) + LN_EPS);
                #pragma unroll
                for (int j = 0; j < CPT; ++j) v[j] = (v[j] - mu) * rs;
                if constexpr (WRLN) {
                    if (wrln_on) {
                        #pragma unroll
                        for (int j4 = 0; j4 < CPT / 4; ++j4) {
                            float4 o4 = {v[4*j4], v[4*j4+1], v[4*j4+2], v[4*j4+3]};
                            *(float4*)&aux[(size_t)(rb + r) * 128 + seg * CPT + 4 * j4] = o4;
                        }
                    }
                }
            }
            #pragma unroll
            for (int j8 = 0; j8 < CPT / 8; ++j8) {
                u16x8 o;
                #pragma unroll
                for (int j = 0; j < 8; ++j) o[j] = f2bf(v[8 * j8 + j]);
                *(u16x8*)&Al[r * 136 + seg * CPT + 8 * j8] = o;
            }
        }
    }

    #pragma unroll 1
    for (int set = 0; set <= DUAL; ++set) {
        const float* Wc = set ? W2 : W;
        const float* bc = set ? bias2 : bias;
        void* ocv = set ? out2v : outv;
        f32x4 acc[CT];
        #pragma unroll
        for (int i = 0; i < CT; ++i) acc[i] = (f32x4){0.f, 0.f, 0.f, 0.f};

        #pragma unroll 1
        for (int kc = 0; kc < KCH; ++kc) {
            if (set || kc) __syncthreads();
            #pragma unroll
            for (int i = 0; i < 8; ++i) {
                int chunk = i * 256 + t;
                int c = chunk >> 4, k8 = chunk & 15;
                if constexpr (WBF) {
                    const unsigned short* wr = ((const unsigned short*)Wc)
                        + (size_t)(co + c) * NI + kc * 128 + k8 * 8;
                    *(u16x8*)&Wl[c * 136 + k8 * 8] = *(const u16x8*)wr;
                } else {
                    const float* wr = &Wc[(size_t)(co + c) * NI + kc * 128 + k8 * 8];
                    float4 v0 = *(const float4*)&wr[0];
                    float4 v1 = *(const float4*)&wr[4];
                    u16x8 o = { f2bf(v0.x), f2bf(v0.y), f2bf(v0.z), f2bf(v0.w),
                                f2bf(v1.x), f2bf(v1.y), f2bf(v1.z), f2bf(v1.w) };
                    *(u16x8*)&Wl[c * 136 + k8 * 8] = o;
                }
            }
            __syncthreads();
            short8 af[4];
            #pragma unroll
            for (int ks = 0; ks < 4; ++ks)
                af[ks] = *(short8*)&Al[(roww * 16 + la) * 136 + ks * 32 + g * 8];
            #pragma unroll
            for (int cti = 0; cti < CT; ++cti) {
                int ct = colg * CT + cti;
                #pragma unroll
                for (int ks = 0; ks < 4; ++ks) {
                    short8 bf = *(short8*)&Wl[(ct * 16 + la) * 136 + ks * 32 + g * 8];
                    acc[cti] = __builtin_amdgcn_mfma_f32_16x16x32_bf16(af[ks], bf, acc[cti], 0, 0, 0);
                }
            }
        }

        float embv[CT][4];
        float invr[4];
        if constexpr (EMB) {
            if (set == 0) {
                int n = rb / PIMG;
                const float* Ii = ascale + n * 9;
                const float* E  = addb + n * 16;
                float d0[4], d1[4], d2[4], d3[4];
                #pragma unroll
                for (int r = 0; r < 4; ++r) {
                    int row = rb + roww * 16 + g * 4 + r;
                    int p = row % PIMG;
                    int hh = p / FWW, wp = p % FWW;
                    float gx = (float)wp * (768.0f / 95.0f);
                    float gy = (float)hh * (256.0f / 31.0f);
                    float c0 = Ii[0]*gx + Ii[1]*gy + Ii[2];
                    float c1 = Ii[3]*gx + Ii[4]*gy + Ii[5];
                    float c2 = Ii[6]*gx + Ii[7]*gy + Ii[8];
                    d0[r] = E[0]*c0  + E[1]*c1  + E[2]*c2  + E[3];
                    d1[r] = E[4]*c0  + E[5]*c1  + E[6]*c2  + E[7];
                    d2[r] = E[8]*c0  + E[9]*c1  + E[10]*c2 + E[11];
                    d3[r] = E[12]*c0 + E[13]*c1 + E[14]*c2 + E[15];
                }
                float ssr[4] = {0.f, 0.f, 0.f, 0.f};
                #pragma unroll
                for (int cti = 0; cti < CT; ++cti) {
                    int col = co + (colg * CT + cti) * 16 + la;
                    const float* iw = bias + col * 4;
                    const float* cw = bias2 + col * 4;
                    float cemb = E[3]*cw[0] + E[7]*cw[1] + E[11]*cw[2] + E[15]*cw[3];
                    #pragma unroll
                    for (int r = 0; r < 4; ++r) {
                        float e = d0[r]*iw[0] + d1[r]*iw[1] + d2[r]*iw[2] + d3[r]*iw[3] - cemb;
                        embv[cti][r] = e;
                        ssr[r] += e * e;
                    }
                }
                #pragma unroll
                for (int r = 0; r < 4; ++r) {
                    float s = ssr[r];
                    s += __shfl_xor(s, 1); s += __shfl_xor(s, 2);
                    s += __shfl_xor(s, 4); s += __shfl_xor(s, 8);
                    invr[r] = 1.0f / (sqrtf(s) + 1e-7f);
                }
            }
        }

        #pragma unroll
        for (int cti = 0; cti < CT; ++cti) {
            int ct = colg * CT + cti;
            int col = co + ct * 16 + la;
            float bv = 0.f;
            if constexpr (BIASF) bv = bc[col];
            if constexpr (STM == 1) {
                int row0 = rb + roww * 16 + g * 4;
                float vv[4];
                #pragma unroll
                for (int r = 0; r < 4; ++r) {
                    float v = acc[cti][r] + bv;
                    if constexpr (SCL)  v *= BN_S;
                    if constexpr (ACT)  v = gelu_f(v);
                    if constexpr (QSCL) v *= ATT_SCALE;
                    vv[r] = v;
                }
                float4 o4 = {vv[0], vv[1], vv[2], vv[3]};
                *(float4*)&((float*)ocv)[(size_t)col * PBEV + row0] = o4;
            } else {
                #pragma unroll
                for (int r = 0; r < 4; ++r) {
                    int row = rb + roww * 16 + g * 4 + r;
                    float v = acc[cti][r] + bv;
                    if constexpr (SCL)  v *= BN_S;
                    if constexpr (ACT)  v = gelu_f(v);
                    if constexpr (QSCL) v *= ATT_SCALE;
                    if constexpr (EMB) { if (set == 0) v += embv[cti][r] * invr[r]; }
                    if constexpr (ADDM == 1) { if (set == 0) v += addb[(size_t)row * 128 + col]; }
                    if constexpr (ADDM == 2) { if (set == 0) v += addb[(size_t)col * PBEV + row]; }
                    if constexpr (OUTBF) ((unsigned short*)ocv)[(size_t)row * NOT + col] = f2bf(v);
                    else                 ((float*)ocv)[(size_t)row * NOT + col] = v;
                }
            }
        }
    }
}

// ---------- thin wrapper kernel (used for expand) ----------
template<int BR, int KCH, int NOT, int AMODE, int LNF, int BIASF, int ACT, int SCL,
         int ADDM, int STM, int ASCL, int DUAL, int OUTBF, int QSCL, int WRLN,
         int EMB, int WBF>
__global__ __launch_bounds__(256)
void k_gemm_mfma(const float* __restrict__ A, const float* __restrict__ W,
                 const float* __restrict__ bias, const float* __restrict__ addb,
                 const float* __restrict__ ascale, const float* __restrict__ W2,
                 const float* __restrict__ bias2, void* __restrict__ out2v,
                 float* __restrict__ aux, void* __restrict__ outv) {
    __shared__ unsigned short Al[BR * 136];
    __shared__ unsigned short Wl[128 * 136];
    gemm_body<BR,KCH,NOT,AMODE,LNF,BIASF,ACT,SCL,ADDM,STM,ASCL,DUAL,OUTBF,QSCL,WRLN,EMB,WBF>(
        Al, Wl, A, W, bias, addb, ascale, W2, bias2, out2v, aux, outv,
        blockIdx.x * BR, blockIdx.y * 128, blockIdx.y == 0);
}

// ---------- fused keyval (blocks 0..287) + q-head (288..671) launch ----------
__global__ __launch_bounds__(256)
void k_kvq(const float* __restrict__ feat, const unsigned short* __restrict__ wb,
           const float* __restrict__ ie_w, const float* __restrict__ ce_w,
           const float* __restrict__ I_inv, const float* __restrict__ E_inv,
           unsigned short* __restrict__ key_b, unsigned short* __restrict__ val_b,
           const float* __restrict__ a1_qb, const float* __restrict__ bev,
           const float* __restrict__ x_cl, const float* __restrict__ be_w,
           const float* __restrict__ be_b, unsigned short* __restrict__ qh1b) {
    __shared__ unsigned short Al[64 * 136];
    __shared__ unsigned short Wl[128 * 136];
    if (blockIdx.x < 288) {
        // key/val: feature transpose + BN/relu staging, dual GEMM, EMB on key
        gemm_body<64,1,128, 1,0,0,0,0, 0,0,0,1, 1,0,0,1,1>(
            Al, Wl, feat, (const float*)(wb + OFF_FP), ie_w, E_inv, I_inv,
            (const float*)(wb + OFF_FL), ce_w, val_b, nullptr, key_b,
            blockIdx.x * 64, 0, 0);
    } else {
        // q head: fused query gen (AMODE 3), LN, bias, bf16 out, pre-scaled
        gemm_body<64,1,128, 3,1,1,0,0, 0,0,0,0, 1,1,0,0,1>(
            Al, Wl, nullptr, (const float*)(wb + OFF_A1QW), a1_qb, bev, x_cl,
            be_w, be_b, (void*)E_inv, (float*)ce_w, qh1b,
            (blockIdx.x - 288) * 64, 0, 0);
    }
}

// ---------- merged k/v head GEMM (bf16 A, LN, dual weights, bf16 out) ----------
struct KVJob {
    const unsigned short* A;
    const unsigned short* W1;
    const float* b1;
    const unsigned short* W2;
    const float* b2;
    unsigned short* o1;
    unsigned short* o2;
};

__global__ __launch_bounds__(256)
void k_kvheads(KVJob jk, KVJob jv) {
    const KVJob j = (blockIdx.x < 288) ? jk : jv;
    const int rb = (blockIdx.x % 288) * 64;
    __shared__ unsigned short Al[64 * 136];
    __shared__ unsigned short Wl[128 * 136];
    const int t = threadIdx.x;
    const int lane = t & 63, wv = t >> 6;
    const int la = lane & 15, g = lane >> 4;

    {   // stage A rows (bf16 in) + LN
        int r = t >> 2, seg = t & 3;
        const unsigned short* ab = j.A + (size_t)(rb + r) * 128 + seg * 32;
        float v[32];
        #pragma unroll
        for (int j8 = 0; j8 < 4; ++j8) {
            u16x8 raw = *(const u16x8*)&ab[8 * j8];
            #pragma unroll
            for (int jj = 0; jj < 8; ++jj) v[8 * j8 + jj] = bf2f(raw[jj]);
        }
        float s = 0.f;
        #pragma unroll
        for (int jj = 0; jj < 32; ++jj) s += v[jj];
        s += __shfl_xor(s, 1); s += __shfl_xor(s, 2);
        float mu = s * (1.0f / 128.0f);
        float ss = 0.f;
        #pragma unroll
        for (int jj = 0; jj < 32; ++jj) { float d = v[jj] - mu; ss += d * d; }
        ss += __shfl_xor(ss, 1); ss += __shfl_xor(ss, 2);
        float rs = rsqrtf(ss * (1.0f / 128.0f) + LN_EPS);
        #pragma unroll
        for (int j8 = 0; j8 < 4; ++j8) {
            u16x8 o;
            #pragma unroll
            for (int jj = 0; jj < 8; ++jj) o[jj] = f2bf((v[8 * j8 + jj] - mu) * rs);
            *(u16x8*)&Al[r * 136 + seg * 32 + 8 * j8] = o;
        }
    }

    #pragma unroll 1
    for (int set = 0; set < 2; ++set) {
        const unsigned short* Wc = set ? j.W2 : j.W1;
        const float* bc = set ? j.b2 : j.b1;
        unsigned short* oc = set ? j.o2 : j.o1;
        if (set) __syncthreads();
        #pragma unroll
        for (int i = 0; i < 8; ++i) {
            int chunk = i * 256 + t;
            int c = chunk >> 4, k8 = chunk & 15;
            *(u16x8*)&Wl[c * 136 + k8 * 8] =
                *(const u16x8*)&Wc[(size_t)c * 128 + k8 * 8];
        }
        __syncthreads();
        short8 af[4];
        #pragma unroll
        for (int ks = 0; ks < 4; ++ks)
            af[ks] = *(short8*)&Al[(wv * 16 + la) * 136 + ks * 32 + g * 8];
        #pragma unroll
        for (int ct = 0; ct < 8; ++ct) {
            f32x4 acc = (f32x4){0.f, 0.f, 0.f, 0.f};
            #pragma unroll
            for (int ks = 0; ks < 4; ++ks) {
                short8 bf = *(short8*)&Wl[(ct * 16 + la) * 136 + ks * 32 + g * 8];
                acc = __builtin_amdgcn_mfma_f32_16x16x32_bf16(af[ks], bf, acc, 0, 0, 0);
            }
            int col = ct * 16 + la;
            float bv = bc[col];
            #pragma unroll
            for (int r = 0; r < 4; ++r) {
                int row = rb + wv * 16 + g * 4 + r;
                oc[(size_t)row * 128 + col] = f2bf(acc[r] + bv);
            }
        }
    }
}

// ---------- fused attn-out projection (+mean/+residual) + LN-MLP (+opt a2q head) ----------
template<int AM, int QOUT>
__global__ __launch_bounds__(256)
void k_projmlp(const float* __restrict__ Ain, const unsigned short* __restrict__ pwb,
               const float* __restrict__ pb, const float* __restrict__ resid,
               const unsigned short* __restrict__ w1b, const float* __restrict__ b1,
               const unsigned short* __restrict__ w2b, const float* __restrict__ b2,
               float* __restrict__ out, const unsigned short* __restrict__ qwb,
               const float* __restrict__ qb, unsigned short* __restrict__ qout) {
    __shared__ unsigned short Al[16 * 136];
    __shared__ unsigned short Wl[128 * 72];
    __shared__ unsigned short Gl[16 * 264];
    __shared__ float Xf[16 * 132];
    const int t = threadIdx.x;
    const int rb = blockIdx.x * 16;
    const int lane = t & 63, wv = t >> 6;
    const int la = lane & 15, g = lane >> 4;

    {   // stage A_in -> Al bf16
        int r = t >> 4, seg = t & 15;
        float v[8];
        if constexpr (AM == 2) {
            int hw = rb + r;
            int h = hw >> 6, w = hw & 63;
            int l = (h >> 3) * 8 + (w >> 3), ww = (h & 7) * 8 + (w & 7);
            const float* src = Ain + ((size_t)(l * 64 + ww)) * 6 * 128 + seg * 8;
            #pragma unroll
            for (int jj = 0; jj < 8; ++jj) v[jj] = 0.f;
            #pragma unroll
            for (int n = 0; n < 6; ++n) {
                float4 x0 = *(const float4*)&src[n * 128];
                float4 x1 = *(const float4*)&src[n * 128 + 4];
                v[0] += x0.x; v[1] += x0.y; v[2] += x0.z; v[3] += x0.w;
                v[4] += x1.x; v[5] += x1.y; v[6] += x1.z; v[7] += x1.w;
            }
            #pragma unroll
            for (int jj = 0; jj < 8; ++jj) v[jj] *= (1.0f / 6.0f);
        } else {
            const float* ar = Ain + (size_t)(rb + r) * 128 + seg * 8;
            *(float4*)&v[0] = *(const float4*)&ar[0];
            *(float4*)&v[4] = *(const float4*)&ar[4];
        }
        u16x8 o;
        #pragma unroll
        for (int jj = 0; jj < 8; ++jj) o[jj] = f2bf(v[jj]);
        *(u16x8*)&Al[r * 136 + seg * 8] = o;
    }
    __syncthreads();

    // proj: X = A . pw^T + pb + resid
    f32x4 acc2[2];
    acc2[0] = (f32x4){0.f, 0.f, 0.f, 0.f};
    acc2[1] = (f32x4){0.f, 0.f, 0.f, 0.f};
    #pragma unroll 1
    for (int kc = 0; kc < 2; ++kc) {
        if (kc) __syncthreads();
        {
            int c = t >> 1, s2 = t & 1;
            const unsigned short* wr = pwb + (size_t)c * 128 + kc * 64 + s2 * 32;
            #pragma unroll
            for (int j8 = 0; j8 < 4; ++j8)
                *(u16x8*)&Wl[c * 72 + s2 * 32 + 8 * j8] = *(const u16x8*)&wr[8 * j8];
        }
        __syncthreads();
        #pragma unroll
        for (int half = 0; half < 2; ++half) {
            short8 pf = *(short8*)&Al[la * 136 + kc * 64 + half * 32 + g * 8];
            #pragma unroll
            for (int ct = 0; ct < 2; ++ct) {
                short8 bf = *(short8*)&Wl[((wv * 2 + ct) * 16 + la) * 72 + half * 32 + g * 8];
                acc2[ct] = __builtin_amdgcn_mfma_f32_16x16x32_bf16(pf, bf, acc2[ct], 0, 0, 0);
            }
        }
    }
    __syncthreads();
    #pragma unroll
    for (int ct = 0; ct < 2; ++ct) {
        int col = (wv * 2 + ct) * 16 + la;
        float bv = pb[col];
        #pragma unroll
        for (int r = 0; r < 4; ++r) {
            int row = g * 4 + r;
            Xf[row * 132 + col] = acc2[ct][r] + bv
                                + resid[(size_t)(rb + row) * 128 + col];
        }
    }
    __syncthreads();

    {   // LN(X) -> Al
        int r = t >> 4, seg = t & 15;
        float v[8];
        #pragma unroll
        for (int jj = 0; jj < 8; ++jj) v[jj] = Xf[r * 132 + seg * 8 + jj];
        float s = 0.f;
        #pragma unroll
        for (int jj = 0; jj < 8; ++jj) s += v[jj];
        s += __shfl_xor(s, 1); s += __shfl_xor(s, 2);
        s += __shfl_xor(s, 4); s += __shfl_xor(s, 8);
        float mu = s * (1.0f / 128.0f);
        float ss = 0.f;
        #pragma unroll
        for (int jj = 0; jj < 8; ++jj) { float d = v[jj] - mu; ss += d * d; }
        ss += __shfl_xor(ss, 1); ss += __shfl_xor(ss, 2);
        ss += __shfl_xor(ss, 4); ss += __shfl_xor(ss, 8);
        float rs = rsqrtf(ss * (1.0f / 128.0f) + LN_EPS);
        u16x8 o;
        #pragma unroll
        for (int jj = 0; jj < 8; ++jj) o[jj] = f2bf((v[jj] - mu) * rs);
        *(u16x8*)&Al[r * 136 + seg * 8] = o;
    }
    __syncthreads();

    short8 af[4];
    #pragma unroll
    for (int ks = 0; ks < 4; ++ks)
        af[ks] = *(short8*)&Al[la * 136 + ks * 32 + g * 8];

    // MLP GEMM1 -> Gl
    #pragma unroll 1
    for (int cc = 0; cc < 4; ++cc) {
        {
            int c = t >> 2, s2 = t & 3;
            const unsigned short* wr = w1b + (size_t)(cc * 64 + c) * 128 + s2 * 32;
            #pragma unroll
            for (int j8 = 0; j8 < 4; ++j8)
                *(u16x8*)&Wl[c * 136 + s2 * 32 + 8 * j8] = *(const u16x8*)&wr[8 * j8];
        }
        __syncthreads();
        f32x4 acc = (f32x4){0.f, 0.f, 0.f, 0.f};
        #pragma unroll
        for (int ks = 0; ks < 4; ++ks) {
            short8 bf = *(short8*)&Wl[(wv * 16 + la) * 136 + ks * 32 + g * 8];
            acc = __builtin_amdgcn_mfma_f32_16x16x32_bf16(af[ks], bf, acc, 0, 0, 0);
        }
        int col = cc * 64 + wv * 16 + la;
        float bv = b1[col];
        #pragma unroll
        for (int r = 0; r < 4; ++r)
            Gl[(g * 4 + r) * 264 + col] = f2bf(gelu_f(acc[r] + bv));
        __syncthreads();
    }

    // MLP GEMM2
    acc2[0] = (f32x4){0.f, 0.f, 0.f, 0.f};
    acc2[1] = (f32x4){0.f, 0.f, 0.f, 0.f};
    #pragma unroll 1
    for (int kc = 0; kc < 4; ++kc) {
        {
            int c = t >> 1, s2 = t & 1;
            const unsigned short* wr = w2b + (size_t)c * 256 + kc * 64 + s2 * 32;
            #pragma unroll
            for (int j8 = 0; j8 < 4; ++j8)
                *(u16x8*)&Wl[c * 72 + s2 * 32 + 8 * j8] = *(const u16x8*)&wr[8 * j8];
        }
        __syncthreads();
        #pragma unroll
        for (int half = 0; half < 2; ++half) {
            short8 pf = *(short8*)&Gl[la * 264 + kc * 64 + half * 32 + g * 8];
            #pragma unroll
            for (int ct = 0; ct < 2; ++ct) {
                short8 bf = *(short8*)&Wl[((wv * 2 + ct) * 16 + la) * 72 + half * 32 + g * 8];
                acc2[ct] = __builtin_amdgcn_mfma_f32_16x16x32_bf16(pf, bf, acc2[ct], 0, 0, 0);
            }
        }
        __syncthreads();
    }
    #pragma unroll
    for (int ct = 0; ct < 2; ++ct) {
        int col = (wv * 2 + ct) * 16 + la;
        float bv = b2[col];
        #pragma unroll
        for (int r = 0; r < 4; ++r) {
            int row = g * 4 + r;
            float y = acc2[ct][r] + bv + Xf[row * 132 + col];
            out[(size_t)(rb + row) * 128 + col] = y;
            if constexpr (QOUT) Xf[row * 132 + col] = y;
        }
    }

    if constexpr (QOUT) {
        __syncthreads();
        {   // LN(Y) -> Al
            int r = t >> 4, seg = t & 15;
            float v[8];
            #pragma unroll
            for (int jj = 0; jj < 8; ++jj) v[jj] = Xf[r * 132 + seg * 8 + jj];
            float s = 0.f;
            #pragma unroll
            for (int jj = 0; jj < 8; ++jj) s += v[jj];
            s += __shfl_xor(s, 1); s += __shfl_xor(s, 2);
            s += __shfl_xor(s, 4); s += __shfl_xor(s, 8);
            float mu = s * (1.0f / 128.0f);
            float ss = 0.f;
            #pragma unroll
            for (int jj = 0; jj < 8; ++jj) { float d = v[jj] - mu; ss += d * d; }
            ss += __shfl_xor(ss, 1); ss += __shfl_xor(ss, 2);
            ss += __shfl_xor(ss, 4); ss += __shfl_xor(ss, 8);
            float rs = rsqrtf(ss * (1.0f / 128.0f) + LN_EPS);
            u16x8 o;
            #pragma unroll
            for (int jj = 0; jj < 8; ++jj) o[jj] = f2bf((v[jj] - mu) * rs);
            *(u16x8*)&Al[r * 136 + seg * 8] = o;
        }
        __syncthreads();
        // a2 q-head GEMM: qout = (LN(Y) . qw^T + qb) * ATT_SCALE  (bf16)
        f32x4 acc3[2];
        acc3[0] = (f32x4){0.f, 0.f, 0.f, 0.f};
        acc3[1] = (f32x4){0.f, 0.f, 0.f, 0.f};
        #pragma unroll 1
        for (int kc = 0; kc < 2; ++kc) {
            if (kc) __syncthreads();
            {
                int c = t >> 1, s2 = t & 1;
                const unsigned short* wr = qwb + (size_t)c * 128 + kc * 64 + s2 * 32;
                #pragma unroll
                for (int j8 = 0; j8 < 4; ++j8)
                    *(u16x8*)&Wl[c * 72 + s2 * 32 + 8 * j8] = *(const u16x8*)&wr[8 * j8];
            }
            __syncthreads();
            #pragma unroll
            for (int half = 0; half < 2; ++half) {
                short8 pf = *(short8*)&Al[la * 136 + kc * 64 + half * 32 + g * 8];
                #pragma unroll
                for (int ct = 0; ct < 2; ++ct) {
                    short8 bf = *(short8*)&Wl[((wv * 2 + ct) * 16 + la) * 72 + half * 32 + g * 8];
                    acc3[ct] = __builtin_amdgcn_mfma_f32_16x16x32_bf16(pf, bf, acc3[ct], 0, 0, 0);
                }
            }
        }
        #pragma unroll
        for (int ct = 0; ct < 2; ++ct) {
            int col = (wv * 2 + ct) * 16 + la;
            float bv = qb[col];
            #pragma unroll
            for (int r = 0; r < 4; ++r) {
                int row = g * 4 + r;
                qout[(size_t)(rb + row) * 128 + col] = f2bf((acc3[ct][r] + bv) * ATT_SCALE);
            }
        }
    }
}

// ---------- fused mbproj(+SE,+zln) -> pm-FFN -> proj_out (gelu, transposed) ----------
__global__ __launch_bounds__(256)
void k_mbprojmlp(const float* __restrict__ dwo, const unsigned short* __restrict__ mbpwb,
                 const float* __restrict__ se, const float* __restrict__ zln,
                 const unsigned short* __restrict__ w1b, const float* __restrict__ b1,
                 const unsigned short* __restrict__ w2b, const float* __restrict__ b2,
                 const unsigned short* __restrict__ pob, const float* __restrict__ pb,
                 float* __restrict__ out) {
    __shared__ unsigned short Al[16 * 136];
    __shared__ unsigned short Wl[128 * 72];
    __shared__ unsigned short Gl[16 * 264];
    __shared__ float Xf[16 * 132];
    const int t = threadIdx.x;
    const int rb = blockIdx.x * 16;
    const int lane = t & 63, wv = t >> 6;
    const int la = lane & 15, g = lane >> 4;

    f32x4 acc2[2];
    acc2[0] = (f32x4){0.f, 0.f, 0.f, 0.f};
    acc2[1] = (f32x4){0.f, 0.f, 0.f, 0.f};
    #pragma unroll 1
    for (int kc = 0; kc < 8; ++kc) {
        if (kc) __syncthreads();
        {
            int r = t >> 4, seg = t & 15;
            const float* ar = dwo + (size_t)(rb + r) * 512 + kc * 64 + seg * 4;
            float4 v = *(const float4*)ar;
            const float* sp = se + kc * 64 + seg * 4;
            v.x *= sp[0]; v.y *= sp[1]; v.z *= sp[2]; v.w *= sp[3];
            unsigned short* dst = &Al[r * 136 + seg * 4];
            dst[0] = f2bf(v.x); dst[1] = f2bf(v.y);
            dst[2] = f2bf(v.z); dst[3] = f2bf(v.w);
        }
        {
            int c = t >> 1, s2 = t & 1;
            const unsigned short* wr = mbpwb + (size_t)c * 512 + kc * 64 + s2 * 32;
            #pragma unroll
            for (int j8 = 0; j8 < 4; ++j8)
                *(u16x8*)&Wl[c * 72 + s2 * 32 + 8 * j8] = *(const u16x8*)&wr[8 * j8];
        }
        __syncthreads();
        #pragma unroll
        for (int half = 0; half < 2; ++half) {
            short8 pf = *(short8*)&Al[la * 136 + half * 32 + g * 8];
            #pragma unroll
            for (int ct = 0; ct < 2; ++ct) {
                short8 bf = *(short8*)&Wl[((wv * 2 + ct) * 16 + la) * 72 + half * 32 + g * 8];
                acc2[ct] = __builtin_amdgcn_mfma_f32_16x16x32_bf16(pf, bf, acc2[ct], 0, 0, 0);
            }
        }
    }
    __syncthreads();
    #pragma unroll
    for (int ct = 0; ct < 2; ++ct) {
        int col = (wv * 2 + ct) * 16 + la;
        #pragma unroll
        for (int r = 0; r < 4; ++r) {
            int row = g * 4 + r;
            Xf[row * 132 + col] = acc2[ct][r] * BN_S
                                + zln[(size_t)(rb + row) * 128 + col];
        }
    }
    __syncthreads();

    {
        int r = t >> 4, seg = t & 15;
        u16x8 o;
        #pragma unroll
        for (int jj = 0; jj < 8; ++jj) o[jj] = f2bf(Xf[r * 132 + seg * 8 + jj]);
        *(u16x8*)&Al[r * 136 + seg * 8] = o;
    }
    __syncthreads();

    short8 af[4];
    #pragma unroll
    for (int ks = 0; ks < 4; ++ks)
        af[ks] = *(short8*)&Al[la * 136 + ks * 32 + g * 8];

    #pragma unroll 1
    for (int cc = 0; cc < 4; ++cc) {
        {
            int c = t >> 2, s2 = t & 3;
            const unsigned short* wr = w1b + (size_t)(cc * 64 + c) * 128 + s2 * 32;
            #pragma unroll
            for (int j8 = 0; j8 < 4; ++j8)
                *(u16x8*)&Wl[c * 136 + s2 * 32 + 8 * j8] = *(const u16x8*)&wr[8 * j8];
        }
        __syncthreads();
        f32x4 acc = (f32x4){0.f, 0.f, 0.f, 0.f};
        #pragma unroll
        for (int ks = 0; ks < 4; ++ks) {
            short8 bf = *(short8*)&Wl[(wv * 16 + la) * 136 + ks * 32 + g * 8];
            acc = __builtin_amdgcn_mfma_f32_16x16x32_bf16(af[ks], bf, acc, 0, 0, 0);
        }
        int col = cc * 64 + wv * 16 + la;
        float bv = b1[col];
        #pragma unroll
        for (int r = 0; r < 4; ++r)
            Gl[(g * 4 + r) * 264 + col] = f2bf(gelu_f(acc[r] + bv));
        __syncthreads();
    }

    acc2[0] = (f32x4){0.f, 0.f, 0.f, 0.f};
    acc2[1] = (f32x4){0.f, 0.f, 0.f, 0.f};
    #pragma unroll 1
    for (int kc = 0; kc < 4; ++kc) {
        {
            int c = t >> 1, s2 = t & 1;
            const unsigned short* wr = w2b + (size_t)c * 256 + kc * 64 + s2 * 32;
            #pragma unroll
            for (int j8 = 0; j8 < 4; ++j8)
                *(u16x8*)&Wl[c * 72 + s2 * 32 + 8 * j8] = *(const u16x8*)&wr[8 * j8];
        }
        __syncthreads();
        #pragma unroll
        for (int half = 0; half < 2; ++half) {
            short8 pf = *(short8*)&Gl[la * 264 + kc * 64 + half * 32 + g * 8];
            #pragma unroll
            for (int ct = 0; ct < 2; ++ct) {
                short8 bf = *(short8*)&Wl[((wv * 2 + ct) * 16 + la) * 72 + half * 32 + g * 8];
                acc2[ct] = __builtin_amdgcn_mfma_f32_16x16x32_bf16(pf, bf, acc2[ct], 0, 0, 0);
            }
        }
        __syncthreads();
    }
    #pragma unroll
    for (int ct = 0; ct < 2; ++ct) {
        int col = (wv * 2 + ct) * 16 + la;
        float bv = b2[col];
        #pragma unroll
        for (int r = 0; r < 4; ++r) {
            int row = g * 4 + r;
            float y = acc2[ct][r] + bv + Xf[row * 132 + col];
            Al[row * 136 + col] = f2bf(y);
        }
    }
    __syncthreads();

    f32x4 acc3[2];
    acc3[0] = (f32x4){0.f, 0.f, 0.f, 0.f};
    acc3[1] = (f32x4){0.f, 0.f, 0.f, 0.f};
    #pragma unroll 1
    for (int kc = 0; kc < 2; ++kc) {
        if (kc) __syncthreads();
        {
            int c = t >> 1, s2 = t & 1;
            const unsigned short* wr = pob + (size_t)c * 128 + kc * 64 + s2 * 32;
            #pragma unroll
            for (int j8 = 0; j8 < 4; ++j8)
                *(u16x8*)&Wl[c * 72 + s2 * 32 + 8 * j8] = *(const u16x8*)&wr[8 * j8];
        }
        __syncthreads();
        #pragma unroll
        for (int half = 0; half < 2; ++half) {
            short8 pf = *(short8*)&Al[la * 136 + kc * 64 + half * 32 + g * 8];
            #pragma unroll
            for (int ct = 0; ct < 2; ++ct) {
                short8 bf = *(short8*)&Wl[((wv * 2 + ct) * 16 + la) * 72 + half * 32 + g * 8];
                acc3[ct] = __builtin_amdgcn_mfma_f32_16x16x32_bf16(pf, bf, acc3[ct], 0, 0, 0);
            }
        }
    }
    #pragma unroll
    for (int ct = 0; ct < 2; ++ct) {
        int col = (wv * 2 + ct) * 16 + la;
        float bv = pb[col];
        float4 o4;
        o4.x = gelu_f(acc3[ct][0] + bv);
        o4.y = gelu_f(acc3[ct][1] + bv);
        o4.z = gelu_f(acc3[ct][2] + bv);
        o4.w = gelu_f(acc3[ct][3] + bv);
        *(float4*)&out[(size_t)col * PBEV + rb + g * 4] = o4;
    }
}

// ---------- MFMA flash attention (S^T trick, shfl P re-layout) ----------
template<int MODE>
__global__ __launch_bounds__(MODE == 1 ? 512 : 256)
void k_attn_mfma(const unsigned short* __restrict__ qh, const unsigned short* __restrict__ kh,
                 const unsigned short* __restrict__ vh, float* __restrict__ aout) {
    constexpr int WAVES = (MODE == 1) ? 8 : 4;
    constexpr int QTPW  = (MODE == 1) ? 3 : 1;
    constexpr int T = WAVES * 64;
    const int l = blockIdx.x, m = blockIdx.y;
    const int xw = l >> 3, yw = l & 7;
    const int t = threadIdx.x;
    const int lane = t & 63, wv = t >> 6;
    const int la = lane & 15, g = lane >> 4;

    __shared__ unsigned short Kl[KROWS * 40];
    __shared__ unsigned short Vt[32 * 312];

    for (int i = t; i < KROWS * 4; i += T) {
        int row = i >> 2, seg = i & 3;
        int n = row / 48, kk = row % 48;
        int k1 = kk / 12, k2 = kk % 12;
        int h, w;
        if (MODE == 1) { h = xw * 4 + k1;  w = yw * 12 + k2; }
        else           { h = k1 * 8 + xw;  w = k2 * 8 + yw;  }
        size_t src = ((size_t)(n * PIMG + h * FWW + w)) * 128 + m * DHD + seg * 8;
        short8 kv = *(const short8*)&kh[src];
        *(short8*)&Kl[row * 40 + seg * 8] = kv;
        short8 vv = *(const short8*)&vh[src];
        #pragma unroll
        for (int j = 0; j < 8; ++j)
            Vt[(seg * 8 + j) * 312 + row] = (unsigned short)vv[j];
    }

    short8 qf[QTPW];
    #pragma unroll
    for (int qt = 0; qt < QTPW; ++qt) {
        int q = (wv * QTPW + qt) * 16 + la;
        int row;
        if (MODE == 1) {
            int n = q >> 6, ww = q & 63;
            row = n * PBEV + (xw * 8 + (ww >> 3)) * 64 + yw * 8 + (ww & 7);
        } else {
            row = ((q >> 3) * 8 + xw) * 64 + (q & 7) * 8 + yw;
        }
        qf[qt] = *(const short8*)&qh[(size_t)row * 128 + m * DHD + g * 8];
    }
    __syncthreads();

    f32x4 acc[QTPW][2];
    float srow[QTPW];
    #pragma unroll
    for (int qt = 0; qt < QTPW; ++qt) {
        acc[qt][0] = (f32x4){0.f, 0.f, 0.f, 0.f};
        acc[qt][1] = (f32x4){0.f, 0.f, 0.f, 0.f};
        srow[qt] = 0.f;
    }
    const int a0 = la + 32 * (g & 1);
    const int a1 = a0 + 16;
    const bool selA = (g < 2);

    #pragma unroll 1
    for (int c = 0; c < 9; ++c) {
        const int kk0 = c * 32;
        short8 kf0 = *(short8*)&Kl[(kk0 + la) * 40 + g * 8];
        short8 kf1 = *(short8*)&Kl[(kk0 + 16 + la) * 40 + g * 8];
        short8 vf0 = *(short8*)&Vt[la * 312 + kk0 + g * 8];
        short8 vf1 = *(short8*)&Vt[(16 + la) * 312 + kk0 + g * 8];
        #pragma unroll
        for (int qt = 0; qt < QTPW; ++qt) {
            f32x4 sA = __builtin_amdgcn_mfma_f32_16x16x32_bf16(kf0, qf[qt], (f32x4){0.f,0.f,0.f,0.f}, 0, 0, 0);
            f32x4 sB = __builtin_amdgcn_mfma_f32_16x16x32_bf16(kf1, qf[qt], (f32x4){0.f,0.f,0.f,0.f}, 0, 0, 0);
            float pA[4], pB[4];
            #pragma unroll
            for (int r = 0; r < 4; ++r) { pA[r] = __expf(sA[r]); pB[r] = __expf(sB[r]); }
            srow[qt] += ((pA[0] + pA[1]) + (pA[2] + pA[3]))
                      + ((pB[0] + pB[1]) + (pB[2] + pB[3]));
            unsigned int loA = (unsigned int)f2bf(pA[0]) | ((unsigned int)f2bf(pA[1]) << 16);
            unsigned int hiA = (unsigned int)f2bf(pA[2]) | ((unsigned int)f2bf(pA[3]) << 16);
            unsigned int loB = (unsigned int)f2bf(pB[0]) | ((unsigned int)f2bf(pB[1]) << 16);
            unsigned int hiB = (unsigned int)f2bf(pB[2]) | ((unsigned int)f2bf(pB[3]) << 16);
            int w0A = __shfl((int)loA, a0); int w0B = __shfl((int)loB, a0);
            int w1A = __shfl((int)hiA, a0); int w1B = __shfl((int)hiB, a0);
            int w2A = __shfl((int)loA, a1); int w2B = __shfl((int)loB, a1);
            int w3A = __shfl((int)hiA, a1); int w3B = __shfl((int)hiB, a1);
            union { int u[4]; short8 s; } pu;
            pu.u[0] = selA ? w0A : w0B;
            pu.u[1] = selA ? w1A : w1B;
            pu.u[2] = selA ? w2A : w2B;
            pu.u[3] = selA ? w3A : w3B;
            acc[qt][0] = __builtin_amdgcn_mfma_f32_16x16x32_bf16(pu.s, vf0, acc[qt][0], 0, 0, 0);
            acc[qt][1] = __builtin_amdgcn_mfma_f32_16x16x32_bf16(pu.s, vf1, acc[qt][1], 0, 0, 0);
        }
    }

    #pragma unroll
    for (int qt = 0; qt < QTPW; ++qt) {
        float s = srow[qt];
        s += __shfl_xor(s, 16);
        s += __shfl_xor(s, 32);
        #pragma unroll
        for (int r = 0; r < 4; ++r) {
            float sq = __shfl(s, g * 4 + r);
            float inv = 1.0f / sq;
            int q = (wv * QTPW + qt) * 16 + g * 4 + r;
            size_t orow;
            if (MODE == 1) {
                int n = q >> 6, ww = q & 63;
                orow = (size_t)(l * 64 + ww) * 6 + n;
            } else {
                orow = (size_t)(((q >> 3) * 8 + xw) * 64 + (q & 7) * 8 + yw);
            }
            float* ap = aout + orow * 128 + m * DHD;
            ap[la]      = acc[qt][0][r] * inv;
            ap[16 + la] = acc[qt][1][r] * inv;
        }
    }
}

// ---------- depthwise 3x3 + gelu + SE partials ----------
__global__ void k_dwconv(const float* __restrict__ ex, const float* __restrict__ dwgt,
                         float* __restrict__ dwout, float* __restrict__ separt) {
    const int TILE = 16;
    int ch = threadIdx.x;
    int hw0 = blockIdx.x * TILE;
    float wreg[9];
    #pragma unroll
    for (int i = 0; i < 9; ++i) wreg[i] = dwgt[ch * 9 + i];
    float sacc = 0.f;
    for (int ti = 0; ti < TILE; ++ti) {
        int hw = hw0 + ti;
        int h = hw >> 6, w = hw & 63;
        float s = 0.f;
        #pragma unroll
        for (int dy = -1; dy <= 1; ++dy) {
            int h2 = h + dy;
            if (h2 < 0 || h2 >= 64) continue;
            #pragma unroll
            for (int dx = -1; dx <= 1; ++dx) {
                int w2 = w + dx;
                if (w2 < 0 || w2 >= 64) continue;
                s += ex[((size_t)(h2 * 64 + w2)) * 512 + ch] * wreg[(dy + 1) * 3 + (dx + 1)];
            }
        }
        float o = gelu_f(s * BN_S);
        dwout[(size_t)hw * 512 + ch] = o;
        sacc += o;
    }
    separt[(size_t)blockIdx.x * 512 + ch] = sacc;
}

// ---------- SE reduce stage 1 ----------
__global__ void k_sered(const float* __restrict__ separt, float* __restrict__ separt2) {
    int t = threadIdx.x, bb = blockIdx.x;
    float s = 0.f;
    #pragma unroll
    for (int i = 0; i < 16; ++i)
        s += separt[(size_t)(bb * 16 + i) * 512 + t];
    separt2[(size_t)bb * 512 + t] = s;
}

// ---------- SE final ----------
__global__ void k_se(const float* __restrict__ separt2,
                     const float* __restrict__ s1w, const float* __restrict__ s1b,
                     const float* __restrict__ s2w, const float* __restrict__ s2b,
                     float* __restrict__ se) {
    __shared__ float mean[512];
    __shared__ float s1[32];
    int t = threadIdx.x;
    float s = 0.f;
    #pragma unroll
    for (int b = 0; b < 16; ++b) s += separt2[b * 512 + t];
    mean[t] = s * (1.0f / 4096.0f);
    __syncthreads();
    int u = t >> 4, seg = t & 15;
    float acc = 0.f;
    #pragma unroll
    for (int j = 0; j < 32; ++j) {
        int c = seg + 16 * j;
        acc += mean[c] * s1w[u * 512 + c];
    }
    acc += __shfl_xor(acc, 1); acc += __shfl_xor(acc, 2);
    acc += __shfl_xor(acc, 4); acc += __shfl_xor(acc, 8);
    if (seg == 0) s1[u] = gelu_f(acc + s1b[u]);
    __syncthreads();
    float a2 = s2b[t];
    #pragma unroll
    for (int j = 0; j < 32; ++j) a2 += s1[j] * s2w[t * 32 + j];
    se[t] = 1.0f / (1.0f + __expf(-a2));
}

extern "C" void kernel_launch(void* const* d_in, const int* in_sizes, int n_in,
                              void* d_out, int out_size, void* d_ws, size_t ws_size,
                              hipStream_t stream) {
    (void)in_sizes; (void)n_in; (void)out_size; (void)ws_size;
    const float* x      = (const float*)d_in[1];
    const float* feat   = (const float*)d_in[2];
    const float* I_inv  = (const float*)d_in[3];
    const float* E_inv  = (const float*)d_in[4];
    const float* bev    = (const float*)d_in[5];
    const float* fl_w   = (const float*)d_in[6];
    const float* fp_w   = (const float*)d_in[7];
    const float* be_w   = (const float*)d_in[8];
    const float* be_b   = (const float*)d_in[9];
    const float* ie_w   = (const float*)d_in[10];
    const float* ce_w   = (const float*)d_in[11];
    const float* a1_qw  = (const float*)d_in[12];
    const float* a1_qb  = (const float*)d_in[13];
    const float* a1_kw  = (const float*)d_in[14];
    const float* a1_kb  = (const float*)d_in[15];
    const float* a1_vw  = (const float*)d_in[16];
    const float* a1_vb  = (const float*)d_in[17];
    const float* a1_pw  = (const float*)d_in[18];
    const float* a1_pb  = (const float*)d_in[19];
    const float* a2_qw  = (const float*)d_in[20];
    const float* a2_qb  = (const float*)d_in[21];
    const float* a2_kw  = (const float*)d_in[22];
    const float* a2_kb  = (const float*)d_in[23];
    const float* a2_vw  = (const float*)d_in[24];
    const float* a2_vb  = (const float*)d_in[25];
    const float* a2_pw  = (const float*)d_in[26];
    const float* a2_pb  = (const float*)d_in[27];
    const float* m1_w1  = (const float*)d_in[28];
    const float* m1_b1  = (const float*)d_in[29];
    const float* m1_w2  = (const float*)d_in[30];
    const float* m1_b2  = (const float*)d_in[31];
    const float* m2_w1  = (const float*)d_in[32];
    const float* m2_b1  = (const float*)d_in[33];
    const float* m2_w2  = (const float*)d_in[34];
    const float* m2_b2  = (const float*)d_in[35];
    const float* mb_ew  = (const float*)d_in[36];
    const float* mb_dw  = (const float*)d_in[37];
    const float* mb_s1w = (const float*)d_in[38];
    const float* mb_s1b = (const float*)d_in[39];
    const float* mb_s2w = (const float*)d_in[40];
    const float* mb_s2b = (const float*)d_in[41];
    const float* mb_pw  = (const float*)d_in[42];
    const float* pm_w1  = (const float*)d_in[43];
    const float* pm_b1  = (const float*)d_in[44];
    const float* pm_w2  = (const float*)d_in[45];
    const float* pm_b2  = (const float*)d_in[46];
    const float* po_w   = (const float*)d_in[47];
    const float* po_b   = (const float*)d_in[48];

    float* ws = (float*)d_ws;
    float* x_cl   = ws + 0;          // 524288
    unsigned short* key_b = (unsigned short*)(ws + 524288);
    unsigned short* val_b = (unsigned short*)(ws + 1703936);
    unsigned short* qh1b  = (unsigned short*)(ws + 2883584);
    unsigned short* kh1b  = (unsigned short*)(ws + 4456448);
    unsigned short* vh1b  = (unsigned short*)(ws + 5636096);
    unsigned short* kh2b  = (unsigned short*)(ws + 6815744);
    unsigned short* vh2b  = (unsigned short*)(ws + 7995392);
    float* abuf   = ws + 9175040;    // 3145728
    float* qimg   = ws + 12320768;
    float* qimg2  = ws + 12845056;
    float* zln    = ws + 13369344;
    float* abuf2  = ws + 13893632;
    float* expandb = ws + 14942208;  // 2097152
    float* dwout   = ws + 17039360;  // 2097152
    float* separt  = ws + 19136512;  // 131072
    float* separt2 = ws + 19267584;  // 8192
    float* sebuf   = ws + 19275776;  // 512
    unsigned short* wb = (unsigned short*)(ws + 19276288);  // 507904 u16
    unsigned short* qh2b = qh1b;

    // prep: weights -> bf16 arena + x transpose (one launch)
    k_prep<<<760, 256, 0, stream>>>(fp_w, fl_w, a1_qw, a1_kw, a2_kw, a1_vw, a2_vw,
                                    a1_pw, m1_w1, m1_w2, a2_qw, a2_pw, m2_w1, m2_w2,
                                    mb_ew, mb_pw, pm_w1, pm_w2, po_w, wb, x, x_cl);

    // key/val + q-head in ONE launch (independent jobs, grid-packed)
    k_kvq<<<672, 256, 0, stream>>>(feat, wb, ie_w, ce_w, I_inv, E_inv,
                                   key_b, val_b, a1_qb, bev, x_cl, be_w, be_b, qh1b);

    // k/v heads merged dual
    {
        KVJob jk = { key_b, wb + OFF_A1KW, a1_kb, wb + OFF_A2KW, a2_kb, kh1b, kh2b };
        KVJob jv = { val_b, wb + OFF_A1VW, a1_vb, wb + OFF_A2VW, a2_vb, vh1b, vh2b };
        k_kvheads<<<576, 256, 0, stream>>>(jk, jv);
    }
    k_attn_mfma<1><<<dim3(64, HEADS), 512, 0, stream>>>(qh1b, kh1b, vh1b, abuf);
    // stage-1 projmlp also emits qh2b (a2 q-head fused, pre-scaled)
    k_projmlp<2,1><<<256, 256, 0, stream>>>(abuf, wb + OFF_A1PW, a1_pb, x_cl,
                                            wb + OFF_M1W1, m1_b1, wb + OFF_M1W2, m1_b2,
                                            qimg, wb + OFF_A2QW, a2_qb, qh2b);

    // stage 2
    k_attn_mfma<2><<<dim3(64, HEADS), 256, 0, stream>>>(qh2b, kh2b, vh2b, abuf2);
    k_projmlp<0,0><<<256, 256, 0, stream>>>(abuf2, wb + OFF_A2PW, a2_pb, qimg,
                                            wb + OFF_M2W1, m2_b1, wb + OFF_M2W2, m2_b2,
                                            qimg2, nullptr, nullptr, nullptr);

    // stage 3
    k_gemm_mfma<16,1,512, 0,1,0,1,1, 0,0,0,0, 0,0,1,0,1><<<dim3(256, 4), 256, 0, stream>>>(
        qimg2, (const float*)(wb + OFF_MBEW), nullptr, nullptr, nullptr, nullptr,
        nullptr, nullptr, zln, expandb);
    k_dwconv<<<256, 512, 0, stream>>>(expandb, mb_dw, dwout, separt);
    k_sered<<<16, 512, 0, stream>>>(separt, separt2);
    k_se<<<1, 512, 0, stream>>>(separt2, mb_s1w, mb_s1b, mb_s2w, mb_s2b, sebuf);
    k_mbprojmlp<<<256, 256, 0, stream>>>(dwout, wb + OFF_MBPW, sebuf, zln,
                                         wb + OFF_PMW1, pm_b1, wb + OFF_PMW2, pm_b2,
                                         wb + OFF_POW, po_b, (float*)d_out);
}